// Round 2
// baseline (5318.340 us; speedup 1.0000x reference)
//
#include <hip/hip_runtime.h>
#include <cstdint>
#include <cstddef>

// NeuralMemory fp32, compact-workspace version (~193 MiB of d_ws).
// Math identical to round-1: mean-over-chunks of per-chunk grads == (1/C) *
// grad over all N=B*S rows; alpha/theta/eta == global gate means.
// Memory plan: g2 lives in d_out until phase 4; u0 is recomputed in backward
// L0; silu' fused into GEMM epilogue (no separate gbuf pass); params updated
// in place over the grad buffers.

#define NROWS 8192   // B*S
#define HDIM  512
#define HEDIM 2048
#define NCHUNK 8

__device__ __forceinline__ float sigmoidf_(float x) { return 1.0f / (1.0f + __expf(-x)); }
__device__ __forceinline__ float siluf_(float x)    { return x * sigmoidf_(x); }
__device__ __forceinline__ float dsiluf_(float x)   { float s = sigmoidf_(x); return s * (1.0f + x * (1.0f - s)); }

#define TS 64
#define KT 16

// Generic tiled GEMM: C[m,n] = sum_k opA(A)[m,k] * opB(B)[k,n] (+bias[n]) (+res[m,n]) (*dsilu(aux[m,n]))
// AKMAJ: A stored [K,M] row-major (lda=M)  else [M,K] (lda=K)
// BKMAJ: B stored [K,N] row-major (ldb=N)  else [N,K] (ldb=K)
template<bool AKMAJ, bool BKMAJ, bool SILUA, bool SILUB, bool BIASF, bool RESF, bool DSILUF>
__global__ __launch_bounds__(256)
void gemm_k(const float* __restrict__ A, const float* __restrict__ B,
            const float* __restrict__ bias, const float* __restrict__ res,
            const float* __restrict__ aux,
            float* __restrict__ C, int M, int N, int K)
{
    __shared__ float As[KT][TS + 4];
    __shared__ float Bs[KT][TS + 4];
    const int tid = threadIdx.x;
    const int m0 = blockIdx.y * TS, n0 = blockIdx.x * TS;
    const int tx = tid & 15, ty = tid >> 4;
    float acc[4][4] = {};

    for (int k0 = 0; k0 < K; k0 += KT) {
        if (AKMAJ) {
            const int r = tid >> 4, c = (tid & 15) << 2;
            float4 v = *reinterpret_cast<const float4*>(A + (size_t)(k0 + r) * M + m0 + c);
            if (SILUA) { v.x = siluf_(v.x); v.y = siluf_(v.y); v.z = siluf_(v.z); v.w = siluf_(v.w); }
            *reinterpret_cast<float4*>(&As[r][c]) = v;
        } else {
            const int r = tid >> 2, c = (tid & 3) << 2;
            float4 v = *reinterpret_cast<const float4*>(A + (size_t)(m0 + r) * K + k0 + c);
            if (SILUA) { v.x = siluf_(v.x); v.y = siluf_(v.y); v.z = siluf_(v.z); v.w = siluf_(v.w); }
            As[c + 0][r] = v.x; As[c + 1][r] = v.y; As[c + 2][r] = v.z; As[c + 3][r] = v.w;
        }
        if (BKMAJ) {
            const int r = tid >> 4, c = (tid & 15) << 2;
            float4 v = *reinterpret_cast<const float4*>(B + (size_t)(k0 + r) * N + n0 + c);
            if (SILUB) { v.x = siluf_(v.x); v.y = siluf_(v.y); v.z = siluf_(v.z); v.w = siluf_(v.w); }
            *reinterpret_cast<float4*>(&Bs[r][c]) = v;
        } else {
            const int r = tid >> 2, c = (tid & 3) << 2;
            float4 v = *reinterpret_cast<const float4*>(B + (size_t)(n0 + r) * K + k0 + c);
            if (SILUB) { v.x = siluf_(v.x); v.y = siluf_(v.y); v.z = siluf_(v.z); v.w = siluf_(v.w); }
            Bs[c + 0][r] = v.x; Bs[c + 1][r] = v.y; Bs[c + 2][r] = v.z; Bs[c + 3][r] = v.w;
        }
        __syncthreads();
        #pragma unroll
        for (int kk = 0; kk < KT; ++kk) {
            const float4 a4 = *reinterpret_cast<const float4*>(&As[kk][ty << 2]);
            const float4 b4 = *reinterpret_cast<const float4*>(&Bs[kk][tx << 2]);
            const float a[4] = {a4.x, a4.y, a4.z, a4.w};
            const float b[4] = {b4.x, b4.y, b4.z, b4.w};
            #pragma unroll
            for (int i = 0; i < 4; ++i)
                #pragma unroll
                for (int j = 0; j < 4; ++j)
                    acc[i][j] += a[i] * b[j];
        }
        __syncthreads();
    }

    const int cn = n0 + (tx << 2);
    float4 bv = make_float4(0.f, 0.f, 0.f, 0.f);
    if (BIASF) bv = *reinterpret_cast<const float4*>(bias + cn);
    #pragma unroll
    for (int i = 0; i < 4; ++i) {
        const size_t row = (size_t)m0 + (ty << 2) + i;
        float4 o;
        o.x = acc[i][0] + bv.x; o.y = acc[i][1] + bv.y;
        o.z = acc[i][2] + bv.z; o.w = acc[i][3] + bv.w;
        if (RESF) {
            float4 rv = *reinterpret_cast<const float4*>(res + row * N + cn);
            o.x += rv.x; o.y += rv.y; o.z += rv.z; o.w += rv.w;
        }
        if (DSILUF) {
            float4 uv = *reinterpret_cast<const float4*>(aux + row * N + cn);
            o.x *= dsiluf_(uv.x); o.y *= dsiluf_(uv.y);
            o.z *= dsiluf_(uv.z); o.w *= dsiluf_(uv.w);
        }
        *reinterpret_cast<float4*>(C + row * N + cn) = o;
    }
}

// in-place row l2norm, rows of HDIM; one wave per row
__global__ __launch_bounds__(64)
void l2norm_k(float* __restrict__ x)
{
    float* p = x + (size_t)blockIdx.x * HDIM;
    const int t = threadIdx.x;
    float4 v0 = *reinterpret_cast<const float4*>(p + t * 8);
    float4 v1 = *reinterpret_cast<const float4*>(p + t * 8 + 4);
    float s = v0.x*v0.x + v0.y*v0.y + v0.z*v0.z + v0.w*v0.w
            + v1.x*v1.x + v1.y*v1.y + v1.z*v1.z + v1.w*v1.w;
    #pragma unroll
    for (int o = 1; o < 64; o <<= 1) s += __shfl_xor(s, o);
    const float sc = 1.0f / fmaxf(sqrtf(s), 1e-12f);
    v0.x *= sc; v0.y *= sc; v0.z *= sc; v0.w *= sc;
    v1.x *= sc; v1.y *= sc; v1.z *= sc; v1.w *= sc;
    *reinterpret_cast<float4*>(p + t * 8)     = v0;
    *reinterpret_cast<float4*>(p + t * 8 + 4) = v1;
}

// per-row scalar gates
__global__ __launch_bounds__(64)
void gates_k(const float* __restrict__ x,
             const float* __restrict__ wlr, const float* __restrict__ blr,
             const float* __restrict__ wf,  const float* __restrict__ bfp,
             const float* __restrict__ wm,  const float* __restrict__ bm,
             float* __restrict__ lr_s, float* __restrict__ f_s, float* __restrict__ m_s)
{
    const size_t row = blockIdx.x;
    const float* p = x + row * HDIM;
    const int t = threadIdx.x;
    float s0 = 0.f, s1 = 0.f, s2 = 0.f;
    #pragma unroll
    for (int i = 0; i < 8; i += 4) {
        float4 xv = *reinterpret_cast<const float4*>(p   + t * 8 + i);
        float4 a  = *reinterpret_cast<const float4*>(wlr + t * 8 + i);
        float4 b  = *reinterpret_cast<const float4*>(wf  + t * 8 + i);
        float4 c  = *reinterpret_cast<const float4*>(wm  + t * 8 + i);
        s0 += xv.x*a.x + xv.y*a.y + xv.z*a.z + xv.w*a.w;
        s1 += xv.x*b.x + xv.y*b.y + xv.z*b.z + xv.w*b.w;
        s2 += xv.x*c.x + xv.y*c.y + xv.z*c.z + xv.w*c.w;
    }
    #pragma unroll
    for (int o = 1; o < 64; o <<= 1) {
        s0 += __shfl_xor(s0, o); s1 += __shfl_xor(s1, o); s2 += __shfl_xor(s2, o);
    }
    if (t == 0) {
        lr_s[row] = sigmoidf_(s0 + blr[0]) * 0.1f;
        f_s[row]  = sigmoidf_(s1 + bfp[0]);
        m_s[row]  = sigmoidf_(s2 + bm[0]);
    }
}

// g2 = lr[row] * 2/(H*C) * (x2 - v)   (in place over x2)
__global__ __launch_bounds__(256)
void dpred_k(float* __restrict__ g2, const float* __restrict__ v, const float* __restrict__ lr_s)
{
    const size_t i4 = (size_t)blockIdx.x * 256 + threadIdx.x;
    const size_t row = i4 >> 7;
    const float coef = lr_s[row] * (2.0f / (HDIM * NCHUNK));
    float4 a = *reinterpret_cast<const float4*>(g2 + (i4 << 2));
    float4 b = *reinterpret_cast<const float4*>(v  + (i4 << 2));
    a.x = coef * (a.x - b.x); a.y = coef * (a.y - b.y);
    a.z = coef * (a.z - b.z); a.w = coef * (a.w - b.w);
    *reinterpret_cast<float4*>(g2 + (i4 << 2)) = a;
}

// column-sum over NROWS rows, 2-pass (deterministic)
__global__ __launch_bounds__(64)
void colsum_part_k(const float* __restrict__ g, float* __restrict__ part, int cols)
{
    const int c = blockIdx.x * 64 + threadIdx.x;
    const int rc = blockIdx.y;
    const float* p = g + (size_t)rc * 128 * cols + c;
    float s = 0.f;
    for (int r = 0; r < 128; ++r) s += p[(size_t)r * cols];
    part[(size_t)rc * cols + c] = s;
}
__global__ __launch_bounds__(256)
void colsum_fin_k(const float* __restrict__ part, float* __restrict__ out, int cols)
{
    const int c = blockIdx.x * 256 + threadIdx.x;
    if (c < cols) {
        float s = 0.f;
        for (int r = 0; r < 64; ++r) s += part[(size_t)r * cols + c];
        out[c] = s;
    }
}

// global means of the gate vectors: sc = {alpha, theta, eta}
__global__ __launch_bounds__(256)
void scalars_k(const float* __restrict__ lr_s, const float* __restrict__ f_s,
               const float* __restrict__ m_s, float* __restrict__ sc)
{
    __shared__ float sh0[256], sh1[256], sh2[256];
    const int t = threadIdx.x;
    float s0 = 0.f, s1 = 0.f, s2 = 0.f;
    for (int i = t; i < NROWS; i += 256) { s0 += f_s[i]; s1 += lr_s[i]; s2 += m_s[i]; }
    sh0[t] = s0; sh1[t] = s1; sh2[t] = s2;
    __syncthreads();
    for (int o = 128; o > 0; o >>= 1) {
        if (t < o) { sh0[t] += sh0[t + o]; sh1[t] += sh1[t + o]; sh2[t] += sh2[t + o]; }
        __syncthreads();
    }
    if (t == 0) {
        sc[0] = sh0[0] / (float)NROWS;
        sc[1] = sh1[0] / (float)NROWS;
        sc[2] = sh2[0] / (float)NROWS;
    }
}

// np = p*(1-alpha) + eta*mom - theta*g   (np may alias g: same-index RW)
__global__ __launch_bounds__(256)
void update_k(const float* __restrict__ p, const float* __restrict__ g,
              const float* __restrict__ mom, const float* __restrict__ sc,
              float* __restrict__ np_, int n)
{
    const int i = blockIdx.x * 256 + threadIdx.x;
    if (i < n) np_[i] = p[i] * (1.0f - sc[0]) + sc[2] * mom[i] - sc[1] * g[i];
}

extern "C" void kernel_launch(void* const* d_in, const int* in_sizes, int n_in,
                              void* d_out, int out_size, void* d_ws, size_t ws_size,
                              hipStream_t stream)
{
    const float* x      = (const float*)d_in[0];
    const float* wq     = (const float*)d_in[1];
    const float* bq     = (const float*)d_in[2];
    const float* wk     = (const float*)d_in[3];
    const float* bk     = (const float*)d_in[4];
    const float* wv     = (const float*)d_in[5];
    const float* bv     = (const float*)d_in[6];
    const float* wlr    = (const float*)d_in[7];
    const float* blr    = (const float*)d_in[8];
    const float* wf     = (const float*)d_in[9];
    const float* bfp    = (const float*)d_in[10];
    const float* wm     = (const float*)d_in[11];
    const float* bm     = (const float*)d_in[12];
    const float* mw1    = (const float*)d_in[13];
    const float* mb1    = (const float*)d_in[14];
    const float* mw2    = (const float*)d_in[15];
    const float* mb2    = (const float*)d_in[16];
    const float* mom_w1 = (const float*)d_in[17];
    const float* mom_b1 = (const float*)d_in[18];
    const float* mom_w2 = (const float*)d_in[19];
    const float* mom_b2 = (const float*)d_in[20];
    float* out = (float*)d_out;

    // ---- workspace layout (floats), ~193 MiB total
    float* w = (float*)d_ws;
    const size_t NH   = (size_t)NROWS * HDIM;      // 4.19 M
    const size_t NHE  = (size_t)NROWS * HEDIM;     // 16.8 M
    const size_t W1SZ = (size_t)2 * HEDIM * HDIM;  // 2.10 M
    size_t off = 0;
    float* kbuf = w + off; off += NH;    // k (l2normed)
    float* vbuf = w + off; off += NH;    // v -> g1 -> q
    float* x1   = w + off; off += NH;    // layer-0 output (fwd on k, then fwd on q)
    float* E1   = w + off; off += NHE;   // u0 -> u1 -> u0(recomputed) -> u0' -> u1'
    float* E2   = w + off; off += NHE;   // gbuf (L1), gbuf (L0)
    float* gW1  = w + off; off += W1SZ;  // grads, then new params (in-place update)
    float* gW2  = w + off; off += W1SZ;
    float* gb1  = w + off; off += 2 * HEDIM;
    float* gb2  = w + off; off += 2 * HDIM;
    float* cpart= w + off; off += (size_t)64 * HEDIM;
    float* sc   = w + off; off += 16;
    float* lr_s = w + off; off += NROWS;
    float* f_s  = w + off; off += NROWS;
    float* m_s  = w + off; off += NROWS;
    float* g2 = out;                     // d_out doubles as the x2/grad buffer

    const dim3 blk(256);
    const dim3 g_n512 (HDIM  / TS, NROWS / TS);   // (8,128)
    const dim3 g_n2048(HEDIM / TS, NROWS / TS);   // (32,128)
    const dim3 g_w2   (HEDIM / TS, HDIM  / TS);   // (32,8)
    const dim3 g_w1   (HDIM  / TS, HEDIM / TS);   // (8,32)

    //                 AKMAJ BKMAJ SILUA SILUB BIAS  RES   DSILU
    #define GEMM_NT_B   gemm_k<false,false,false,false,true ,false,false>
    #define GEMM_NT_SBR gemm_k<false,false,true ,false,true ,true ,false>
    #define GEMM_TN_SB  gemm_k<true ,true ,false,true ,false,false,false>
    #define GEMM_TN     gemm_k<true ,true ,false,false,false,false,false>
    #define GEMM_NN_DS  gemm_k<false,true ,false,false,false,false,true >
    #define GEMM_NN_R   gemm_k<false,true ,false,false,false,true ,false>

    const float* mw1_1 = mw1 + (size_t)HEDIM * HDIM;
    const float* mb1_1 = mb1 + HEDIM;
    const float* mw2_1 = mw2 + (size_t)HDIM * HEDIM;
    const float* mb2_1 = mb2 + HDIM;

    // ---------- phase 1: k, v, gates ----------
    GEMM_NT_B<<<g_n512, blk, 0, stream>>>(x, wk, bk, nullptr, nullptr, kbuf, NROWS, HDIM, HDIM);
    l2norm_k<<<NROWS, 64, 0, stream>>>(kbuf);
    GEMM_NT_B<<<g_n512, blk, 0, stream>>>(x, wv, bv, nullptr, nullptr, vbuf, NROWS, HDIM, HDIM);
    gates_k<<<NROWS, 64, 0, stream>>>(x, wlr, blr, wf, bfp, wm, bm, lr_s, f_s, m_s);

    // ---------- phase 2: memory forward on k ----------
    GEMM_NT_B  <<<g_n2048, blk, 0, stream>>>(kbuf, mw1, mb1, nullptr, nullptr, E1, NROWS, HEDIM, HDIM);        // u0
    GEMM_NT_SBR<<<g_n512 , blk, 0, stream>>>(E1, mw2, mb2, kbuf, nullptr, x1, NROWS, HDIM, HEDIM);             // x1
    GEMM_NT_B  <<<g_n2048, blk, 0, stream>>>(x1, mw1_1, mb1_1, nullptr, nullptr, E1, NROWS, HEDIM, HDIM);      // u1
    GEMM_NT_SBR<<<g_n512 , blk, 0, stream>>>(E1, mw2_1, mb2_1, x1, nullptr, g2, NROWS, HDIM, HEDIM);           // x2
    dpred_k<<<NH/4/256, blk, 0, stream>>>(g2, vbuf, lr_s);                                                     // g2

    // ---------- backward layer 1 (E1 = u1) ----------
    colsum_part_k<<<dim3(HDIM/64, 64), 64, 0, stream>>>(g2, cpart, HDIM);
    colsum_fin_k <<<dim3(HDIM/256), blk, 0, stream>>>(cpart, gb2 + HDIM, HDIM);
    GEMM_TN_SB<<<g_w2, blk, 0, stream>>>(g2, E1, nullptr, nullptr, nullptr, gW2 + (size_t)HDIM*HEDIM, HDIM, HEDIM, NROWS);
    GEMM_NN_DS<<<g_n2048, blk, 0, stream>>>(g2, mw2_1, nullptr, nullptr, E1, E2, NROWS, HEDIM, HDIM);          // gbuf1
    colsum_part_k<<<dim3(HEDIM/64, 64), 64, 0, stream>>>(E2, cpart, HEDIM);
    colsum_fin_k <<<dim3(HEDIM/256), blk, 0, stream>>>(cpart, gb1 + HEDIM, HEDIM);
    GEMM_TN  <<<g_w1, blk, 0, stream>>>(E2, x1, nullptr, nullptr, nullptr, gW1 + (size_t)HEDIM*HDIM, HEDIM, HDIM, NROWS);
    GEMM_NN_R<<<g_n512, blk, 0, stream>>>(E2, mw1_1, nullptr, g2, nullptr, vbuf, NROWS, HDIM, HEDIM);          // g1 (over v)

    // ---------- backward layer 0 (recompute u0 into E1) ----------
    colsum_part_k<<<dim3(HDIM/64, 64), 64, 0, stream>>>(vbuf, cpart, HDIM);
    colsum_fin_k <<<dim3(HDIM/256), blk, 0, stream>>>(cpart, gb2, HDIM);
    GEMM_NT_B <<<g_n2048, blk, 0, stream>>>(kbuf, mw1, mb1, nullptr, nullptr, E1, NROWS, HEDIM, HDIM);         // u0 again
    GEMM_TN_SB<<<g_w2, blk, 0, stream>>>(vbuf, E1, nullptr, nullptr, nullptr, gW2, HDIM, HEDIM, NROWS);
    GEMM_NN_DS<<<g_n2048, blk, 0, stream>>>(vbuf, mw2, nullptr, nullptr, E1, E2, NROWS, HEDIM, HDIM);          // gbuf0
    colsum_part_k<<<dim3(HEDIM/64, 64), 64, 0, stream>>>(E2, cpart, HEDIM);
    colsum_fin_k <<<dim3(HEDIM/256), blk, 0, stream>>>(cpart, gb1, HEDIM);
    GEMM_TN<<<g_w1, blk, 0, stream>>>(E2, kbuf, nullptr, nullptr, nullptr, gW1, HEDIM, HDIM, NROWS);

    // ---------- phase 3: scalar gates + in-place param update ----------
    scalars_k<<<1, blk, 0, stream>>>(lr_s, f_s, m_s, sc);
    update_k<<<dim3((unsigned)(W1SZ/256)), blk, 0, stream>>>(mw1, gW1, mom_w1, sc, gW1, (int)W1SZ);
    update_k<<<dim3((unsigned)(W1SZ/256)), blk, 0, stream>>>(mw2, gW2, mom_w2, sc, gW2, (int)W1SZ);
    update_k<<<dim3(2*HEDIM/256), blk, 0, stream>>>(mb1, gb1, mom_b1, sc, gb1, 2*HEDIM);
    update_k<<<dim3((2*HDIM+255)/256), blk, 0, stream>>>(mb2, gb2, mom_b2, sc, gb2, 2*HDIM);

    // ---------- phase 4: q projection + memory forward with new params ----------
    GEMM_NT_B<<<g_n512, blk, 0, stream>>>(x, wq, bq, nullptr, nullptr, vbuf, NROWS, HDIM, HDIM);               // q
    l2norm_k<<<NROWS, 64, 0, stream>>>(vbuf);
    GEMM_NT_B  <<<g_n2048, blk, 0, stream>>>(vbuf, gW1, gb1, nullptr, nullptr, E1, NROWS, HEDIM, HDIM);        // u0'
    GEMM_NT_SBR<<<g_n512 , blk, 0, stream>>>(E1, gW2, gb2, vbuf, nullptr, x1, NROWS, HDIM, HEDIM);             // x1'
    GEMM_NT_B  <<<g_n2048, blk, 0, stream>>>(x1, gW1 + (size_t)HEDIM*HDIM, gb1 + HEDIM, nullptr, nullptr, E1, NROWS, HEDIM, HDIM); // u1'
    GEMM_NT_SBR<<<g_n512 , blk, 0, stream>>>(E1, gW2 + (size_t)HDIM*HEDIM, gb2 + HDIM, x1, nullptr, out, NROWS, HDIM, HEDIM);      // out

    #undef GEMM_NT_B
    #undef GEMM_NT_SBR
    #undef GEMM_TN_SB
    #undef GEMM_TN
    #undef GEMM_NN_DS
    #undef GEMM_NN_R
    (void)in_sizes; (void)n_in; (void)out_size; (void)ws_size;
}

// Round 3
// 1700.386 us; speedup vs baseline: 3.1277x; 3.1277x over previous
//
#include <hip/hip_runtime.h>
#include <cstdint>
#include <cstddef>

// NeuralMemory — bf16 MFMA GEMMs (fp32 accum, fp32 buffers, cvt at staging).
// Same dataflow as round-2: grads over all 8192 rows scaled by lr*2/(H*C);
// gate scalars are global means; g2 lives in d_out; u0 recomputed; TN weight
// grads use split-K x4 with partials in dead activation buffers.

#define NROWS 8192
#define HDIM  512
#define HEDIM 2048
#define NCHUNK 8
#define LDST  40   // LDS row stride in ushorts (32 data + 8 pad -> 80B rows)

typedef __attribute__((ext_vector_type(8))) short bf16x8;
typedef __attribute__((ext_vector_type(4))) float f32x4;

__device__ __forceinline__ float sigmoidf_(float x){ return 1.0f/(1.0f+__expf(-x)); }
__device__ __forceinline__ float siluf_(float x){ return x*sigmoidf_(x); }
__device__ __forceinline__ float dsiluf_(float x){ float s=sigmoidf_(x); return s*(1.0f+x*(1.0f-s)); }

// pack two fp32 -> (bf16(a) | bf16(b)<<16), round-to-nearest-even
__device__ __forceinline__ unsigned bfpack_(float a, float b){
    union{float f; unsigned u;} ua, ub; ua.f = a; ub.f = b;
    unsigned ra = (ua.u + 0x7fffu + ((ua.u>>16)&1u)) >> 16;
    unsigned rb = (ub.u + 0x7fffu + ((ub.u>>16)&1u)) & 0xffff0000u;
    return ra | rb;
}

// C[m,n] = sum_k A'[m,k]*B'[k,n] (+bias) (+res) (*dsilu(aux))
// ATR: A stored [K,M] (lda=M) else [M,K] (lda=K)
// BTR: B stored [K,N] (ldb=N) else [N,K] (ldb=K)
// SPLITK: grid.z=4, each writes partial C + z*M*N over K/4 slice
template<bool ATR,bool BTR,bool SILUA,bool SILUB,bool BIASF,bool RESF,bool DSILF,bool SPLITK>
__global__ __launch_bounds__(256)
void mgemm_k(const float* __restrict__ A, const float* __restrict__ B,
             const float* __restrict__ bias, const float* __restrict__ res,
             const float* __restrict__ aux, float* __restrict__ C,
             int M, int N, int K, int lda, int ldb)
{
    __shared__ ushort As[128*LDST];
    __shared__ ushort Bs[128*LDST];
    const int tid = threadIdx.x;
    const int lane = tid & 63, wv = tid >> 6;
    const int wm = wv >> 1, wn = wv & 1;
    const int lr = lane & 15, lq = lane >> 4;
    const int m0 = blockIdx.y * 128, n0 = blockIdx.x * 128;
    int kbeg = 0, kend = K;
    if (SPLITK){ const int ks = K >> 2; kbeg = blockIdx.z * ks; kend = kbeg + ks; }

    f32x4 acc[4][4];
    const f32x4 zz = {0.f, 0.f, 0.f, 0.f};
    #pragma unroll
    for (int i = 0; i < 4; ++i)
        #pragma unroll
        for (int j = 0; j < 4; ++j) acc[i][j] = zz;

    for (int k0 = kbeg; k0 < kend; k0 += 32) {
        // ---------- stage A tile -> As[m 0..127][k 0..31]
        if (!ATR) {
            const int r = tid >> 1, kc = (tid & 1) << 4;
            const float* s = A + (size_t)(m0 + r) * lda + k0 + kc;
            float4 f0 = *(const float4*)s,     f1 = *(const float4*)(s+4),
                   f2 = *(const float4*)(s+8), f3 = *(const float4*)(s+12);
            if (SILUA){
                f0.x=siluf_(f0.x); f0.y=siluf_(f0.y); f0.z=siluf_(f0.z); f0.w=siluf_(f0.w);
                f1.x=siluf_(f1.x); f1.y=siluf_(f1.y); f1.z=siluf_(f1.z); f1.w=siluf_(f1.w);
                f2.x=siluf_(f2.x); f2.y=siluf_(f2.y); f2.z=siluf_(f2.z); f2.w=siluf_(f2.w);
                f3.x=siluf_(f3.x); f3.y=siluf_(f3.y); f3.z=siluf_(f3.z); f3.w=siluf_(f3.w);
            }
            uint4 w0, w1;
            w0.x=bfpack_(f0.x,f0.y); w0.y=bfpack_(f0.z,f0.w);
            w0.z=bfpack_(f1.x,f1.y); w0.w=bfpack_(f1.z,f1.w);
            w1.x=bfpack_(f2.x,f2.y); w1.y=bfpack_(f2.z,f2.w);
            w1.z=bfpack_(f3.x,f3.y); w1.w=bfpack_(f3.z,f3.w);
            *(uint4*)&As[r*LDST + kc]     = w0;
            *(uint4*)&As[r*LDST + kc + 8] = w1;
        } else {
            const int kp = tid >> 4, c = (tid & 15) << 3;
            const float* s0 = A + (size_t)(k0 + 2*kp) * lda + m0 + c;
            const float* s1 = s0 + lda;
            float4 a0 = *(const float4*)s0, a1 = *(const float4*)(s0+4);
            float4 b0 = *(const float4*)s1, b1 = *(const float4*)(s1+4);
            if (SILUA){
                a0.x=siluf_(a0.x); a0.y=siluf_(a0.y); a0.z=siluf_(a0.z); a0.w=siluf_(a0.w);
                a1.x=siluf_(a1.x); a1.y=siluf_(a1.y); a1.z=siluf_(a1.z); a1.w=siluf_(a1.w);
                b0.x=siluf_(b0.x); b0.y=siluf_(b0.y); b0.z=siluf_(b0.z); b0.w=siluf_(b0.w);
                b1.x=siluf_(b1.x); b1.y=siluf_(b1.y); b1.z=siluf_(b1.z); b1.w=siluf_(b1.w);
            }
            *(unsigned*)&As[(c+0)*LDST + 2*kp] = bfpack_(a0.x, b0.x);
            *(unsigned*)&As[(c+1)*LDST + 2*kp] = bfpack_(a0.y, b0.y);
            *(unsigned*)&As[(c+2)*LDST + 2*kp] = bfpack_(a0.z, b0.z);
            *(unsigned*)&As[(c+3)*LDST + 2*kp] = bfpack_(a0.w, b0.w);
            *(unsigned*)&As[(c+4)*LDST + 2*kp] = bfpack_(a1.x, b1.x);
            *(unsigned*)&As[(c+5)*LDST + 2*kp] = bfpack_(a1.y, b1.y);
            *(unsigned*)&As[(c+6)*LDST + 2*kp] = bfpack_(a1.z, b1.z);
            *(unsigned*)&As[(c+7)*LDST + 2*kp] = bfpack_(a1.w, b1.w);
        }
        // ---------- stage B tile -> Bs[n 0..127][k 0..31]
        if (!BTR) {
            const int r = tid >> 1, kc = (tid & 1) << 4;
            const float* s = B + (size_t)(n0 + r) * ldb + k0 + kc;
            float4 f0 = *(const float4*)s,     f1 = *(const float4*)(s+4),
                   f2 = *(const float4*)(s+8), f3 = *(const float4*)(s+12);
            if (SILUB){
                f0.x=siluf_(f0.x); f0.y=siluf_(f0.y); f0.z=siluf_(f0.z); f0.w=siluf_(f0.w);
                f1.x=siluf_(f1.x); f1.y=siluf_(f1.y); f1.z=siluf_(f1.z); f1.w=siluf_(f1.w);
                f2.x=siluf_(f2.x); f2.y=siluf_(f2.y); f2.z=siluf_(f2.z); f2.w=siluf_(f2.w);
                f3.x=siluf_(f3.x); f3.y=siluf_(f3.y); f3.z=siluf_(f3.z); f3.w=siluf_(f3.w);
            }
            uint4 w0, w1;
            w0.x=bfpack_(f0.x,f0.y); w0.y=bfpack_(f0.z,f0.w);
            w0.z=bfpack_(f1.x,f1.y); w0.w=bfpack_(f1.z,f1.w);
            w1.x=bfpack_(f2.x,f2.y); w1.y=bfpack_(f2.z,f2.w);
            w1.z=bfpack_(f3.x,f3.y); w1.w=bfpack_(f3.z,f3.w);
            *(uint4*)&Bs[r*LDST + kc]     = w0;
            *(uint4*)&Bs[r*LDST + kc + 8] = w1;
        } else {
            const int kp = tid >> 4, c = (tid & 15) << 3;
            const float* s0 = B + (size_t)(k0 + 2*kp) * ldb + n0 + c;
            const float* s1 = s0 + ldb;
            float4 a0 = *(const float4*)s0, a1 = *(const float4*)(s0+4);
            float4 b0 = *(const float4*)s1, b1 = *(const float4*)(s1+4);
            if (SILUB){
                a0.x=siluf_(a0.x); a0.y=siluf_(a0.y); a0.z=siluf_(a0.z); a0.w=siluf_(a0.w);
                a1.x=siluf_(a1.x); a1.y=siluf_(a1.y); a1.z=siluf_(a1.z); a1.w=siluf_(a1.w);
                b0.x=siluf_(b0.x); b0.y=siluf_(b0.y); b0.z=siluf_(b0.z); b0.w=siluf_(b0.w);
                b1.x=siluf_(b1.x); b1.y=siluf_(b1.y); b1.z=siluf_(b1.z); b1.w=siluf_(b1.w);
            }
            *(unsigned*)&Bs[(c+0)*LDST + 2*kp] = bfpack_(a0.x, b0.x);
            *(unsigned*)&Bs[(c+1)*LDST + 2*kp] = bfpack_(a0.y, b0.y);
            *(unsigned*)&Bs[(c+2)*LDST + 2*kp] = bfpack_(a0.z, b0.z);
            *(unsigned*)&Bs[(c+3)*LDST + 2*kp] = bfpack_(a0.w, b0.w);
            *(unsigned*)&Bs[(c+4)*LDST + 2*kp] = bfpack_(a1.x, b1.x);
            *(unsigned*)&Bs[(c+5)*LDST + 2*kp] = bfpack_(a1.y, b1.y);
            *(unsigned*)&Bs[(c+6)*LDST + 2*kp] = bfpack_(a1.z, b1.z);
            *(unsigned*)&Bs[(c+7)*LDST + 2*kp] = bfpack_(a1.w, b1.w);
        }
        __syncthreads();
        bf16x8 afr[4], bfr[4];
        #pragma unroll
        for (int i = 0; i < 4; ++i){
            afr[i] = *(const bf16x8*)&As[(wm*64 + i*16 + lr)*LDST + lq*8];
            bfr[i] = *(const bf16x8*)&Bs[(wn*64 + i*16 + lr)*LDST + lq*8];
        }
        #pragma unroll
        for (int mi = 0; mi < 4; ++mi)
            #pragma unroll
            for (int ni = 0; ni < 4; ++ni)
                acc[mi][ni] = __builtin_amdgcn_mfma_f32_16x16x32_bf16(afr[mi], bfr[ni], acc[mi][ni], 0, 0, 0);
        __syncthreads();
    }

    float* Co = C + (SPLITK ? (size_t)blockIdx.z * M * N : (size_t)0);
    #pragma unroll
    for (int ni = 0; ni < 4; ++ni){
        const int col = n0 + wn*64 + ni*16 + lr;
        const float bv = BIASF ? bias[col] : 0.0f;
        #pragma unroll
        for (int mi = 0; mi < 4; ++mi){
            const int rbase = m0 + wm*64 + mi*16 + lq*4;
            #pragma unroll
            for (int v = 0; v < 4; ++v){
                const size_t idx = (size_t)(rbase + v) * N + col;
                float o = acc[mi][ni][v] + bv;
                if (RESF)  o += res[idx];
                if (DSILF) o *= dsiluf_(aux[idx]);
                Co[idx] = o;
            }
        }
    }
}

// out[i] = p[0*n+i] + p[1*n+i] + p[2*n+i] + p[3*n+i]
__global__ __launch_bounds__(256)
void reduce4_k(const float* __restrict__ p, float* __restrict__ o, int n)
{
    const int i = blockIdx.x * 256 + threadIdx.x;
    if (i < n) o[i] = p[i] + p[(size_t)n + i] + p[(size_t)2*n + i] + p[(size_t)3*n + i];
}

__global__ __launch_bounds__(64)
void l2norm_k(float* __restrict__ x)
{
    float* p = x + (size_t)blockIdx.x * HDIM;
    const int t = threadIdx.x;
    float4 v0 = *(const float4*)(p + t*8), v1 = *(const float4*)(p + t*8 + 4);
    float s = v0.x*v0.x+v0.y*v0.y+v0.z*v0.z+v0.w*v0.w
            + v1.x*v1.x+v1.y*v1.y+v1.z*v1.z+v1.w*v1.w;
    #pragma unroll
    for (int o = 1; o < 64; o <<= 1) s += __shfl_xor(s, o);
    const float sc = 1.0f / fmaxf(sqrtf(s), 1e-12f);
    v0.x*=sc; v0.y*=sc; v0.z*=sc; v0.w*=sc;
    v1.x*=sc; v1.y*=sc; v1.z*=sc; v1.w*=sc;
    *(float4*)(p + t*8) = v0; *(float4*)(p + t*8 + 4) = v1;
}

__global__ __launch_bounds__(64)
void gates_k(const float* __restrict__ x,
             const float* __restrict__ wlr, const float* __restrict__ blr,
             const float* __restrict__ wf,  const float* __restrict__ bfp,
             const float* __restrict__ wm,  const float* __restrict__ bm,
             float* __restrict__ lr_s, float* __restrict__ f_s, float* __restrict__ m_s)
{
    const size_t row = blockIdx.x;
    const float* p = x + row * HDIM;
    const int t = threadIdx.x;
    float s0 = 0.f, s1 = 0.f, s2 = 0.f;
    #pragma unroll
    for (int i = 0; i < 8; i += 4){
        float4 xv = *(const float4*)(p   + t*8 + i);
        float4 a  = *(const float4*)(wlr + t*8 + i);
        float4 b  = *(const float4*)(wf  + t*8 + i);
        float4 c  = *(const float4*)(wm  + t*8 + i);
        s0 += xv.x*a.x + xv.y*a.y + xv.z*a.z + xv.w*a.w;
        s1 += xv.x*b.x + xv.y*b.y + xv.z*b.z + xv.w*b.w;
        s2 += xv.x*c.x + xv.y*c.y + xv.z*c.z + xv.w*c.w;
    }
    #pragma unroll
    for (int o = 1; o < 64; o <<= 1){
        s0 += __shfl_xor(s0, o); s1 += __shfl_xor(s1, o); s2 += __shfl_xor(s2, o);
    }
    if (t == 0){
        lr_s[row] = sigmoidf_(s0 + blr[0]) * 0.1f;
        f_s[row]  = sigmoidf_(s1 + bfp[0]);
        m_s[row]  = sigmoidf_(s2 + bm[0]);
    }
}

__global__ __launch_bounds__(256)
void dpred_k(float* __restrict__ g2, const float* __restrict__ v, const float* __restrict__ lr_s)
{
    const size_t i4 = (size_t)blockIdx.x * 256 + threadIdx.x;
    const size_t row = i4 >> 7;
    const float coef = lr_s[row] * (2.0f / (HDIM * NCHUNK));
    float4 a = *(const float4*)(g2 + (i4<<2));
    float4 b = *(const float4*)(v  + (i4<<2));
    a.x = coef*(a.x-b.x); a.y = coef*(a.y-b.y);
    a.z = coef*(a.z-b.z); a.w = coef*(a.w-b.w);
    *(float4*)(g2 + (i4<<2)) = a;
}

__global__ __launch_bounds__(64)
void colsum_part_k(const float* __restrict__ g, float* __restrict__ part, int cols)
{
    const int c = blockIdx.x * 64 + threadIdx.x;
    const int rc = blockIdx.y;
    const float* p = g + (size_t)rc * 128 * cols + c;
    float s = 0.f;
    for (int r = 0; r < 128; ++r) s += p[(size_t)r * cols];
    part[(size_t)rc * cols + c] = s;
}
__global__ __launch_bounds__(256)
void colsum_fin_k(const float* __restrict__ part, float* __restrict__ out, int cols)
{
    const int c = blockIdx.x * 256 + threadIdx.x;
    if (c < cols){
        float s = 0.f;
        for (int r = 0; r < 64; ++r) s += part[(size_t)r * cols + c];
        out[c] = s;
    }
}

__global__ __launch_bounds__(256)
void scalars_k(const float* __restrict__ lr_s, const float* __restrict__ f_s,
               const float* __restrict__ m_s, float* __restrict__ sc)
{
    __shared__ float sh0[256], sh1[256], sh2[256];
    const int t = threadIdx.x;
    float s0 = 0.f, s1 = 0.f, s2 = 0.f;
    for (int i = t; i < NROWS; i += 256){ s0 += f_s[i]; s1 += lr_s[i]; s2 += m_s[i]; }
    sh0[t] = s0; sh1[t] = s1; sh2[t] = s2;
    __syncthreads();
    for (int o = 128; o > 0; o >>= 1){
        if (t < o){ sh0[t] += sh0[t+o]; sh1[t] += sh1[t+o]; sh2[t] += sh2[t+o]; }
        __syncthreads();
    }
    if (t == 0){
        sc[0] = sh0[0] / (float)NROWS;
        sc[1] = sh1[0] / (float)NROWS;
        sc[2] = sh2[0] / (float)NROWS;
    }
}

__global__ __launch_bounds__(256)
void update_k(const float* __restrict__ p, const float* __restrict__ g,
              const float* __restrict__ mom, const float* __restrict__ sc,
              float* __restrict__ np_, int n)
{
    const int i = blockIdx.x * 256 + threadIdx.x;
    if (i < n) np_[i] = p[i] * (1.0f - sc[0]) + sc[2] * mom[i] - sc[1] * g[i];
}

extern "C" void kernel_launch(void* const* d_in, const int* in_sizes, int n_in,
                              void* d_out, int out_size, void* d_ws, size_t ws_size,
                              hipStream_t stream)
{
    const float* x      = (const float*)d_in[0];
    const float* wq     = (const float*)d_in[1];
    const float* bq     = (const float*)d_in[2];
    const float* wk     = (const float*)d_in[3];
    const float* bk     = (const float*)d_in[4];
    const float* wv     = (const float*)d_in[5];
    const float* bv     = (const float*)d_in[6];
    const float* wlr    = (const float*)d_in[7];
    const float* blr    = (const float*)d_in[8];
    const float* wf     = (const float*)d_in[9];
    const float* bfp    = (const float*)d_in[10];
    const float* wm     = (const float*)d_in[11];
    const float* bm     = (const float*)d_in[12];
    const float* mw1    = (const float*)d_in[13];
    const float* mb1    = (const float*)d_in[14];
    const float* mw2    = (const float*)d_in[15];
    const float* mb2    = (const float*)d_in[16];
    const float* mom_w1 = (const float*)d_in[17];
    const float* mom_b1 = (const float*)d_in[18];
    const float* mom_w2 = (const float*)d_in[19];
    const float* mom_b2 = (const float*)d_in[20];
    float* out = (float*)d_out;

    float* w = (float*)d_ws;
    const size_t NH   = (size_t)NROWS * HDIM;
    const size_t NHE  = (size_t)NROWS * HEDIM;
    const size_t W1SZ = (size_t)2 * HEDIM * HDIM;
    const int    WHALF = HEDIM * HDIM;            // 1,048,576
    size_t off = 0;
    float* kbuf = w + off; off += NH;
    float* vbuf = w + off; off += NH;   // v -> TN partials -> g1 -> q
    float* x1   = w + off; off += NH;   // x1 -> TN partials (L0) -> x1'
    float* E1   = w + off; off += NHE;  // u0 -> u1 -> u0(recomp) -> u0'/u1'
    float* E2   = w + off; off += NHE;  // dh1 -> dh0
    float* gW1  = w + off; off += W1SZ; // grads then new params (in-place)
    float* gW2  = w + off; off += W1SZ;
    float* gb1  = w + off; off += 2 * HEDIM;
    float* gb2  = w + off; off += 2 * HDIM;
    float* cpart= w + off; off += (size_t)64 * HEDIM;
    float* sc   = w + off; off += 16;
    float* lr_s = w + off; off += NROWS;
    float* f_s  = w + off; off += NROWS;
    float* m_s  = w + off; off += NROWS;
    float* g2 = out;

    const dim3 blk(256);
    const dim3 gNT512 (HDIM/128,  NROWS/128);      // (4,64)
    const dim3 gNT2048(HEDIM/128, NROWS/128);      // (16,64)
    const dim3 gW2g   (HEDIM/128, HDIM/128, 4);    // (16,4,4) split-K
    const dim3 gW1g   (HDIM/128,  HEDIM/128, 4);   // (4,16,4) split-K

    //                ATR  BTR  SILUA SILUB BIAS  RES   DSIL  SPLITK
    #define MG_NT_B   mgemm_k<false,false,false,false,true ,false,false,false>
    #define MG_NT_SBR mgemm_k<false,false,true ,false,true ,true ,false,false>
    #define MG_TN_SB  mgemm_k<true ,true ,false,true ,false,false,false,true >
    #define MG_TN     mgemm_k<true ,true ,false,false,false,false,false,true >
    #define MG_NN_DS  mgemm_k<false,true ,false,false,false,false,true ,false>
    #define MG_NN_R   mgemm_k<false,true ,false,false,false,true ,false,false>

    const float* mw1_1 = mw1 + (size_t)HEDIM * HDIM;
    const float* mb1_1 = mb1 + HEDIM;
    const float* mw2_1 = mw2 + (size_t)HDIM * HEDIM;
    const float* mb2_1 = mb2 + HDIM;

    // ---------- phase 1: k, v, gates ----------
    MG_NT_B<<<gNT512, blk, 0, stream>>>(x, wk, bk, nullptr, nullptr, kbuf, NROWS, HDIM, HDIM, HDIM, HDIM);
    l2norm_k<<<NROWS, 64, 0, stream>>>(kbuf);
    MG_NT_B<<<gNT512, blk, 0, stream>>>(x, wv, bv, nullptr, nullptr, vbuf, NROWS, HDIM, HDIM, HDIM, HDIM);
    gates_k<<<NROWS, 64, 0, stream>>>(x, wlr, blr, wf, bfp, wm, bm, lr_s, f_s, m_s);

    // ---------- phase 2: memory forward on k ----------
    MG_NT_B  <<<gNT2048, blk, 0, stream>>>(kbuf, mw1, mb1, nullptr, nullptr, E1, NROWS, HEDIM, HDIM, HDIM, HDIM);          // u0
    MG_NT_SBR<<<gNT512 , blk, 0, stream>>>(E1, mw2, mb2, kbuf, nullptr, x1, NROWS, HDIM, HEDIM, HEDIM, HEDIM);             // x1
    MG_NT_B  <<<gNT2048, blk, 0, stream>>>(x1, mw1_1, mb1_1, nullptr, nullptr, E1, NROWS, HEDIM, HDIM, HDIM, HDIM);        // u1
    MG_NT_SBR<<<gNT512 , blk, 0, stream>>>(E1, mw2_1, mb2_1, x1, nullptr, g2, NROWS, HDIM, HEDIM, HEDIM, HEDIM);           // x2
    dpred_k<<<NH/4/256, blk, 0, stream>>>(g2, vbuf, lr_s);                                                                 // g2

    // ---------- backward layer 1 (E1 = u1) ----------
    colsum_part_k<<<dim3(HDIM/64, 64), 64, 0, stream>>>(g2, cpart, HDIM);
    colsum_fin_k <<<dim3(HDIM/256), blk, 0, stream>>>(cpart, gb2 + HDIM, HDIM);
    MG_TN_SB<<<gW2g, blk, 0, stream>>>(g2, E1, nullptr, nullptr, nullptr, vbuf, HDIM, HEDIM, NROWS, HDIM, HEDIM);          // gW2_1 partials
    reduce4_k<<<WHALF/256, blk, 0, stream>>>(vbuf, gW2 + (size_t)HDIM*HEDIM, WHALF);
    MG_NN_DS<<<gNT2048, blk, 0, stream>>>(g2, mw2_1, nullptr, nullptr, E1, E2, NROWS, HEDIM, HDIM, HDIM, HEDIM);           // dh1
    colsum_part_k<<<dim3(HEDIM/64, 64), 64, 0, stream>>>(E2, cpart, HEDIM);
    colsum_fin_k <<<dim3(HEDIM/256), blk, 0, stream>>>(cpart, gb1 + HEDIM, HEDIM);
    MG_TN<<<gW1g, blk, 0, stream>>>(E2, x1, nullptr, nullptr, nullptr, vbuf, HEDIM, HDIM, NROWS, HEDIM, HDIM);             // gW1_1 partials
    reduce4_k<<<WHALF/256, blk, 0, stream>>>(vbuf, gW1 + (size_t)HEDIM*HDIM, WHALF);
    MG_NN_R<<<gNT512, blk, 0, stream>>>(E2, mw1_1, nullptr, g2, nullptr, vbuf, NROWS, HDIM, HEDIM, HEDIM, HDIM);           // g1 -> vbuf

    // ---------- backward layer 0 (recompute u0 into E1) ----------
    colsum_part_k<<<dim3(HDIM/64, 64), 64, 0, stream>>>(vbuf, cpart, HDIM);
    colsum_fin_k <<<dim3(HDIM/256), blk, 0, stream>>>(cpart, gb2, HDIM);
    MG_NT_B<<<gNT2048, blk, 0, stream>>>(kbuf, mw1, mb1, nullptr, nullptr, E1, NROWS, HEDIM, HDIM, HDIM, HDIM);            // u0 again
    MG_TN_SB<<<gW2g, blk, 0, stream>>>(vbuf, E1, nullptr, nullptr, nullptr, x1, HDIM, HEDIM, NROWS, HDIM, HEDIM);          // gW2_0 partials
    reduce4_k<<<WHALF/256, blk, 0, stream>>>(x1, gW2, WHALF);
    MG_NN_DS<<<gNT2048, blk, 0, stream>>>(vbuf, mw2, nullptr, nullptr, E1, E2, NROWS, HEDIM, HDIM, HDIM, HEDIM);           // dh0
    colsum_part_k<<<dim3(HEDIM/64, 64), 64, 0, stream>>>(E2, cpart, HEDIM);
    colsum_fin_k <<<dim3(HEDIM/256), blk, 0, stream>>>(cpart, gb1, HEDIM);
    MG_TN<<<gW1g, blk, 0, stream>>>(E2, kbuf, nullptr, nullptr, nullptr, x1, HEDIM, HDIM, NROWS, HEDIM, HDIM);             // gW1_0 partials
    reduce4_k<<<WHALF/256, blk, 0, stream>>>(x1, gW1, WHALF);

    // ---------- phase 3: scalar gates + in-place param update ----------
    scalars_k<<<1, blk, 0, stream>>>(lr_s, f_s, m_s, sc);
    update_k<<<dim3((unsigned)(W1SZ/256)), blk, 0, stream>>>(mw1, gW1, mom_w1, sc, gW1, (int)W1SZ);
    update_k<<<dim3((unsigned)(W1SZ/256)), blk, 0, stream>>>(mw2, gW2, mom_w2, sc, gW2, (int)W1SZ);
    update_k<<<dim3(2*HEDIM/256), blk, 0, stream>>>(mb1, gb1, mom_b1, sc, gb1, 2*HEDIM);
    update_k<<<dim3((2*HDIM+255)/256), blk, 0, stream>>>(mb2, gb2, mom_b2, sc, gb2, 2*HDIM);

    // ---------- phase 4: q projection + forward with new params ----------
    MG_NT_B<<<gNT512, blk, 0, stream>>>(x, wq, bq, nullptr, nullptr, vbuf, NROWS, HDIM, HDIM, HDIM, HDIM);                 // q
    l2norm_k<<<NROWS, 64, 0, stream>>>(vbuf);
    MG_NT_B  <<<gNT2048, blk, 0, stream>>>(vbuf, gW1, gb1, nullptr, nullptr, E1, NROWS, HEDIM, HDIM, HDIM, HDIM);          // u0'
    MG_NT_SBR<<<gNT512 , blk, 0, stream>>>(E1, gW2, gb2, vbuf, nullptr, x1, NROWS, HDIM, HEDIM, HEDIM, HEDIM);             // x1'
    MG_NT_B  <<<gNT2048, blk, 0, stream>>>(x1, gW1 + (size_t)HEDIM*HDIM, gb1 + HEDIM, nullptr, nullptr, E1, NROWS, HEDIM, HDIM, HDIM, HDIM); // u1'
    MG_NT_SBR<<<gNT512 , blk, 0, stream>>>(E1, gW2 + (size_t)HDIM*HEDIM, gb2 + HDIM, x1, nullptr, out, NROWS, HDIM, HEDIM, HEDIM, HEDIM);    // out

    #undef MG_NT_B
    #undef MG_NT_SBR
    #undef MG_TN_SB
    #undef MG_TN
    #undef MG_NN_DS
    #undef MG_NN_R
    (void)in_sizes; (void)n_in; (void)out_size; (void)ws_size;
}

// Round 4
// 1129.857 us; speedup vs baseline: 4.7071x; 1.5050x over previous
//
#include <hip/hip_runtime.h>
#include <cstdint>
#include <cstddef>

// NeuralMemory — bf16-operand MFMA GEMMs, BK=64, padded LDS, fused epilogues.
// All GEMM operands are pre-converted bf16 buffers (staging = pure ushort copy).
// NN GEMMs NT-ified via pre-transposed bf16 weights; TN (K=8192) weight-grads
// keep transpose staging from bf16. q-forward residual chain stays fp32.

#define NROWS 8192
#define HDIM  512
#define HEDIM 2048
#define NCHUNK 8
#define BK    64
#define LDST  72   // LDS row stride in ushorts (64 data + 8 pad -> 144B rows)
#define DPCOEF (2.0f / (HDIM * NCHUNK))

typedef unsigned short u16;
typedef __attribute__((ext_vector_type(8))) unsigned short u16x8;
typedef __attribute__((ext_vector_type(8))) short bf16x8;
typedef __attribute__((ext_vector_type(4))) float f32x4;

__device__ __forceinline__ float sigmoidf_(float x){ return 1.0f/(1.0f+__expf(-x)); }
__device__ __forceinline__ float siluf_(float x){ return x*sigmoidf_(x); }
__device__ __forceinline__ float dsiluf_(float x){ float s=sigmoidf_(x); return s*(1.0f+x*(1.0f-s)); }
__device__ __forceinline__ u16 bf1_(float x){
    union{float f; unsigned u;} v; v.f = x;
    return (u16)((v.u + 0x7fffu + ((v.u>>16)&1u)) >> 16);
}
__device__ __forceinline__ float bf2f_(u16 h){
    union{unsigned u; float f;} v; v.u = ((unsigned)h) << 16; return v.f;
}

// ---------------------------------------------------------------------------
// Unified bf16 GEMM.  C[m,n] = sum_k A'[m,k] * B'[k,n]  (128x128 tile, BK=64)
// ATR=false: A[M,K] bf16 (lda=K), B[N,K] bf16 (ldb=K)  -- "NT", k-contig
// ATR=true : A[K,M] bf16 (lda=M), B[K,N] bf16 (ldb=N)  -- "TN", transpose-staged
// MODE epilogues:
// 0: outF = acc+bias
// 1: u=acc+bias; outB=bf(silu(u)); outB2=bf(dsilu(u))
// 3: outF[z*M*N+idx] = acc            (split-K x4 partials)
// 4: outB = bf(acc * f(aux))
// 5: outB = bf(acc + resF)
// 6: t=acc+bias+resF; outF=t; outB=bf(t)
// 7: outF = acc+bias+resF
// 8: t=acc+bias+f(resB); g=lrs[row]*DPCOEF*(t-vf); outF=g; outB=bf(g)
// 9: outB = bf(acc+bias+f(resB))
// ---------------------------------------------------------------------------
template<int MODE, bool ATR>
__global__ __launch_bounds__(256)
void mgemm_k(const u16* __restrict__ A, const u16* __restrict__ B,
             const float* __restrict__ bias, const float* __restrict__ resF,
             const u16* __restrict__ resB, const u16* __restrict__ aux,
             const float* __restrict__ vf, const float* __restrict__ lrs,
             float* __restrict__ outF, u16* __restrict__ outB, u16* __restrict__ outB2,
             int M, int N, int K, int lda, int ldb)
{
    __shared__ u16 As[128 * LDST];
    __shared__ u16 Bs[128 * LDST];
    const int tid = threadIdx.x;
    const int lane = tid & 63, wvi = tid >> 6;
    const int wm = wvi >> 1, wn = wvi & 1;
    const int lr = lane & 15, lq = lane >> 4;
    const int m0 = blockIdx.y * 128, n0 = blockIdx.x * 128;

    int kbeg = 0, kend = K;
    if (MODE == 3){ const int ks = K >> 2; kbeg = blockIdx.z * ks; kend = kbeg + ks; }

    f32x4 acc[4][4];
    const f32x4 zz = {0.f,0.f,0.f,0.f};
    #pragma unroll
    for (int i = 0; i < 4; ++i)
        #pragma unroll
        for (int j = 0; j < 4; ++j) acc[i][j] = zz;

    for (int k0 = kbeg; k0 < kend; k0 += BK) {
        if (!ATR) {
            // ---- NT staging: pure vector copies, [row][k] layout
            const int srow = tid >> 1, skc = (tid & 1) << 5;
            {
                const u16* p = A + (size_t)(m0 + srow) * lda + k0 + skc;
                u16x8 v0 = *(const u16x8*)p,      v1 = *(const u16x8*)(p + 8);
                u16x8 v2 = *(const u16x8*)(p+16), v3 = *(const u16x8*)(p + 24);
                u16* d = &As[srow * LDST + skc];
                *(u16x8*)d = v0; *(u16x8*)(d+8) = v1;
                *(u16x8*)(d+16) = v2; *(u16x8*)(d+24) = v3;
            }
            {
                const u16* p = B + (size_t)(n0 + srow) * ldb + k0 + skc;
                u16x8 v0 = *(const u16x8*)p,      v1 = *(const u16x8*)(p + 8);
                u16x8 v2 = *(const u16x8*)(p+16), v3 = *(const u16x8*)(p + 24);
                u16* d = &Bs[srow * LDST + skc];
                *(u16x8*)d = v0; *(u16x8*)(d+8) = v1;
                *(u16x8*)(d+16) = v2; *(u16x8*)(d+24) = v3;
            }
        } else {
            // ---- TN staging: coalesced loads of 2 k-rows, pair-packed b32 LDS writes
            #pragma unroll
            for (int r = 0; r < 2; ++r) {
                const int slot = r * 256 + tid;
                const int mc = slot & 15, kp = slot >> 4;      // kp 0..31
                {
                    const u16* p = A + (size_t)(k0 + 2*kp) * lda + m0 + mc*8;
                    u16x8 e = *(const u16x8*)p;
                    u16x8 o = *(const u16x8*)(p + lda);
                    #pragma unroll
                    for (int j = 0; j < 8; ++j){
                        unsigned wpk = (unsigned)e[j] | ((unsigned)o[j] << 16);
                        *(unsigned*)&As[(mc*8 + j) * LDST + 2*kp] = wpk;
                    }
                }
                {
                    const u16* p = B + (size_t)(k0 + 2*kp) * ldb + n0 + mc*8;
                    u16x8 e = *(const u16x8*)p;
                    u16x8 o = *(const u16x8*)(p + ldb);
                    #pragma unroll
                    for (int j = 0; j < 8; ++j){
                        unsigned wpk = (unsigned)e[j] | ((unsigned)o[j] << 16);
                        *(unsigned*)&Bs[(mc*8 + j) * LDST + 2*kp] = wpk;
                    }
                }
            }
        }
        __syncthreads();
        #pragma unroll
        for (int ks = 0; ks < 2; ++ks) {
            bf16x8 afr[4], bfr[4];
            #pragma unroll
            for (int i = 0; i < 4; ++i){
                afr[i] = *(const bf16x8*)&As[(wm*64 + i*16 + lr) * LDST + ks*32 + lq*8];
                bfr[i] = *(const bf16x8*)&Bs[(wn*64 + i*16 + lr) * LDST + ks*32 + lq*8];
            }
            #pragma unroll
            for (int mi = 0; mi < 4; ++mi)
                #pragma unroll
                for (int ni = 0; ni < 4; ++ni)
                    acc[mi][ni] = __builtin_amdgcn_mfma_f32_16x16x32_bf16(afr[mi], bfr[ni], acc[mi][ni], 0, 0, 0);
        }
        __syncthreads();
    }

    // ---- epilogue
    #pragma unroll
    for (int ni = 0; ni < 4; ++ni){
        const int col = n0 + wn*64 + ni*16 + lr;
        float bv = 0.0f;
        if (MODE==0 || MODE==1 || MODE==6 || MODE==7 || MODE==8 || MODE==9) bv = bias[col];
        #pragma unroll
        for (int mi = 0; mi < 4; ++mi){
            const int rbase = m0 + wm*64 + mi*16 + lq*4;
            #pragma unroll
            for (int v = 0; v < 4; ++v){
                const int row = rbase + v;
                const size_t idx = (size_t)row * N + col;
                const float o = acc[mi][ni][v];
                if (MODE == 0){ outF[idx] = o + bv; }
                else if (MODE == 1){
                    const float u = o + bv;
                    outB[idx]  = bf1_(siluf_(u));
                    outB2[idx] = bf1_(dsiluf_(u));
                }
                else if (MODE == 3){ outF[(size_t)blockIdx.z * M * N + idx] = o; }
                else if (MODE == 4){ outB[idx] = bf1_(o * bf2f_(aux[idx])); }
                else if (MODE == 5){ outB[idx] = bf1_(o + resF[idx]); }
                else if (MODE == 6){ const float t = o + bv + resF[idx]; outF[idx] = t; outB[idx] = bf1_(t); }
                else if (MODE == 7){ outF[idx] = o + bv + resF[idx]; }
                else if (MODE == 8){
                    const float t = o + bv + bf2f_(resB[idx]);
                    const float g = lrs[row] * DPCOEF * (t - vf[idx]);
                    outF[idx] = g; outB[idx] = bf1_(g);
                }
                else if (MODE == 9){ outB[idx] = bf1_(o + bv + bf2f_(resB[idx])); }
            }
        }
    }
}

// fp32 -> bf16 elementwise cvt (n multiple of 8)
__global__ __launch_bounds__(256)
void cvt_k(const float* __restrict__ in, u16* __restrict__ out, int n8)
{
    const int i = blockIdx.x * 256 + threadIdx.x;
    if (i < n8){
        const float4 a = *(const float4*)(in + (size_t)i*8);
        const float4 b = *(const float4*)(in + (size_t)i*8 + 4);
        u16x8 o;
        o[0]=bf1_(a.x); o[1]=bf1_(a.y); o[2]=bf1_(a.z); o[3]=bf1_(a.w);
        o[4]=bf1_(b.x); o[5]=bf1_(b.y); o[6]=bf1_(b.z); o[7]=bf1_(b.w);
        *(u16x8*)(out + (size_t)i*8) = o;
    }
}

// fp32 [R,C] -> bf16 [C,R] transpose-cvt, 32x32 tiles
__global__ __launch_bounds__(256)
void tcvt_k(const float* __restrict__ in, u16* __restrict__ out, int R, int C)
{
    __shared__ float t[32][33];
    const int tx = threadIdx.x & 31, ty = threadIdx.x >> 5;   // ty 0..7
    const int c0 = blockIdx.x * 32, r0 = blockIdx.y * 32;
    #pragma unroll
    for (int j = 0; j < 4; ++j)
        t[ty + 8*j][tx] = in[(size_t)(r0 + ty + 8*j) * C + c0 + tx];
    __syncthreads();
    #pragma unroll
    for (int j = 0; j < 4; ++j)
        out[(size_t)(c0 + ty + 8*j) * R + r0 + tx] = bf1_(t[tx][ty + 8*j]);
}

// row l2norm over HDIM: read fp32, optionally write fp32 (in-place ok), write bf16
template<bool WF32>
__global__ __launch_bounds__(64)
void l2norm_k(const float* __restrict__ in, float* __restrict__ outF, u16* __restrict__ outB)
{
    const float* p = in + (size_t)blockIdx.x * HDIM;
    const int t = threadIdx.x;
    float4 v0 = *(const float4*)(p + t*8), v1 = *(const float4*)(p + t*8 + 4);
    float s = v0.x*v0.x+v0.y*v0.y+v0.z*v0.z+v0.w*v0.w
            + v1.x*v1.x+v1.y*v1.y+v1.z*v1.z+v1.w*v1.w;
    #pragma unroll
    for (int o = 1; o < 64; o <<= 1) s += __shfl_xor(s, o);
    const float sc = 1.0f / fmaxf(sqrtf(s), 1e-12f);
    v0.x*=sc; v0.y*=sc; v0.z*=sc; v0.w*=sc;
    v1.x*=sc; v1.y*=sc; v1.z*=sc; v1.w*=sc;
    if (WF32){
        float* q = outF + (size_t)blockIdx.x * HDIM;
        *(float4*)(q + t*8) = v0; *(float4*)(q + t*8 + 4) = v1;
    }
    u16x8 ob;
    ob[0]=bf1_(v0.x); ob[1]=bf1_(v0.y); ob[2]=bf1_(v0.z); ob[3]=bf1_(v0.w);
    ob[4]=bf1_(v1.x); ob[5]=bf1_(v1.y); ob[6]=bf1_(v1.z); ob[7]=bf1_(v1.w);
    *(u16x8*)(outB + (size_t)blockIdx.x * HDIM + t*8) = ob;
}

__global__ __launch_bounds__(64)
void gates_k(const float* __restrict__ x,
             const float* __restrict__ wlr, const float* __restrict__ blr,
             const float* __restrict__ wf,  const float* __restrict__ bfp,
             const float* __restrict__ wm,  const float* __restrict__ bm,
             float* __restrict__ lr_s, float* __restrict__ f_s, float* __restrict__ m_s)
{
    const size_t row = blockIdx.x;
    const float* p = x + row * HDIM;
    const int t = threadIdx.x;
    float s0 = 0.f, s1 = 0.f, s2 = 0.f;
    #pragma unroll
    for (int i = 0; i < 8; i += 4){
        float4 xv = *(const float4*)(p   + t*8 + i);
        float4 a  = *(const float4*)(wlr + t*8 + i);
        float4 b  = *(const float4*)(wf  + t*8 + i);
        float4 c  = *(const float4*)(wm  + t*8 + i);
        s0 += xv.x*a.x + xv.y*a.y + xv.z*a.z + xv.w*a.w;
        s1 += xv.x*b.x + xv.y*b.y + xv.z*b.z + xv.w*b.w;
        s2 += xv.x*c.x + xv.y*c.y + xv.z*c.z + xv.w*c.w;
    }
    #pragma unroll
    for (int o = 1; o < 64; o <<= 1){
        s0 += __shfl_xor(s0, o); s1 += __shfl_xor(s1, o); s2 += __shfl_xor(s2, o);
    }
    if (t == 0){
        lr_s[row] = sigmoidf_(s0 + blr[0]) * 0.1f;
        f_s[row]  = sigmoidf_(s1 + bfp[0]);
        m_s[row]  = sigmoidf_(s2 + bm[0]);
    }
}

__global__ __launch_bounds__(256)
void scalars_k(const float* __restrict__ lr_s, const float* __restrict__ f_s,
               const float* __restrict__ m_s, float* __restrict__ sc)
{
    __shared__ float sh0[256], sh1[256], sh2[256];
    const int t = threadIdx.x;
    float s0 = 0.f, s1 = 0.f, s2 = 0.f;
    for (int i = t; i < NROWS; i += 256){ s0 += f_s[i]; s1 += lr_s[i]; s2 += m_s[i]; }
    sh0[t] = s0; sh1[t] = s1; sh2[t] = s2;
    __syncthreads();
    for (int o = 128; o > 0; o >>= 1){
        if (t < o){ sh0[t] += sh0[t+o]; sh1[t] += sh1[t+o]; sh2[t] += sh2[t+o]; }
        __syncthreads();
    }
    if (t == 0){
        sc[0] = sh0[0] / (float)NROWS;   // alpha
        sc[1] = sh1[0] / (float)NROWS;   // theta
        sc[2] = sh2[0] / (float)NROWS;   // eta
    }
}

// column partial sums (128-row chunks), input fp32 or bf16
template<typename T>
__global__ __launch_bounds__(64)
void colsum_part_k(const T* __restrict__ g, float* __restrict__ part, int cols)
{
    const int c = blockIdx.x * 64 + threadIdx.x;
    const int rc = blockIdx.y;
    const T* p = g + (size_t)rc * 128 * cols + c;
    float s = 0.f;
    for (int r = 0; r < 128; ++r){
        if (sizeof(T) == 2) s += bf2f_(*(const u16*)(p + (size_t)r * cols));
        else                s += *(const float*)(p + (size_t)r * cols);
    }
    part[(size_t)rc * cols + c] = s;
}
__global__ __launch_bounds__(256)
void colsum_fin_k(const float* __restrict__ part, float* __restrict__ out, int cols)
{
    const int c = blockIdx.x * 256 + threadIdx.x;
    if (c < cols){
        float s = 0.f;
        for (int r = 0; r < 64; ++r) s += part[(size_t)r * cols + c];
        out[c] = s;
    }
}

// bias update (fp32 out): np = p*(1-a) + e*mom - t*g
__global__ __launch_bounds__(256)
void update_k(const float* __restrict__ p, const float* __restrict__ g,
              const float* __restrict__ mom, const float* __restrict__ sc,
              float* __restrict__ np_, int n)
{
    const int i = blockIdx.x * 256 + threadIdx.x;
    if (i < n) np_[i] = p[i] * (1.0f - sc[0]) + sc[2] * mom[i] - sc[1] * g[i];
}

// fused split-K reduce + param update -> bf16 new weights
__global__ __launch_bounds__(256)
void fupdate_k(const float* __restrict__ p, const float* __restrict__ P,
               const float* __restrict__ mom, const float* __restrict__ sc,
               u16* __restrict__ nWb, int n)
{
    const int i = blockIdx.x * 256 + threadIdx.x;
    if (i < n){
        const float g = P[i] + P[(size_t)n + i] + P[(size_t)2*n + i] + P[(size_t)3*n + i];
        nWb[i] = bf1_(p[i] * (1.0f - sc[0]) + sc[2] * mom[i] - sc[1] * g);
    }
}

extern "C" void kernel_launch(void* const* d_in, const int* in_sizes, int n_in,
                              void* d_out, int out_size, void* d_ws, size_t ws_size,
                              hipStream_t stream)
{
    const float* x      = (const float*)d_in[0];
    const float* wq     = (const float*)d_in[1];
    const float* bq     = (const float*)d_in[2];
    const float* wk     = (const float*)d_in[3];
    const float* bk     = (const float*)d_in[4];
    const float* wv     = (const float*)d_in[5];
    const float* bv     = (const float*)d_in[6];
    const float* wlr    = (const float*)d_in[7];
    const float* blr    = (const float*)d_in[8];
    const float* wf     = (const float*)d_in[9];
    const float* bfp    = (const float*)d_in[10];
    const float* wm     = (const float*)d_in[11];
    const float* bm     = (const float*)d_in[12];
    const float* mw1    = (const float*)d_in[13];
    const float* mb1    = (const float*)d_in[14];
    const float* mw2    = (const float*)d_in[15];
    const float* mb2    = (const float*)d_in[16];
    const float* mom_w1 = (const float*)d_in[17];
    const float* mom_b1 = (const float*)d_in[18];
    const float* mom_w2 = (const float*)d_in[19];
    const float* mom_b2 = (const float*)d_in[20];
    float* out = (float*)d_out;

    // ---- workspace layout (bytes), ~193 MB
    char* base = (char*)d_ws;
    size_t off = 0;
    auto alloc = [&](size_t bytes)->char*{ char* p = base + off; off += (bytes + 255) & ~(size_t)255; return p; };
    const size_t NHf  = (size_t)NROWS * HDIM  * 4;   // 16 MB
    const size_t NHb  = (size_t)NROWS * HDIM  * 2;   // 8 MB
    const size_t NHEb = (size_t)NROWS * HEDIM * 2;   // 32 MB
    const int    WHALF = HEDIM * HDIM;               // 1,048,576

    float* F1   = (float*)alloc(NHf);        // k_raw -> x1f (q-path)
    float* F2   = (float*)alloc(NHf);        // v -> splitK partials P -> q_raw/qf
    u16*  xb    = (u16*) alloc(NHb);         // x bf16; later qb overlays
    u16*  kb    = (u16*) alloc(NHb);
    u16*  x1b   = (u16*) alloc(NHb);
    u16*  g2b   = (u16*) alloc(NHb);         // later g1b overlays
    u16*  hb    = (u16*) alloc(NHEb);        // silu(u), shared L0/L1 via recompute
    u16*  db    = (u16*) alloc(NHEb);        // dsilu(u)
    u16*  dhb   = (u16*) alloc(NHEb);        // dh, shared L1/L0
    u16*  wqb   = (u16*) alloc((size_t)HDIM*HDIM*2);
    u16*  wkb   = (u16*) alloc((size_t)HDIM*HDIM*2);
    u16*  wvb   = (u16*) alloc((size_t)HDIM*HDIM*2);
    u16*  mw1b  = (u16*) alloc((size_t)2*WHALF*2);
    u16*  mw2b  = (u16*) alloc((size_t)2*WHALF*2);
    u16*  mw2Tb = (u16*) alloc((size_t)2*WHALF*2);
    u16*  mw1T1b= (u16*) alloc((size_t)WHALF*2);
    u16*  nW1b  = (u16*) alloc((size_t)2*WHALF*2);
    u16*  nW2b  = (u16*) alloc((size_t)2*WHALF*2);
    float* cpart= (float*)alloc((size_t)64*HEDIM*4);
    float* lr_s = (float*)alloc((size_t)NROWS*4);
    float* f_s  = (float*)alloc((size_t)NROWS*4);
    float* m_s  = (float*)alloc((size_t)NROWS*4);
    float* sc   = (float*)alloc(64);
    float* gb1  = (float*)alloc((size_t)2*HEDIM*4);
    float* gb2  = (float*)alloc((size_t)2*HDIM*4);
    float* nb1  = (float*)alloc((size_t)2*HEDIM*4);
    float* nb2  = (float*)alloc((size_t)2*HDIM*4);
    u16* qb  = xb;      // overlay: xb dead after q-projection
    u16* g1b = g2b;     // overlay: g2b dead after backward L1
    float* P = F2;      // overlay: v dead after x2/dpred epilogue

    const dim3 blk(256);
    const dim3 gN512 (HDIM/128,  NROWS/128);       // (4,64)
    const dim3 gN2048(HEDIM/128, NROWS/128);       // (16,64)
    const dim3 gTN2  (HEDIM/128, HDIM/128, 4);     // gW2: M=512,N=2048
    const dim3 gTN1  (HDIM/128,  HEDIM/128, 4);    // gW1: M=2048,N=512

    const float* mw1_1 = mw1 + (size_t)WHALF;
    const float* mw2_1 = mw2 + (size_t)WHALF;

    #define GARG(Ab,Bb,bi,rF,rB,ax,vv,ll,oF,oB,oB2,M,N,K,la,lb) \
        ((const u16*)(Ab),(const u16*)(Bb),(const float*)(bi),(const float*)(rF),\
         (const u16*)(rB),(const u16*)(ax),(const float*)(vv),(const float*)(ll),\
         (float*)(oF),(u16*)(oB),(u16*)(oB2),(M),(N),(K),(la),(lb))

    // ---------- phase 0: conversions + gates ----------
    cvt_k<<<dim3((NROWS*HDIM/8)/256), blk, 0, stream>>>(x, xb, NROWS*HDIM/8);
    cvt_k<<<dim3((HDIM*HDIM/8)/256), blk, 0, stream>>>(wq, wqb, HDIM*HDIM/8);
    cvt_k<<<dim3((HDIM*HDIM/8)/256), blk, 0, stream>>>(wk, wkb, HDIM*HDIM/8);
    cvt_k<<<dim3((HDIM*HDIM/8)/256), blk, 0, stream>>>(wv, wvb, HDIM*HDIM/8);
    cvt_k<<<dim3((2*WHALF/8)/256), blk, 0, stream>>>(mw1, mw1b, 2*WHALF/8);
    cvt_k<<<dim3((2*WHALF/8)/256), blk, 0, stream>>>(mw2, mw2b, 2*WHALF/8);
    tcvt_k<<<dim3(HEDIM/32, HDIM/32), blk, 0, stream>>>(mw2,   mw2Tb,          HDIM, HEDIM);
    tcvt_k<<<dim3(HEDIM/32, HDIM/32), blk, 0, stream>>>(mw2_1, mw2Tb + WHALF,  HDIM, HEDIM);
    tcvt_k<<<dim3(HDIM/32, HEDIM/32), blk, 0, stream>>>(mw1_1, mw1T1b,         HEDIM, HDIM);
    gates_k<<<NROWS, 64, 0, stream>>>(x, wlr, blr, wf, bfp, wm, bm, lr_s, f_s, m_s);
    scalars_k<<<1, blk, 0, stream>>>(lr_s, f_s, m_s, sc);

    // ---------- phase 1: k, v projections ----------
    mgemm_k<0,false><<<gN512, blk, 0, stream>>>GARG(xb, wkb, bk, 0,0,0,0,0, F1, 0,0, NROWS,HDIM,HDIM, HDIM,HDIM);
    l2norm_k<false><<<NROWS, 64, 0, stream>>>(F1, nullptr, kb);
    mgemm_k<0,false><<<gN512, blk, 0, stream>>>GARG(xb, wvb, bv, 0,0,0,0,0, F2, 0,0, NROWS,HDIM,HDIM, HDIM,HDIM);

    // ---------- phase 2: memory forward on k ----------
    mgemm_k<1,false><<<gN2048, blk, 0, stream>>>GARG(kb, mw1b, mb1, 0,0,0,0,0, 0, hb, db, NROWS,HEDIM,HDIM, HDIM,HDIM);
    mgemm_k<9,false><<<gN512, blk, 0, stream>>>GARG(hb, mw2b, mb2, 0, kb, 0,0,0, 0, x1b, 0, NROWS,HDIM,HEDIM, HEDIM,HEDIM);
    mgemm_k<1,false><<<gN2048, blk, 0, stream>>>GARG(x1b, mw1b+WHALF, mb1+HEDIM, 0,0,0,0,0, 0, hb, db, NROWS,HEDIM,HDIM, HDIM,HDIM);
    mgemm_k<8,false><<<gN512, blk, 0, stream>>>GARG(hb, mw2b+WHALF, mb2+HDIM, 0, x1b, 0, F2, lr_s, out, g2b, 0, NROWS,HDIM,HEDIM, HEDIM,HEDIM);

    // ---------- backward layer 1 (hb=h1, db=d1) ----------
    colsum_part_k<float><<<dim3(HDIM/64,64), 64, 0, stream>>>(out, cpart, HDIM);
    colsum_fin_k<<<dim3(HDIM/256), blk, 0, stream>>>(cpart, gb2 + HDIM, HDIM);
    update_k<<<dim3(HDIM/256), blk, 0, stream>>>(mb2+HDIM, gb2+HDIM, mom_b2+HDIM, sc, nb2+HDIM, HDIM);
    mgemm_k<3,true><<<gTN2, blk, 0, stream>>>GARG(g2b, hb, 0,0,0,0,0,0, P, 0,0, HDIM,HEDIM,NROWS, HDIM,HEDIM);
    fupdate_k<<<dim3(WHALF/256), blk, 0, stream>>>(mw2_1, P, mom_w2+WHALF, sc, nW2b+WHALF, WHALF);
    mgemm_k<4,false><<<gN2048, blk, 0, stream>>>GARG(g2b, mw2Tb+WHALF, 0,0,0, db, 0,0, 0, dhb, 0, NROWS,HEDIM,HDIM, HDIM,HDIM);
    colsum_part_k<u16><<<dim3(HEDIM/64,64), 64, 0, stream>>>(dhb, cpart, HEDIM);
    colsum_fin_k<<<dim3(HEDIM/256), blk, 0, stream>>>(cpart, gb1 + HEDIM, HEDIM);
    update_k<<<dim3(HEDIM/256), blk, 0, stream>>>(mb1+HEDIM, gb1+HEDIM, mom_b1+HEDIM, sc, nb1+HEDIM, HEDIM);
    mgemm_k<3,true><<<gTN1, blk, 0, stream>>>GARG(dhb, x1b, 0,0,0,0,0,0, P, 0,0, HEDIM,HDIM,NROWS, HEDIM,HDIM);
    fupdate_k<<<dim3(WHALF/256), blk, 0, stream>>>(mw1_1, P, mom_w1+WHALF, sc, nW1b+WHALF, WHALF);
    mgemm_k<5,false><<<gN512, blk, 0, stream>>>GARG(dhb, mw1T1b, 0, out, 0,0,0,0, 0, g1b, 0, NROWS,HDIM,HEDIM, HEDIM,HEDIM);

    // ---------- backward layer 0 (recompute u0 -> hb,db) ----------
    colsum_part_k<u16><<<dim3(HDIM/64,64), 64, 0, stream>>>(g1b, cpart, HDIM);
    colsum_fin_k<<<dim3(HDIM/256), blk, 0, stream>>>(cpart, gb2, HDIM);
    update_k<<<dim3(HDIM/256), blk, 0, stream>>>(mb2, gb2, mom_b2, sc, nb2, HDIM);
    mgemm_k<1,false><<<gN2048, blk, 0, stream>>>GARG(kb, mw1b, mb1, 0,0,0,0,0, 0, hb, db, NROWS,HEDIM,HDIM, HDIM,HDIM);
    mgemm_k<3,true><<<gTN2, blk, 0, stream>>>GARG(g1b, hb, 0,0,0,0,0,0, P, 0,0, HDIM,HEDIM,NROWS, HDIM,HEDIM);
    fupdate_k<<<dim3(WHALF/256), blk, 0, stream>>>(mw2, P, mom_w2, sc, nW2b, WHALF);
    mgemm_k<4,false><<<gN2048, blk, 0, stream>>>GARG(g1b, mw2Tb, 0,0,0, db, 0,0, 0, dhb, 0, NROWS,HEDIM,HDIM, HDIM,HDIM);
    colsum_part_k<u16><<<dim3(HEDIM/64,64), 64, 0, stream>>>(dhb, cpart, HEDIM);
    colsum_fin_k<<<dim3(HEDIM/256), blk, 0, stream>>>(cpart, gb1, HEDIM);
    update_k<<<dim3(HEDIM/256), blk, 0, stream>>>(mb1, gb1, mom_b1, sc, nb1, HEDIM);
    mgemm_k<3,true><<<gTN1, blk, 0, stream>>>GARG(dhb, kb, 0,0,0,0,0,0, P, 0,0, HEDIM,HDIM,NROWS, HEDIM,HDIM);
    fupdate_k<<<dim3(WHALF/256), blk, 0, stream>>>(mw1, P, mom_w1, sc, nW1b, WHALF);

    // ---------- phase 4: q projection + forward with new params ----------
    mgemm_k<0,false><<<gN512, blk, 0, stream>>>GARG(xb, wqb, bq, 0,0,0,0,0, F2, 0,0, NROWS,HDIM,HDIM, HDIM,HDIM);
    l2norm_k<true><<<NROWS, 64, 0, stream>>>(F2, F2, qb);
    mgemm_k<1,false><<<gN2048, blk, 0, stream>>>GARG(qb, nW1b, nb1, 0,0,0,0,0, 0, hb, db, NROWS,HEDIM,HDIM, HDIM,HDIM);
    mgemm_k<6,false><<<gN512, blk, 0, stream>>>GARG(hb, nW2b, nb2, F2, 0,0,0,0, F1, x1b, 0, NROWS,HDIM,HEDIM, HEDIM,HEDIM);
    mgemm_k<1,false><<<gN2048, blk, 0, stream>>>GARG(x1b, nW1b+WHALF, nb1+HEDIM, 0,0,0,0,0, 0, hb, db, NROWS,HEDIM,HDIM, HDIM,HDIM);
    mgemm_k<7,false><<<gN512, blk, 0, stream>>>GARG(hb, nW2b+WHALF, nb2+HDIM, F1, 0,0,0,0, out, 0,0, NROWS,HDIM,HEDIM, HEDIM,HEDIM);

    #undef GARG
    (void)in_sizes; (void)n_in; (void)out_size; (void)ws_size; (void)wq;
}

// Round 5
// 838.461 us; speedup vs baseline: 6.3430x; 1.3475x over previous
//
#include <hip/hip_runtime.h>
#include <cstdint>
#include <cstddef>

// NeuralMemory — bf16 MFMA GEMMs, BK=64, swizzled linear LDS (no pad),
// NT staging via global_load_lds(16B), TN staging swizzled reg->LDS,
// split-K x8 weight grads with partials in dead 32MB activation buffer.

#define NROWS 8192
#define HDIM  512
#define HEDIM 2048
#define NCHUNK 8
#define BK    64
#define DPCOEF (2.0f / (HDIM * NCHUNK))

typedef unsigned short u16;
typedef __attribute__((ext_vector_type(8))) unsigned short u16x8;
typedef __attribute__((ext_vector_type(8))) short bf16x8;
typedef __attribute__((ext_vector_type(4))) float f32x4;

__device__ __forceinline__ float sigmoidf_(float x){ return 1.0f/(1.0f+__expf(-x)); }
__device__ __forceinline__ float siluf_(float x){ return x*sigmoidf_(x); }
__device__ __forceinline__ float dsiluf_(float x){ float s=sigmoidf_(x); return s*(1.0f+x*(1.0f-s)); }
__device__ __forceinline__ u16 bf1_(float x){
    union{float f; unsigned u;} v; v.f = x;
    return (u16)((v.u + 0x7fffu + ((v.u>>16)&1u)) >> 16);
}
__device__ __forceinline__ float bf2f_(u16 h){
    union{unsigned u; float f;} v; v.u = ((unsigned)h) << 16; return v.f;
}
// swizzle key from row bits 3..5 (bit-reversed) — spreads banks for both the
// TN per-mc writes and the per-lr fragment reads.
__device__ __forceinline__ int swkey_(int row){
    return (((row>>3)&1)<<2) | (((row>>4)&1)<<1) | ((row>>5)&1);
}
__device__ __forceinline__ void gl_lds16(const u16* g, u16* l){
    __builtin_amdgcn_global_load_lds(
        (const __attribute__((address_space(1))) unsigned*)g,
        (__attribute__((address_space(3))) unsigned*)l, 16, 0, 0);
}

// ---------------------------------------------------------------------------
// bf16 GEMM, 128x128 tile, BK=64, 4 waves. LDS tile: [128 rows][64 k] ushorts,
// linear, chunk-XOR swizzled (chunk' = chunk ^ swkey(row), chunk = 16B unit).
// ATR=false: A[M,K], B[N,K] (k-contiguous) — staged via global_load_lds.
// ATR=true : A[K,M], B[K,N] — transpose-staged, pair-packed b32 writes.
// MODE: 0 outF=acc+b | 1 h,dsilu | 2 h only | 3 splitK8 partials | 4 *dsilu
//       5 +resF->bf | 6 +b+resF->f32+bf | 7 +b+resF->f32 | 8 dpred | 9 +b+resB->bf
// ---------------------------------------------------------------------------
template<int MODE, bool ATR>
__global__ __launch_bounds__(256)
void mgemm_k(const u16* __restrict__ A, const u16* __restrict__ B,
             const float* __restrict__ bias, const float* __restrict__ resF,
             const u16* __restrict__ resB, const u16* __restrict__ aux,
             const float* __restrict__ vf, const float* __restrict__ lrs,
             float* __restrict__ outF, u16* __restrict__ outB, u16* __restrict__ outB2,
             int M, int N, int K, int lda, int ldb)
{
    __shared__ __align__(128) u16 As[128*64];
    __shared__ __align__(128) u16 Bs[128*64];
    const int tid = threadIdx.x;
    const int lane = tid & 63, wvi = tid >> 6;
    const int wm = wvi >> 1, wn = wvi & 1;
    const int lr = lane & 15, lq = lane >> 4;
    const int m0 = blockIdx.y * 128, n0 = blockIdx.x * 128;

    int kbeg = 0, kend = K;
    if (MODE == 3){ const int ks = K >> 3; kbeg = blockIdx.z * ks; kend = kbeg + ks; }

    f32x4 acc[4][4];
    const f32x4 zz = {0.f,0.f,0.f,0.f};
    #pragma unroll
    for (int i = 0; i < 4; ++i)
        #pragma unroll
        for (int j = 0; j < 4; ++j) acc[i][j] = zz;

    // hoisted read offsets (ushort): row*64 + (chunk^key)*8
    int roffA[4], roffB[4];
    #pragma unroll
    for (int i = 0; i < 4; ++i){
        const int ra = wm*64 + i*16 + lr, rb = wn*64 + i*16 + lr;
        roffA[i] = ra*64 + ((lq ^ swkey_(ra)) << 3);   // chunk = ks*4+lq; ks handled below
        roffB[i] = rb*64 + ((lq ^ swkey_(rb)) << 3);
    }
    // ks=1 flips chunk bit2: offset delta = ((lq^key^4) - (lq^key))*8 = ±32
    // compute both explicitly below instead.

    for (int k0 = kbeg; k0 < kend; k0 += BK) {
        if (!ATR) {
            #pragma unroll
            for (int it = 0; it < 4; ++it){
                const int seg = it*4 + wvi;                 // 0..15 (8 rows each)
                const int key = (((seg&1)<<2)|(((seg>>1)&1)<<1)|((seg>>2)&1));
                const int row = seg*8 + (lane>>3);
                const int chunk = (lane&7) ^ key;
                gl_lds16(A + (size_t)(m0+row)*lda + k0 + chunk*8, &As[seg*512]);
                gl_lds16(B + (size_t)(n0+row)*ldb + k0 + chunk*8, &Bs[seg*512]);
            }
        } else {
            #pragma unroll
            for (int r = 0; r < 2; ++r){
                const int slot = r*256 + tid;
                const int mc = slot & 15, kp = slot >> 4;   // kp 0..31 (k-pairs)
                const int chunk = kp >> 2, t = kp & 3;
                const int key = (((mc&1)<<2)|(((mc>>1)&1)<<1)|((mc>>2)&1));
                const int cs = ((chunk ^ key) << 3) + t*2;
                {
                    const u16* p = A + (size_t)(k0 + 2*kp) * lda + m0 + mc*8;
                    u16x8 e = *(const u16x8*)p;
                    u16x8 o = *(const u16x8*)(p + lda);
                    #pragma unroll
                    for (int j = 0; j < 8; ++j)
                        *(unsigned*)&As[(mc*8 + j)*64 + cs] = (unsigned)e[j] | ((unsigned)o[j] << 16);
                }
                {
                    const u16* p = B + (size_t)(k0 + 2*kp) * ldb + n0 + mc*8;
                    u16x8 e = *(const u16x8*)p;
                    u16x8 o = *(const u16x8*)(p + ldb);
                    #pragma unroll
                    for (int j = 0; j < 8; ++j)
                        *(unsigned*)&Bs[(mc*8 + j)*64 + cs] = (unsigned)e[j] | ((unsigned)o[j] << 16);
                }
            }
        }
        __syncthreads();
        #pragma unroll
        for (int ks = 0; ks < 2; ++ks) {
            bf16x8 afr[4], bfr[4];
            #pragma unroll
            for (int i = 0; i < 4; ++i){
                const int ra = wm*64 + i*16 + lr, rb = wn*64 + i*16 + lr;
                afr[i] = *(const bf16x8*)&As[ra*64 + (((ks*4 + lq) ^ swkey_(ra)) << 3)];
                bfr[i] = *(const bf16x8*)&Bs[rb*64 + (((ks*4 + lq) ^ swkey_(rb)) << 3)];
            }
            #pragma unroll
            for (int mi = 0; mi < 4; ++mi)
                #pragma unroll
                for (int ni = 0; ni < 4; ++ni)
                    acc[mi][ni] = __builtin_amdgcn_mfma_f32_16x16x32_bf16(afr[mi], bfr[ni], acc[mi][ni], 0, 0, 0);
        }
        __syncthreads();
    }
    (void)roffA; (void)roffB;

    #pragma unroll
    for (int ni = 0; ni < 4; ++ni){
        const int col = n0 + wn*64 + ni*16 + lr;
        float bv = 0.0f;
        if (MODE==0 || MODE==1 || MODE==2 || MODE==6 || MODE==7 || MODE==8 || MODE==9) bv = bias[col];
        #pragma unroll
        for (int mi = 0; mi < 4; ++mi){
            const int rbase = m0 + wm*64 + mi*16 + lq*4;
            #pragma unroll
            for (int v = 0; v < 4; ++v){
                const int row = rbase + v;
                const size_t idx = (size_t)row * N + col;
                const float o = acc[mi][ni][v];
                if (MODE == 0){ outF[idx] = o + bv; }
                else if (MODE == 1){
                    const float u = o + bv;
                    outB[idx]  = bf1_(siluf_(u));
                    outB2[idx] = bf1_(dsiluf_(u));
                }
                else if (MODE == 2){ outB[idx] = bf1_(siluf_(o + bv)); }
                else if (MODE == 3){ outF[(size_t)blockIdx.z * M * N + idx] = o; }
                else if (MODE == 4){ outB[idx] = bf1_(o * bf2f_(aux[idx])); }
                else if (MODE == 5){ outB[idx] = bf1_(o + resF[idx]); }
                else if (MODE == 6){ const float t = o + bv + resF[idx]; outF[idx] = t; outB[idx] = bf1_(t); }
                else if (MODE == 7){ outF[idx] = o + bv + resF[idx]; }
                else if (MODE == 8){
                    const float t = o + bv + bf2f_(resB[idx]);
                    const float g = lrs[row] * DPCOEF * (t - vf[idx]);
                    outF[idx] = g; outB[idx] = bf1_(g);
                }
                else if (MODE == 9){ outB[idx] = bf1_(o + bv + bf2f_(resB[idx])); }
            }
        }
    }
}

__global__ __launch_bounds__(256)
void cvt_k(const float* __restrict__ in, u16* __restrict__ out, int n8)
{
    const int i = blockIdx.x * 256 + threadIdx.x;
    if (i < n8){
        const float4 a = *(const float4*)(in + (size_t)i*8);
        const float4 b = *(const float4*)(in + (size_t)i*8 + 4);
        u16x8 o;
        o[0]=bf1_(a.x); o[1]=bf1_(a.y); o[2]=bf1_(a.z); o[3]=bf1_(a.w);
        o[4]=bf1_(b.x); o[5]=bf1_(b.y); o[6]=bf1_(b.z); o[7]=bf1_(b.w);
        *(u16x8*)(out + (size_t)i*8) = o;
    }
}

__global__ __launch_bounds__(256)
void tcvt_k(const float* __restrict__ in, u16* __restrict__ out, int R, int C)
{
    __shared__ float t[32][33];
    const int tx = threadIdx.x & 31, ty = threadIdx.x >> 5;
    const int c0 = blockIdx.x * 32, r0 = blockIdx.y * 32;
    #pragma unroll
    for (int j = 0; j < 4; ++j)
        t[ty + 8*j][tx] = in[(size_t)(r0 + ty + 8*j) * C + c0 + tx];
    __syncthreads();
    #pragma unroll
    for (int j = 0; j < 4; ++j)
        out[(size_t)(c0 + ty + 8*j) * R + r0 + tx] = bf1_(t[tx][ty + 8*j]);
}

template<bool WF32>
__global__ __launch_bounds__(64)
void l2norm_k(const float* __restrict__ in, float* __restrict__ outF, u16* __restrict__ outB)
{
    const float* p = in + (size_t)blockIdx.x * HDIM;
    const int t = threadIdx.x;
    float4 v0 = *(const float4*)(p + t*8), v1 = *(const float4*)(p + t*8 + 4);
    float s = v0.x*v0.x+v0.y*v0.y+v0.z*v0.z+v0.w*v0.w
            + v1.x*v1.x+v1.y*v1.y+v1.z*v1.z+v1.w*v1.w;
    #pragma unroll
    for (int o = 1; o < 64; o <<= 1) s += __shfl_xor(s, o);
    const float sc = 1.0f / fmaxf(sqrtf(s), 1e-12f);
    v0.x*=sc; v0.y*=sc; v0.z*=sc; v0.w*=sc;
    v1.x*=sc; v1.y*=sc; v1.z*=sc; v1.w*=sc;
    if (WF32){
        float* q = outF + (size_t)blockIdx.x * HDIM;
        *(float4*)(q + t*8) = v0; *(float4*)(q + t*8 + 4) = v1;
    }
    u16x8 ob;
    ob[0]=bf1_(v0.x); ob[1]=bf1_(v0.y); ob[2]=bf1_(v0.z); ob[3]=bf1_(v0.w);
    ob[4]=bf1_(v1.x); ob[5]=bf1_(v1.y); ob[6]=bf1_(v1.z); ob[7]=bf1_(v1.w);
    *(u16x8*)(outB + (size_t)blockIdx.x * HDIM + t*8) = ob;
}

__global__ __launch_bounds__(64)
void gates_k(const float* __restrict__ x,
             const float* __restrict__ wlr, const float* __restrict__ blr,
             const float* __restrict__ wf,  const float* __restrict__ bfp,
             const float* __restrict__ wm,  const float* __restrict__ bm,
             float* __restrict__ lr_s, float* __restrict__ f_s, float* __restrict__ m_s)
{
    const size_t row = blockIdx.x;
    const float* p = x + row * HDIM;
    const int t = threadIdx.x;
    float s0 = 0.f, s1 = 0.f, s2 = 0.f;
    #pragma unroll
    for (int i = 0; i < 8; i += 4){
        float4 xv = *(const float4*)(p   + t*8 + i);
        float4 a  = *(const float4*)(wlr + t*8 + i);
        float4 b  = *(const float4*)(wf  + t*8 + i);
        float4 c  = *(const float4*)(wm  + t*8 + i);
        s0 += xv.x*a.x + xv.y*a.y + xv.z*a.z + xv.w*a.w;
        s1 += xv.x*b.x + xv.y*b.y + xv.z*b.z + xv.w*b.w;
        s2 += xv.x*c.x + xv.y*c.y + xv.z*c.z + xv.w*c.w;
    }
    #pragma unroll
    for (int o = 1; o < 64; o <<= 1){
        s0 += __shfl_xor(s0, o); s1 += __shfl_xor(s1, o); s2 += __shfl_xor(s2, o);
    }
    if (t == 0){
        lr_s[row] = sigmoidf_(s0 + blr[0]) * 0.1f;
        f_s[row]  = sigmoidf_(s1 + bfp[0]);
        m_s[row]  = sigmoidf_(s2 + bm[0]);
    }
}

__global__ __launch_bounds__(256)
void scalars_k(const float* __restrict__ lr_s, const float* __restrict__ f_s,
               const float* __restrict__ m_s, float* __restrict__ sc)
{
    __shared__ float sh0[256], sh1[256], sh2[256];
    const int t = threadIdx.x;
    float s0 = 0.f, s1 = 0.f, s2 = 0.f;
    for (int i = t; i < NROWS; i += 256){ s0 += f_s[i]; s1 += lr_s[i]; s2 += m_s[i]; }
    sh0[t] = s0; sh1[t] = s1; sh2[t] = s2;
    __syncthreads();
    for (int o = 128; o > 0; o >>= 1){
        if (t < o){ sh0[t] += sh0[t+o]; sh1[t] += sh1[t+o]; sh2[t] += sh2[t+o]; }
        __syncthreads();
    }
    if (t == 0){
        sc[0] = sh0[0] / (float)NROWS;
        sc[1] = sh1[0] / (float)NROWS;
        sc[2] = sh2[0] / (float)NROWS;
    }
}

template<typename T>
__global__ __launch_bounds__(64)
void colsum_part_k(const T* __restrict__ g, float* __restrict__ part, int cols)
{
    const int c = blockIdx.x * 64 + threadIdx.x;
    const int rc = blockIdx.y;
    const T* p = g + (size_t)rc * 128 * cols + c;
    float s = 0.f;
    for (int r = 0; r < 128; ++r){
        if (sizeof(T) == 2) s += bf2f_(*(const u16*)(p + (size_t)r * cols));
        else                s += *(const float*)(p + (size_t)r * cols);
    }
    part[(size_t)rc * cols + c] = s;
}
__global__ __launch_bounds__(256)
void colsum_fin_k(const float* __restrict__ part, float* __restrict__ out, int cols)
{
    const int c = blockIdx.x * 256 + threadIdx.x;
    if (c < cols){
        float s = 0.f;
        for (int r = 0; r < 64; ++r) s += part[(size_t)r * cols + c];
        out[c] = s;
    }
}

__global__ __launch_bounds__(256)
void update_k(const float* __restrict__ p, const float* __restrict__ g,
              const float* __restrict__ mom, const float* __restrict__ sc,
              float* __restrict__ np_, int n)
{
    const int i = blockIdx.x * 256 + threadIdx.x;
    if (i < n) np_[i] = p[i] * (1.0f - sc[0]) + sc[2] * mom[i] - sc[1] * g[i];
}

// fused split-K8 reduce + param update -> bf16 new weights
__global__ __launch_bounds__(256)
void fupdate8_k(const float* __restrict__ p, const float* __restrict__ P,
                const float* __restrict__ mom, const float* __restrict__ sc,
                u16* __restrict__ nWb, int n)
{
    const int i = blockIdx.x * 256 + threadIdx.x;
    if (i < n){
        float g = 0.f;
        #pragma unroll
        for (int z = 0; z < 8; ++z) g += P[(size_t)z * n + i];
        nWb[i] = bf1_(p[i] * (1.0f - sc[0]) + sc[2] * mom[i] - sc[1] * g);
    }
}

extern "C" void kernel_launch(void* const* d_in, const int* in_sizes, int n_in,
                              void* d_out, int out_size, void* d_ws, size_t ws_size,
                              hipStream_t stream)
{
    const float* x      = (const float*)d_in[0];
    const float* wq     = (const float*)d_in[1];
    const float* bq     = (const float*)d_in[2];
    const float* wk     = (const float*)d_in[3];
    const float* bk     = (const float*)d_in[4];
    const float* wv     = (const float*)d_in[5];
    const float* bv     = (const float*)d_in[6];
    const float* wlr    = (const float*)d_in[7];
    const float* blr    = (const float*)d_in[8];
    const float* wf     = (const float*)d_in[9];
    const float* bfp    = (const float*)d_in[10];
    const float* wm     = (const float*)d_in[11];
    const float* bm     = (const float*)d_in[12];
    const float* mw1    = (const float*)d_in[13];
    const float* mb1    = (const float*)d_in[14];
    const float* mw2    = (const float*)d_in[15];
    const float* mb2    = (const float*)d_in[16];
    const float* mom_w1 = (const float*)d_in[17];
    const float* mom_b1 = (const float*)d_in[18];
    const float* mom_w2 = (const float*)d_in[19];
    const float* mom_b2 = (const float*)d_in[20];
    float* out = (float*)d_out;

    char* base = (char*)d_ws;
    size_t off = 0;
    auto alloc = [&](size_t bytes)->char*{ char* p = base + off; off += (bytes + 255) & ~(size_t)255; return p; };
    const size_t NHf  = (size_t)NROWS * HDIM  * 4;
    const size_t NHb  = (size_t)NROWS * HDIM  * 2;
    const size_t NHEb = (size_t)NROWS * HEDIM * 2;
    const int    WHALF = HEDIM * HDIM;

    float* F1   = (float*)alloc(NHf);        // k_raw -> x1f (q-path)
    float* F2   = (float*)alloc(NHf);        // v -> q_raw/qf
    u16*  xb    = (u16*) alloc(NHb);         // x bf16; later qb overlays
    u16*  kb    = (u16*) alloc(NHb);
    u16*  x1b   = (u16*) alloc(NHb);
    u16*  g2b   = (u16*) alloc(NHb);         // later g1b overlays
    u16*  hb    = (u16*) alloc(NHEb);        // silu(u)
    u16*  db    = (u16*) alloc(NHEb);        // dsilu(u) / split-K partials (32MB)
    u16*  dhb   = (u16*) alloc(NHEb);        // dh
    u16*  wqb   = (u16*) alloc((size_t)HDIM*HDIM*2);
    u16*  wkb   = (u16*) alloc((size_t)HDIM*HDIM*2);
    u16*  wvb   = (u16*) alloc((size_t)HDIM*HDIM*2);
    u16*  mw1b  = (u16*) alloc((size_t)2*WHALF*2);
    u16*  mw2b  = (u16*) alloc((size_t)2*WHALF*2);
    u16*  mw2Tb = (u16*) alloc((size_t)2*WHALF*2);
    u16*  mw1T1b= (u16*) alloc((size_t)WHALF*2);
    u16*  nW1b  = (u16*) alloc((size_t)2*WHALF*2);
    u16*  nW2b  = (u16*) alloc((size_t)2*WHALF*2);
    float* cpart= (float*)alloc((size_t)64*HEDIM*4);
    float* lr_s = (float*)alloc((size_t)NROWS*4);
    float* f_s  = (float*)alloc((size_t)NROWS*4);
    float* m_s  = (float*)alloc((size_t)NROWS*4);
    float* sc   = (float*)alloc(64);
    float* gb1  = (float*)alloc((size_t)2*HEDIM*4);
    float* gb2  = (float*)alloc((size_t)2*HDIM*4);
    float* nb1  = (float*)alloc((size_t)2*HEDIM*4);
    float* nb2  = (float*)alloc((size_t)2*HDIM*4);
    u16* qb  = xb;
    u16* g1b = g2b;
    float* P = (float*)db;                   // split-K partials: 8 x 4MB = 32MB

    const dim3 blk(256);
    const dim3 gN512 (HDIM/128,  NROWS/128);
    const dim3 gN2048(HEDIM/128, NROWS/128);
    const dim3 gTN2  (HEDIM/128, HDIM/128, 8);
    const dim3 gTN1  (HDIM/128,  HEDIM/128, 8);

    const float* mw1_1 = mw1 + (size_t)WHALF;
    const float* mw2_1 = mw2 + (size_t)WHALF;

    #define GARG(Ab,Bb,bi,rF,rB,ax,vv,ll,oF,oB,oB2,M,N,K,la,lb) \
        ((const u16*)(Ab),(const u16*)(Bb),(const float*)(bi),(const float*)(rF),\
         (const u16*)(rB),(const u16*)(ax),(const float*)(vv),(const float*)(ll),\
         (float*)(oF),(u16*)(oB),(u16*)(oB2),(M),(N),(K),(la),(lb))

    // ---------- phase 0: conversions + gates ----------
    cvt_k<<<dim3((NROWS*HDIM/8)/256), blk, 0, stream>>>(x, xb, NROWS*HDIM/8);
    cvt_k<<<dim3((HDIM*HDIM/8)/256), blk, 0, stream>>>(wq, wqb, HDIM*HDIM/8);
    cvt_k<<<dim3((HDIM*HDIM/8)/256), blk, 0, stream>>>(wk, wkb, HDIM*HDIM/8);
    cvt_k<<<dim3((HDIM*HDIM/8)/256), blk, 0, stream>>>(wv, wvb, HDIM*HDIM/8);
    cvt_k<<<dim3((2*WHALF/8)/256), blk, 0, stream>>>(mw1, mw1b, 2*WHALF/8);
    cvt_k<<<dim3((2*WHALF/8)/256), blk, 0, stream>>>(mw2, mw2b, 2*WHALF/8);
    tcvt_k<<<dim3(HEDIM/32, HDIM/32), blk, 0, stream>>>(mw2,   mw2Tb,         HDIM, HEDIM);
    tcvt_k<<<dim3(HEDIM/32, HDIM/32), blk, 0, stream>>>(mw2_1, mw2Tb + WHALF, HDIM, HEDIM);
    tcvt_k<<<dim3(HDIM/32, HEDIM/32), blk, 0, stream>>>(mw1_1, mw1T1b,        HEDIM, HDIM);
    gates_k<<<NROWS, 64, 0, stream>>>(x, wlr, blr, wf, bfp, wm, bm, lr_s, f_s, m_s);
    scalars_k<<<1, blk, 0, stream>>>(lr_s, f_s, m_s, sc);

    // ---------- phase 1: k, v projections ----------
    mgemm_k<0,false><<<gN512, blk, 0, stream>>>GARG(xb, wkb, bk, 0,0,0,0,0, F1, 0,0, NROWS,HDIM,HDIM, HDIM,HDIM);
    l2norm_k<false><<<NROWS, 64, 0, stream>>>(F1, nullptr, kb);
    mgemm_k<0,false><<<gN512, blk, 0, stream>>>GARG(xb, wvb, bv, 0,0,0,0,0, F2, 0,0, NROWS,HDIM,HDIM, HDIM,HDIM);

    // ---------- phase 2: memory forward on k ----------
    mgemm_k<2,false><<<gN2048, blk, 0, stream>>>GARG(kb, mw1b, mb1, 0,0,0,0,0, 0, hb, 0, NROWS,HEDIM,HDIM, HDIM,HDIM);
    mgemm_k<9,false><<<gN512, blk, 0, stream>>>GARG(hb, mw2b, mb2, 0, kb, 0,0,0, 0, x1b, 0, NROWS,HDIM,HEDIM, HEDIM,HEDIM);
    mgemm_k<1,false><<<gN2048, blk, 0, stream>>>GARG(x1b, mw1b+WHALF, mb1+HEDIM, 0,0,0,0,0, 0, hb, db, NROWS,HEDIM,HDIM, HDIM,HDIM);
    mgemm_k<8,false><<<gN512, blk, 0, stream>>>GARG(hb, mw2b+WHALF, mb2+HDIM, 0, x1b, 0, F2, lr_s, out, g2b, 0, NROWS,HDIM,HEDIM, HEDIM,HEDIM);

    // ---------- backward layer 1 ----------
    colsum_part_k<float><<<dim3(HDIM/64,64), 64, 0, stream>>>(out, cpart, HDIM);
    colsum_fin_k<<<dim3(HDIM/256), blk, 0, stream>>>(cpart, gb2 + HDIM, HDIM);
    update_k<<<dim3(HDIM/256), blk, 0, stream>>>(mb2+HDIM, gb2+HDIM, mom_b2+HDIM, sc, nb2+HDIM, HDIM);
    mgemm_k<4,false><<<gN2048, blk, 0, stream>>>GARG(g2b, mw2Tb+WHALF, 0,0,0, db, 0,0, 0, dhb, 0, NROWS,HEDIM,HDIM, HDIM,HDIM);  // dh1 (db dead after)
    mgemm_k<3,true><<<gTN2, blk, 0, stream>>>GARG(g2b, hb, 0,0,0,0,0,0, P, 0,0, HDIM,HEDIM,NROWS, HDIM,HEDIM);                   // gW2_1 partials
    fupdate8_k<<<dim3(WHALF/256), blk, 0, stream>>>(mw2_1, P, mom_w2+WHALF, sc, nW2b+WHALF, WHALF);
    colsum_part_k<u16><<<dim3(HEDIM/64,64), 64, 0, stream>>>(dhb, cpart, HEDIM);
    colsum_fin_k<<<dim3(HEDIM/256), blk, 0, stream>>>(cpart, gb1 + HEDIM, HEDIM);
    update_k<<<dim3(HEDIM/256), blk, 0, stream>>>(mb1+HEDIM, gb1+HEDIM, mom_b1+HEDIM, sc, nb1+HEDIM, HEDIM);
    mgemm_k<3,true><<<gTN1, blk, 0, stream>>>GARG(dhb, x1b, 0,0,0,0,0,0, P, 0,0, HEDIM,HDIM,NROWS, HEDIM,HDIM);                  // gW1_1 partials
    fupdate8_k<<<dim3(WHALF/256), blk, 0, stream>>>(mw1_1, P, mom_w1+WHALF, sc, nW1b+WHALF, WHALF);
    mgemm_k<5,false><<<gN512, blk, 0, stream>>>GARG(dhb, mw1T1b, 0, out, 0,0,0,0, 0, g1b, 0, NROWS,HDIM,HEDIM, HEDIM,HEDIM);     // g1

    // ---------- backward layer 0 ----------
    colsum_part_k<u16><<<dim3(HDIM/64,64), 64, 0, stream>>>(g1b, cpart, HDIM);
    colsum_fin_k<<<dim3(HDIM/256), blk, 0, stream>>>(cpart, gb2, HDIM);
    update_k<<<dim3(HDIM/256), blk, 0, stream>>>(mb2, gb2, mom_b2, sc, nb2, HDIM);
    mgemm_k<1,false><<<gN2048, blk, 0, stream>>>GARG(kb, mw1b, mb1, 0,0,0,0,0, 0, hb, db, NROWS,HEDIM,HDIM, HDIM,HDIM);          // recompute u0 -> h0,d0
    mgemm_k<4,false><<<gN2048, blk, 0, stream>>>GARG(g1b, mw2Tb, 0,0,0, db, 0,0, 0, dhb, 0, NROWS,HEDIM,HDIM, HDIM,HDIM);        // dh0 (db dead after)
    mgemm_k<3,true><<<gTN2, blk, 0, stream>>>GARG(g1b, hb, 0,0,0,0,0,0, P, 0,0, HDIM,HEDIM,NROWS, HDIM,HEDIM);                   // gW2_0 partials
    fupdate8_k<<<dim3(WHALF/256), blk, 0, stream>>>(mw2, P, mom_w2, sc, nW2b, WHALF);
    colsum_part_k<u16><<<dim3(HEDIM/64,64), 64, 0, stream>>>(dhb, cpart, HEDIM);
    colsum_fin_k<<<dim3(HEDIM/256), blk, 0, stream>>>(cpart, gb1, HEDIM);
    update_k<<<dim3(HEDIM/256), blk, 0, stream>>>(mb1, gb1, mom_b1, sc, nb1, HEDIM);
    mgemm_k<3,true><<<gTN1, blk, 0, stream>>>GARG(dhb, kb, 0,0,0,0,0,0, P, 0,0, HEDIM,HDIM,NROWS, HEDIM,HDIM);                   // gW1_0 partials
    fupdate8_k<<<dim3(WHALF/256), blk, 0, stream>>>(mw1, P, mom_w1, sc, nW1b, WHALF);

    // ---------- phase 4: q projection + forward with new params ----------
    mgemm_k<0,false><<<gN512, blk, 0, stream>>>GARG(xb, wqb, bq, 0,0,0,0,0, F2, 0,0, NROWS,HDIM,HDIM, HDIM,HDIM);
    l2norm_k<true><<<NROWS, 64, 0, stream>>>(F2, F2, qb);
    mgemm_k<2,false><<<gN2048, blk, 0, stream>>>GARG(qb, nW1b, nb1, 0,0,0,0,0, 0, hb, 0, NROWS,HEDIM,HDIM, HDIM,HDIM);
    mgemm_k<6,false><<<gN512, blk, 0, stream>>>GARG(hb, nW2b, nb2, F2, 0,0,0,0, F1, x1b, 0, NROWS,HDIM,HEDIM, HEDIM,HEDIM);
    mgemm_k<2,false><<<gN2048, blk, 0, stream>>>GARG(x1b, nW1b+WHALF, nb1+HEDIM, 0,0,0,0,0, 0, hb, 0, NROWS,HEDIM,HDIM, HDIM,HDIM);
    mgemm_k<7,false><<<gN512, blk, 0, stream>>>GARG(hb, nW2b+WHALF, nb2+HDIM, F1, 0,0,0,0, out, 0,0, NROWS,HDIM,HEDIM, HEDIM,HEDIM);

    #undef GARG
    (void)in_sizes; (void)n_in; (void)out_size; (void)ws_size;
}

// Round 6
// 807.712 us; speedup vs baseline: 6.5845x; 1.0381x over previous
//
#include <hip/hip_runtime.h>
#include <cstdint>
#include <cstddef>

// NeuralMemory — bf16 MFMA GEMMs, BK=64, swizzled linear LDS, NT staging via
// global_load_lds(16B), TN transpose-staging, split-K x16 bf16 partials,
// fused kvq projection, XCD-chunked block swizzle, fused bias updates.

#define NROWS 8192
#define HDIM  512
#define HEDIM 2048
#define NCHUNK 8
#define BK    64
#define DPCOEF (2.0f / (HDIM * NCHUNK))

typedef unsigned short u16;
typedef __attribute__((ext_vector_type(8))) unsigned short u16x8;
typedef __attribute__((ext_vector_type(8))) short bf16x8;
typedef __attribute__((ext_vector_type(4))) float f32x4;

__device__ __forceinline__ float sigmoidf_(float x){ return 1.0f/(1.0f+__expf(-x)); }
__device__ __forceinline__ float siluf_(float x){ return x*sigmoidf_(x); }
__device__ __forceinline__ float dsiluf_(float x){ float s=sigmoidf_(x); return s*(1.0f+x*(1.0f-s)); }
__device__ __forceinline__ u16 bf1_(float x){
    union{float f; unsigned u;} v; v.f = x;
    return (u16)((v.u + 0x7fffu + ((v.u>>16)&1u)) >> 16);
}
__device__ __forceinline__ float bf2f_(u16 h){
    union{unsigned u; float f;} v; v.u = ((unsigned)h) << 16; return v.f;
}
__device__ __forceinline__ int swkey_(int row){
    return (((row>>3)&1)<<2) | (((row>>4)&1)<<1) | ((row>>5)&1);
}
__device__ __forceinline__ void gl_lds16(const u16* g, u16* l){
    __builtin_amdgcn_global_load_lds(
        (const __attribute__((address_space(1))) unsigned*)g,
        (__attribute__((address_space(3))) unsigned*)l, 16, 0, 0);
}

// ---------------------------------------------------------------------------
// bf16 GEMM, 128x128 tile, BK=64, 4 waves, XCD-chunked block swizzle.
// ATR=false: A[M,K], B[N,K] k-contiguous — global_load_lds, swizzled source.
// ATR=true : A[K,M], B[K,N] — transpose staging, pair-packed b32 writes.
// MODE: 0 outF=acc+b | 1 h,dsilu | 2 h only | 3 splitK16 bf16 partials
//       4 *dsilu(aux) | 5 +resF->bf | 6 +b+resF->f32+bf | 7 +b+resF->f32
//       8 dpred (vf strided ldv) | 9 +b+resB->bf
// ---------------------------------------------------------------------------
template<int MODE, bool ATR>
__global__ __launch_bounds__(256)
void mgemm_k(const u16* __restrict__ A, const u16* __restrict__ B,
             const float* __restrict__ bias, const float* __restrict__ resF,
             const u16* __restrict__ resB, const u16* __restrict__ aux,
             const float* __restrict__ vf, const float* __restrict__ lrs,
             float* __restrict__ outF, u16* __restrict__ outB, u16* __restrict__ outB2,
             int M, int N, int K, int lda, int ldb, int ldv)
{
    __shared__ __align__(128) u16 As[128*64];
    __shared__ __align__(128) u16 Bs[128*64];
    const int tid = threadIdx.x;
    const int lane = tid & 63, wvi = tid >> 6;
    const int wm = wvi >> 1, wn = wvi & 1;
    const int lr = lane & 15, lq = lane >> 4;

    // XCD-chunked swizzle over (x,y); all grids have nwg % 8 == 0
    const int gx = gridDim.x;
    const int nwg = gx * gridDim.y;
    int bid = blockIdx.y * gx + blockIdx.x;
    bid = (bid & 7) * (nwg >> 3) + (bid >> 3);
    const int m0 = (bid / gx) * 128, n0 = (bid % gx) * 128;

    int kbeg = 0, kend = K;
    if (MODE == 3){ const int ks = K >> 4; kbeg = blockIdx.z * ks; kend = kbeg + ks; }

    f32x4 acc[4][4];
    const f32x4 zz = {0.f,0.f,0.f,0.f};
    #pragma unroll
    for (int i = 0; i < 4; ++i)
        #pragma unroll
        for (int j = 0; j < 4; ++j) acc[i][j] = zz;

    for (int k0 = kbeg; k0 < kend; k0 += BK) {
        if (!ATR) {
            #pragma unroll
            for (int it = 0; it < 4; ++it){
                const int seg = it*4 + wvi;
                const int key = (((seg&1)<<2)|(((seg>>1)&1)<<1)|((seg>>2)&1));
                const int row = seg*8 + (lane>>3);
                const int chunk = (lane&7) ^ key;
                gl_lds16(A + (size_t)(m0+row)*lda + k0 + chunk*8, &As[seg*512]);
                gl_lds16(B + (size_t)(n0+row)*ldb + k0 + chunk*8, &Bs[seg*512]);
            }
        } else {
            #pragma unroll
            for (int r = 0; r < 2; ++r){
                const int slot = r*256 + tid;
                const int mc = slot & 15, kp = slot >> 4;
                const int chunk = kp >> 2, t = kp & 3;
                const int key = (((mc&1)<<2)|(((mc>>1)&1)<<1)|((mc>>2)&1));
                const int cs = ((chunk ^ key) << 3) + t*2;
                {
                    const u16* p = A + (size_t)(k0 + 2*kp) * lda + m0 + mc*8;
                    u16x8 e = *(const u16x8*)p;
                    u16x8 o = *(const u16x8*)(p + lda);
                    #pragma unroll
                    for (int j = 0; j < 8; ++j)
                        *(unsigned*)&As[(mc*8 + j)*64 + cs] = (unsigned)e[j] | ((unsigned)o[j] << 16);
                }
                {
                    const u16* p = B + (size_t)(k0 + 2*kp) * ldb + n0 + mc*8;
                    u16x8 e = *(const u16x8*)p;
                    u16x8 o = *(const u16x8*)(p + ldb);
                    #pragma unroll
                    for (int j = 0; j < 8; ++j)
                        *(unsigned*)&Bs[(mc*8 + j)*64 + cs] = (unsigned)e[j] | ((unsigned)o[j] << 16);
                }
            }
        }
        __syncthreads();
        #pragma unroll
        for (int ks = 0; ks < 2; ++ks) {
            bf16x8 afr[4], bfr[4];
            #pragma unroll
            for (int i = 0; i < 4; ++i){
                const int ra = wm*64 + i*16 + lr, rb = wn*64 + i*16 + lr;
                afr[i] = *(const bf16x8*)&As[ra*64 + (((ks*4 + lq) ^ swkey_(ra)) << 3)];
                bfr[i] = *(const bf16x8*)&Bs[rb*64 + (((ks*4 + lq) ^ swkey_(rb)) << 3)];
            }
            #pragma unroll
            for (int mi = 0; mi < 4; ++mi)
                #pragma unroll
                for (int ni = 0; ni < 4; ++ni)
                    acc[mi][ni] = __builtin_amdgcn_mfma_f32_16x16x32_bf16(afr[mi], bfr[ni], acc[mi][ni], 0, 0, 0);
        }
        __syncthreads();
    }

    #pragma unroll
    for (int ni = 0; ni < 4; ++ni){
        const int col = n0 + wn*64 + ni*16 + lr;
        float bv = 0.0f;
        if (MODE==0 || MODE==1 || MODE==2 || MODE==6 || MODE==7 || MODE==8 || MODE==9) bv = bias[col];
        #pragma unroll
        for (int mi = 0; mi < 4; ++mi){
            const int rbase = m0 + wm*64 + mi*16 + lq*4;
            #pragma unroll
            for (int v = 0; v < 4; ++v){
                const int row = rbase + v;
                const size_t idx = (size_t)row * N + col;
                const float o = acc[mi][ni][v];
                if (MODE == 0){ outF[idx] = o + bv; }
                else if (MODE == 1){
                    const float u = o + bv;
                    outB[idx]  = bf1_(siluf_(u));
                    outB2[idx] = bf1_(dsiluf_(u));
                }
                else if (MODE == 2){ outB[idx] = bf1_(siluf_(o + bv)); }
                else if (MODE == 3){ outB[(size_t)blockIdx.z * M * N + idx] = bf1_(o); }
                else if (MODE == 4){ outB[idx] = bf1_(o * bf2f_(aux[idx])); }
                else if (MODE == 5){ outB[idx] = bf1_(o + resF[idx]); }
                else if (MODE == 6){ const float t = o + bv + resF[idx]; outF[idx] = t; outB[idx] = bf1_(t); }
                else if (MODE == 7){ outF[idx] = o + bv + resF[idx]; }
                else if (MODE == 8){
                    const float t = o + bv + bf2f_(resB[idx]);
                    const float g = lrs[row] * DPCOEF * (t - vf[(size_t)row * ldv + col]);
                    outF[idx] = g; outB[idx] = bf1_(g);
                }
                else if (MODE == 9){ outB[idx] = bf1_(o + bv + bf2f_(resB[idx])); }
            }
        }
    }
}

__global__ __launch_bounds__(256)
void cvt_k(const float* __restrict__ in, u16* __restrict__ out, int n8)
{
    const int i = blockIdx.x * 256 + threadIdx.x;
    if (i < n8){
        const float4 a = *(const float4*)(in + (size_t)i*8);
        const float4 b = *(const float4*)(in + (size_t)i*8 + 4);
        u16x8 o;
        o[0]=bf1_(a.x); o[1]=bf1_(a.y); o[2]=bf1_(a.z); o[3]=bf1_(a.w);
        o[4]=bf1_(b.x); o[5]=bf1_(b.y); o[6]=bf1_(b.z); o[7]=bf1_(b.w);
        *(u16x8*)(out + (size_t)i*8) = o;
    }
}

// concat-convert wk|wv|wq -> wkvqb [1536,512] bf16, and bk|bv|bq -> bkvq f32
__global__ __launch_bounds__(256)
void prep_kvq_k(const float* __restrict__ wk, const float* __restrict__ wv,
                const float* __restrict__ wq, const float* __restrict__ bk,
                const float* __restrict__ bv, const float* __restrict__ bq,
                u16* __restrict__ wkvqb, float* __restrict__ bkvq)
{
    const int per = HDIM*HDIM/8;          // 32768
    const int id = blockIdx.x * 256 + threadIdx.x;
    if (id < 3*per){
        const float* src = (id < per) ? wk : (id < 2*per ? wv : wq);
        const int i = id - (id < per ? 0 : (id < 2*per ? per : 2*per));
        const float4 a = *(const float4*)(src + (size_t)i*8);
        const float4 b = *(const float4*)(src + (size_t)i*8 + 4);
        u16x8 o;
        o[0]=bf1_(a.x); o[1]=bf1_(a.y); o[2]=bf1_(a.z); o[3]=bf1_(a.w);
        o[4]=bf1_(b.x); o[5]=bf1_(b.y); o[6]=bf1_(b.z); o[7]=bf1_(b.w);
        *(u16x8*)(wkvqb + (size_t)id*8) = o;
    } else {
        const int j = id - 3*per;
        if (j < 3*HDIM)
            bkvq[j] = (j < HDIM) ? bk[j] : (j < 2*HDIM ? bv[j-HDIM] : bq[j-2*HDIM]);
    }
}

__global__ __launch_bounds__(256)
void tcvt_k(const float* __restrict__ in, u16* __restrict__ out, int R, int C)
{
    __shared__ float t[32][33];
    const int tx = threadIdx.x & 31, ty = threadIdx.x >> 5;
    const int c0 = blockIdx.x * 32, r0 = blockIdx.y * 32;
    #pragma unroll
    for (int j = 0; j < 4; ++j)
        t[ty + 8*j][tx] = in[(size_t)(r0 + ty + 8*j) * C + c0 + tx];
    __syncthreads();
    #pragma unroll
    for (int j = 0; j < 4; ++j)
        out[(size_t)(c0 + ty + 8*j) * R + r0 + tx] = bf1_(t[tx][ty + 8*j]);
}

// row l2norm over HDIM cols of a row-strided fp32 matrix
template<bool WF32>
__global__ __launch_bounds__(64)
void l2norm_k(const float* __restrict__ in, int ld,
              float* __restrict__ outF, u16* __restrict__ outB)
{
    const float* p = in + (size_t)blockIdx.x * ld;
    const int t = threadIdx.x;
    float4 v0 = *(const float4*)(p + t*8), v1 = *(const float4*)(p + t*8 + 4);
    float s = v0.x*v0.x+v0.y*v0.y+v0.z*v0.z+v0.w*v0.w
            + v1.x*v1.x+v1.y*v1.y+v1.z*v1.z+v1.w*v1.w;
    #pragma unroll
    for (int o = 1; o < 64; o <<= 1) s += __shfl_xor(s, o);
    const float sc = 1.0f / fmaxf(sqrtf(s), 1e-12f);
    v0.x*=sc; v0.y*=sc; v0.z*=sc; v0.w*=sc;
    v1.x*=sc; v1.y*=sc; v1.z*=sc; v1.w*=sc;
    if (WF32){
        float* q = outF + (size_t)blockIdx.x * HDIM;
        *(float4*)(q + t*8) = v0; *(float4*)(q + t*8 + 4) = v1;
    }
    u16x8 ob;
    ob[0]=bf1_(v0.x); ob[1]=bf1_(v0.y); ob[2]=bf1_(v0.z); ob[3]=bf1_(v0.w);
    ob[4]=bf1_(v1.x); ob[5]=bf1_(v1.y); ob[6]=bf1_(v1.z); ob[7]=bf1_(v1.w);
    *(u16x8*)(outB + (size_t)blockIdx.x * HDIM + t*8) = ob;
}

__global__ __launch_bounds__(64)
void gates_k(const float* __restrict__ x,
             const float* __restrict__ wlr, const float* __restrict__ blr,
             const float* __restrict__ wf,  const float* __restrict__ bfp,
             const float* __restrict__ wm,  const float* __restrict__ bm,
             float* __restrict__ lr_s, float* __restrict__ f_s, float* __restrict__ m_s)
{
    const size_t row = blockIdx.x;
    const float* p = x + row * HDIM;
    const int t = threadIdx.x;
    float s0 = 0.f, s1 = 0.f, s2 = 0.f;
    #pragma unroll
    for (int i = 0; i < 8; i += 4){
        float4 xv = *(const float4*)(p   + t*8 + i);
        float4 a  = *(const float4*)(wlr + t*8 + i);
        float4 b  = *(const float4*)(wf  + t*8 + i);
        float4 c  = *(const float4*)(wm  + t*8 + i);
        s0 += xv.x*a.x + xv.y*a.y + xv.z*a.z + xv.w*a.w;
        s1 += xv.x*b.x + xv.y*b.y + xv.z*b.z + xv.w*b.w;
        s2 += xv.x*c.x + xv.y*c.y + xv.z*c.z + xv.w*c.w;
    }
    #pragma unroll
    for (int o = 1; o < 64; o <<= 1){
        s0 += __shfl_xor(s0, o); s1 += __shfl_xor(s1, o); s2 += __shfl_xor(s2, o);
    }
    if (t == 0){
        lr_s[row] = sigmoidf_(s0 + blr[0]) * 0.1f;
        f_s[row]  = sigmoidf_(s1 + bfp[0]);
        m_s[row]  = sigmoidf_(s2 + bm[0]);
    }
}

__global__ __launch_bounds__(256)
void scalars_k(const float* __restrict__ lr_s, const float* __restrict__ f_s,
               const float* __restrict__ m_s, float* __restrict__ sc)
{
    __shared__ float sh0[256], sh1[256], sh2[256];
    const int t = threadIdx.x;
    float s0 = 0.f, s1 = 0.f, s2 = 0.f;
    for (int i = t; i < NROWS; i += 256){ s0 += f_s[i]; s1 += lr_s[i]; s2 += m_s[i]; }
    sh0[t] = s0; sh1[t] = s1; sh2[t] = s2;
    __syncthreads();
    for (int o = 128; o > 0; o >>= 1){
        if (t < o){ sh0[t] += sh0[t+o]; sh1[t] += sh1[t+o]; sh2[t] += sh2[t+o]; }
        __syncthreads();
    }
    if (t == 0){
        sc[0] = sh0[0] / (float)NROWS;
        sc[1] = sh1[0] / (float)NROWS;
        sc[2] = sh2[0] / (float)NROWS;
    }
}

template<typename T>
__global__ __launch_bounds__(64)
void colsum_part_k(const T* __restrict__ g, float* __restrict__ part, int cols)
{
    const int c = blockIdx.x * 64 + threadIdx.x;
    const int rc = blockIdx.y;
    const T* p = g + (size_t)rc * 128 * cols + c;
    float s = 0.f;
    for (int r = 0; r < 128; ++r){
        if (sizeof(T) == 2) s += bf2f_(*(const u16*)(p + (size_t)r * cols));
        else                s += *(const float*)(p + (size_t)r * cols);
    }
    part[(size_t)rc * cols + c] = s;
}

// colsum finish fused with bias update: nb = p*(1-a) + eta*mom - theta*gsum
__global__ __launch_bounds__(256)
void colsum_upd_k(const float* __restrict__ part, const float* __restrict__ p,
                  const float* __restrict__ mom, const float* __restrict__ sc,
                  float* __restrict__ nb, int cols)
{
    const int c = blockIdx.x * 256 + threadIdx.x;
    if (c < cols){
        float s = 0.f;
        for (int r = 0; r < 64; ++r) s += part[(size_t)r * cols + c];
        nb[c] = p[c] * (1.0f - sc[0]) + sc[2] * mom[c] - sc[1] * s;
    }
}

// split-K16 bf16-partial reduce + weight update -> bf16 new weights
__global__ __launch_bounds__(256)
void fupdate16_k(const float* __restrict__ p, const u16* __restrict__ P,
                 const float* __restrict__ mom, const float* __restrict__ sc,
                 u16* __restrict__ nWb, int n)
{
    const int i = blockIdx.x * 256 + threadIdx.x;
    if (i < n){
        float g = 0.f;
        #pragma unroll
        for (int z = 0; z < 16; ++z) g += bf2f_(P[(size_t)z * n + i]);
        nWb[i] = bf1_(p[i] * (1.0f - sc[0]) + sc[2] * mom[i] - sc[1] * g);
    }
}

extern "C" void kernel_launch(void* const* d_in, const int* in_sizes, int n_in,
                              void* d_out, int out_size, void* d_ws, size_t ws_size,
                              hipStream_t stream)
{
    const float* x      = (const float*)d_in[0];
    const float* wq     = (const float*)d_in[1];
    const float* bq     = (const float*)d_in[2];
    const float* wk     = (const float*)d_in[3];
    const float* bk     = (const float*)d_in[4];
    const float* wv     = (const float*)d_in[5];
    const float* bv     = (const float*)d_in[6];
    const float* wlr    = (const float*)d_in[7];
    const float* blr    = (const float*)d_in[8];
    const float* wf     = (const float*)d_in[9];
    const float* bfp    = (const float*)d_in[10];
    const float* wm     = (const float*)d_in[11];
    const float* bm     = (const float*)d_in[12];
    const float* mw1    = (const float*)d_in[13];
    const float* mb1    = (const float*)d_in[14];
    const float* mw2    = (const float*)d_in[15];
    const float* mb2    = (const float*)d_in[16];
    const float* mom_w1 = (const float*)d_in[17];
    const float* mom_b1 = (const float*)d_in[18];
    const float* mom_w2 = (const float*)d_in[19];
    const float* mom_b2 = (const float*)d_in[20];
    float* out = (float*)d_out;

    char* base = (char*)d_ws;
    size_t off = 0;
    auto alloc = [&](size_t bytes)->char*{ char* p = base + off; off += (bytes + 255) & ~(size_t)255; return p; };
    const size_t NHf  = (size_t)NROWS * HDIM  * 4;   // 16MB
    const size_t NHb  = (size_t)NROWS * HDIM  * 2;   // 8MB
    const size_t NHEb = (size_t)NROWS * HEDIM * 2;   // 32MB
    const int    WHALF = HEDIM * HDIM;

    float* F2   = (float*)alloc(NHf);          // qf
    u16*  xb    = (u16*) alloc(NHb);           // x bf16 -> qb overlay
    u16*  kb    = (u16*) alloc(NHb);
    u16*  x1b   = (u16*) alloc(NHb);
    u16*  g2b   = (u16*) alloc(NHb);           // -> g1b overlay
    u16*  hb    = (u16*) alloc(NHEb);          // silu(u)
    u16*  db    = (u16*) alloc(NHEb);          // dsilu(u) / split-K16 bf16 partials
    u16*  dhb   = (u16*) alloc(NHEb + NHf);    // P3 (kvq f32, 48MB) -> dh (32MB) + F1 tail
    u16*  wkvqb = (u16*) alloc((size_t)3*HDIM*HDIM*2);
    float* bkvq = (float*)alloc((size_t)3*HDIM*4);
    u16*  mw1b  = (u16*) alloc((size_t)2*WHALF*2);
    u16*  mw2b  = (u16*) alloc((size_t)2*WHALF*2);
    u16*  mw2Tb = (u16*) alloc((size_t)2*WHALF*2);
    u16*  mw1T1b= (u16*) alloc((size_t)WHALF*2);
    u16*  nW1b  = (u16*) alloc((size_t)2*WHALF*2);
    u16*  nW2b  = (u16*) alloc((size_t)2*WHALF*2);
    float* cpart= (float*)alloc((size_t)64*HEDIM*4);
    float* lr_s = (float*)alloc((size_t)NROWS*4);
    float* f_s  = (float*)alloc((size_t)NROWS*4);
    float* m_s  = (float*)alloc((size_t)NROWS*4);
    float* sc   = (float*)alloc(64);
    float* nb1  = (float*)alloc((size_t)2*HEDIM*4);
    float* nb2  = (float*)alloc((size_t)2*HDIM*4);
    u16* qb  = xb;
    u16* g1b = g2b;
    float* P3 = (float*)dhb;                   // [8192,1536] f32 kvq output
    float* F1 = (float*)((char*)dhb + NHEb);   // x1f (phase 4), tail 16MB
    u16*  Pp  = db;                            // split-K bf16 partials

    const dim3 blk(256);
    const dim3 gKVQ (3*HDIM/128, NROWS/128);       // (12,64)
    const dim3 gN512 (HDIM/128,  NROWS/128);       // (4,64)
    const dim3 gN2048(HEDIM/128, NROWS/128);       // (16,64)
    const dim3 gTN2  (HEDIM/128, HDIM/128, 16);
    const dim3 gTN1  (HDIM/128,  HEDIM/128, 16);

    const float* mw1_1 = mw1 + (size_t)WHALF;
    const float* mw2_1 = mw2 + (size_t)WHALF;

    #define GARG(Ab,Bb,bi,rF,rB,ax,vv,ll,oF,oB,oB2,M,N,K,la,lb,lv) \
        ((const u16*)(Ab),(const u16*)(Bb),(const float*)(bi),(const float*)(rF),\
         (const u16*)(rB),(const u16*)(ax),(const float*)(vv),(const float*)(ll),\
         (float*)(oF),(u16*)(oB),(u16*)(oB2),(M),(N),(K),(la),(lb),(lv))

    // ---------- phase 0: conversions + gates ----------
    cvt_k<<<dim3((NROWS*HDIM/8)/256), blk, 0, stream>>>(x, xb, NROWS*HDIM/8);
    prep_kvq_k<<<dim3((3*HDIM*HDIM/8 + 3*HDIM + 255)/256), blk, 0, stream>>>(wk, wv, wq, bk, bv, bq, wkvqb, bkvq);
    cvt_k<<<dim3((2*WHALF/8)/256), blk, 0, stream>>>(mw1, mw1b, 2*WHALF/8);
    cvt_k<<<dim3((2*WHALF/8)/256), blk, 0, stream>>>(mw2, mw2b, 2*WHALF/8);
    tcvt_k<<<dim3(HEDIM/32, HDIM/32), blk, 0, stream>>>(mw2,   mw2Tb,         HDIM, HEDIM);
    tcvt_k<<<dim3(HEDIM/32, HDIM/32), blk, 0, stream>>>(mw2_1, mw2Tb + WHALF, HDIM, HEDIM);
    tcvt_k<<<dim3(HDIM/32, HEDIM/32), blk, 0, stream>>>(mw1_1, mw1T1b,        HEDIM, HDIM);
    gates_k<<<NROWS, 64, 0, stream>>>(x, wlr, blr, wf, bfp, wm, bm, lr_s, f_s, m_s);
    scalars_k<<<1, blk, 0, stream>>>(lr_s, f_s, m_s, sc);

    // ---------- phase 1: fused k|v|q projection ----------
    mgemm_k<0,false><<<gKVQ, blk, 0, stream>>>GARG(xb, wkvqb, bkvq, 0,0,0,0,0, P3, 0,0, NROWS,3*HDIM,HDIM, HDIM,HDIM, 3*HDIM);
    l2norm_k<false><<<NROWS, 64, 0, stream>>>(P3,          3*HDIM, nullptr, kb);
    l2norm_k<true ><<<NROWS, 64, 0, stream>>>(P3 + 2*HDIM, 3*HDIM, F2, qb);

    // ---------- phase 2: memory forward on k ----------
    mgemm_k<2,false><<<gN2048, blk, 0, stream>>>GARG(kb, mw1b, mb1, 0,0,0,0,0, 0, hb, 0, NROWS,HEDIM,HDIM, HDIM,HDIM, HEDIM);
    mgemm_k<9,false><<<gN512, blk, 0, stream>>>GARG(hb, mw2b, mb2, 0, kb, 0,0,0, 0, x1b, 0, NROWS,HDIM,HEDIM, HEDIM,HEDIM, HDIM);
    mgemm_k<1,false><<<gN2048, blk, 0, stream>>>GARG(x1b, mw1b+WHALF, mb1+HEDIM, 0,0,0,0,0, 0, hb, db, NROWS,HEDIM,HDIM, HDIM,HDIM, HEDIM);
    mgemm_k<8,false><<<gN512, blk, 0, stream>>>GARG(hb, mw2b+WHALF, mb2+HDIM, 0, x1b, 0, P3 + HDIM, lr_s, out, g2b, 0, NROWS,HDIM,HEDIM, HEDIM,HEDIM, 3*HDIM);

    // ---------- backward layer 1 ----------
    colsum_part_k<float><<<dim3(HDIM/64,64), 64, 0, stream>>>(out, cpart, HDIM);
    colsum_upd_k<<<dim3(HDIM/256), blk, 0, stream>>>(cpart, mb2+HDIM, mom_b2+HDIM, sc, nb2+HDIM, HDIM);
    mgemm_k<4,false><<<gN2048, blk, 0, stream>>>GARG(g2b, mw2Tb+WHALF, 0,0,0, db, 0,0, 0, dhb, 0, NROWS,HEDIM,HDIM, HDIM,HDIM, HEDIM);  // dh1
    mgemm_k<3,true><<<gTN2, blk, 0, stream>>>GARG(g2b, hb, 0,0,0,0,0,0, 0, Pp, 0, HDIM,HEDIM,NROWS, HDIM,HEDIM, HEDIM);                 // gW2_1
    fupdate16_k<<<dim3(WHALF/256), blk, 0, stream>>>(mw2_1, Pp, mom_w2+WHALF, sc, nW2b+WHALF, WHALF);
    colsum_part_k<u16><<<dim3(HEDIM/64,64), 64, 0, stream>>>(dhb, cpart, HEDIM);
    colsum_upd_k<<<dim3(HEDIM/256), blk, 0, stream>>>(cpart, mb1+HEDIM, mom_b1+HEDIM, sc, nb1+HEDIM, HEDIM);
    mgemm_k<3,true><<<gTN1, blk, 0, stream>>>GARG(dhb, x1b, 0,0,0,0,0,0, 0, Pp, 0, HEDIM,HDIM,NROWS, HEDIM,HDIM, HDIM);                 // gW1_1
    fupdate16_k<<<dim3(WHALF/256), blk, 0, stream>>>(mw1_1, Pp, mom_w1+WHALF, sc, nW1b+WHALF, WHALF);
    mgemm_k<5,false><<<gN512, blk, 0, stream>>>GARG(dhb, mw1T1b, 0, out, 0,0,0,0, 0, g1b, 0, NROWS,HDIM,HEDIM, HEDIM,HEDIM, HDIM);      // g1

    // ---------- backward layer 0 ----------
    colsum_part_k<u16><<<dim3(HDIM/64,64), 64, 0, stream>>>(g1b, cpart, HDIM);
    colsum_upd_k<<<dim3(HDIM/256), blk, 0, stream>>>(cpart, mb2, mom_b2, sc, nb2, HDIM);
    mgemm_k<1,false><<<gN2048, blk, 0, stream>>>GARG(kb, mw1b, mb1, 0,0,0,0,0, 0, hb, db, NROWS,HEDIM,HDIM, HDIM,HDIM, HEDIM);          // recompute u0
    mgemm_k<4,false><<<gN2048, blk, 0, stream>>>GARG(g1b, mw2Tb, 0,0,0, db, 0,0, 0, dhb, 0, NROWS,HEDIM,HDIM, HDIM,HDIM, HEDIM);        // dh0
    mgemm_k<3,true><<<gTN2, blk, 0, stream>>>GARG(g1b, hb, 0,0,0,0,0,0, 0, Pp, 0, HDIM,HEDIM,NROWS, HDIM,HEDIM, HEDIM);                 // gW2_0
    fupdate16_k<<<dim3(WHALF/256), blk, 0, stream>>>(mw2, Pp, mom_w2, sc, nW2b, WHALF);
    colsum_part_k<u16><<<dim3(HEDIM/64,64), 64, 0, stream>>>(dhb, cpart, HEDIM);
    colsum_upd_k<<<dim3(HEDIM/256), blk, 0, stream>>>(cpart, mb1, mom_b1, sc, nb1, HEDIM);
    mgemm_k<3,true><<<gTN1, blk, 0, stream>>>GARG(dhb, kb, 0,0,0,0,0,0, 0, Pp, 0, HEDIM,HDIM,NROWS, HEDIM,HDIM, HDIM);                  // gW1_0
    fupdate16_k<<<dim3(WHALF/256), blk, 0, stream>>>(mw1, Pp, mom_w1, sc, nW1b, WHALF);

    // ---------- phase 4: forward on q with new params ----------
    mgemm_k<2,false><<<gN2048, blk, 0, stream>>>GARG(qb, nW1b, nb1, 0,0,0,0,0, 0, hb, 0, NROWS,HEDIM,HDIM, HDIM,HDIM, HEDIM);
    mgemm_k<6,false><<<gN512, blk, 0, stream>>>GARG(hb, nW2b, nb2, F2, 0,0,0,0, F1, x1b, 0, NROWS,HDIM,HEDIM, HEDIM,HEDIM, HDIM);
    mgemm_k<2,false><<<gN2048, blk, 0, stream>>>GARG(x1b, nW1b+WHALF, nb1+HEDIM, 0,0,0,0,0, 0, hb, 0, NROWS,HEDIM,HDIM, HDIM,HDIM, HEDIM);
    mgemm_k<7,false><<<gN512, blk, 0, stream>>>GARG(hb, nW2b+WHALF, nb2+HDIM, F1, 0,0,0,0, out, 0,0, NROWS,HDIM,HEDIM, HEDIM,HEDIM, HDIM);

    #undef GARG
    (void)in_sizes; (void)n_in; (void)out_size; (void)ws_size;
}

// Round 7
// 807.412 us; speedup vs baseline: 6.5869x; 1.0004x over previous
//
#include <hip/hip_runtime.h>
#include <cstdint>
#include <cstddef>

// NeuralMemory — bf16 MFMA GEMMs, BK=64, swizzled linear LDS, NT staging via
// global_load_lds(16B), TN staging 4-row b64 writes, TN partials pair-packed
// u32 (coalesced), split-K x16, fused kvq projection, XCD swizzle.

#define NROWS 8192
#define HDIM  512
#define HEDIM 2048
#define NCHUNK 8
#define BK    64
#define DPCOEF (2.0f / (HDIM * NCHUNK))

typedef unsigned short u16;
typedef __attribute__((ext_vector_type(8))) unsigned short u16x8;
typedef __attribute__((ext_vector_type(8))) short bf16x8;
typedef __attribute__((ext_vector_type(4))) float f32x4;

__device__ __forceinline__ float sigmoidf_(float x){ return 1.0f/(1.0f+__expf(-x)); }
__device__ __forceinline__ float siluf_(float x){ return x*sigmoidf_(x); }
__device__ __forceinline__ float dsiluf_(float x){ float s=sigmoidf_(x); return s*(1.0f+x*(1.0f-s)); }
__device__ __forceinline__ u16 bf1_(float x){
    union{float f; unsigned u;} v; v.f = x;
    return (u16)((v.u + 0x7fffu + ((v.u>>16)&1u)) >> 16);
}
__device__ __forceinline__ unsigned bfpack_(float a, float b){
    union{float f; unsigned u;} ua, ub; ua.f = a; ub.f = b;
    unsigned ra = (ua.u + 0x7fffu + ((ua.u>>16)&1u)) >> 16;
    unsigned rb = (ub.u + 0x7fffu + ((ub.u>>16)&1u)) & 0xffff0000u;
    return ra | rb;
}
__device__ __forceinline__ float bf2f_(u16 h){
    union{unsigned u; float f;} v; v.u = ((unsigned)h) << 16; return v.f;
}
__device__ __forceinline__ int swkey_(int row){
    return (((row>>3)&1)<<2) | (((row>>4)&1)<<1) | ((row>>5)&1);
}
__device__ __forceinline__ void gl_lds16(const u16* g, u16* l){
    __builtin_amdgcn_global_load_lds(
        (const __attribute__((address_space(1))) unsigned*)g,
        (__attribute__((address_space(3))) unsigned*)l, 16, 0, 0);
}

// ---------------------------------------------------------------------------
// bf16 GEMM, 128x128 tile, BK=64, 4 waves, XCD-chunked block swizzle.
// ATR=false: A[M,K], B[N,K] k-contiguous — global_load_lds, swizzled source.
// ATR=true : A[K,M], B[K,N] — transpose staging, 4-row b64 writes.
// MODE: 0 outF=acc+b | 1 h,dsilu | 2 h only | 3 splitK16 pair-packed u32 bf16
//       4 *dsilu(aux) | 5 +resF->bf | 6 +b+resF->f32+bf | 7 +b+resF->f32
//       8 dpred (vf strided ldv) | 9 +b+resB->bf
// ---------------------------------------------------------------------------
template<int MODE, bool ATR>
__global__ __launch_bounds__(256)
void mgemm_k(const u16* __restrict__ A, const u16* __restrict__ B,
             const float* __restrict__ bias, const float* __restrict__ resF,
             const u16* __restrict__ resB, const u16* __restrict__ aux,
             const float* __restrict__ vf, const float* __restrict__ lrs,
             float* __restrict__ outF, u16* __restrict__ outB, u16* __restrict__ outB2,
             int M, int N, int K, int lda, int ldb, int ldv)
{
    __shared__ __align__(128) u16 As[128*64];
    __shared__ __align__(128) u16 Bs[128*64];
    const int tid = threadIdx.x;
    const int lane = tid & 63, wvi = tid >> 6;
    const int wm = wvi >> 1, wn = wvi & 1;
    const int lr = lane & 15, lq = lane >> 4;

    const int gx = gridDim.x;
    const int nwg = gx * gridDim.y;
    int bid = blockIdx.y * gx + blockIdx.x;
    bid = (bid & 7) * (nwg >> 3) + (bid >> 3);
    const int m0 = (bid / gx) * 128, n0 = (bid % gx) * 128;

    int kbeg = 0, kend = K;
    if (MODE == 3){ const int ks = K >> 4; kbeg = blockIdx.z * ks; kend = kbeg + ks; }

    f32x4 acc[4][4];
    const f32x4 zz = {0.f,0.f,0.f,0.f};
    #pragma unroll
    for (int i = 0; i < 4; ++i)
        #pragma unroll
        for (int j = 0; j < 4; ++j) acc[i][j] = zz;

    for (int k0 = kbeg; k0 < kend; k0 += BK) {
        if (!ATR) {
            #pragma unroll
            for (int it = 0; it < 4; ++it){
                const int seg = it*4 + wvi;
                const int key = (((seg&1)<<2)|(((seg>>1)&1)<<1)|((seg>>2)&1));
                const int row = seg*8 + (lane>>3);
                const int chunk = (lane&7) ^ key;
                gl_lds16(A + (size_t)(m0+row)*lda + k0 + chunk*8, &As[seg*512]);
                gl_lds16(B + (size_t)(n0+row)*ldb + k0 + chunk*8, &Bs[seg*512]);
            }
        } else {
            // 4 consecutive k-rows per thread, pack quads, b64 LDS writes
            const int mc = tid & 15, kp = tid >> 4;          // kp 0..15 (k-quads)
            const int key = (((mc&1)<<2)|(((mc>>1)&1)<<1)|((mc>>2)&1));
            const int cs = ((kp >> 1) ^ key) * 8 + (kp & 1) * 4;
            {
                const u16* p = A + (size_t)(k0 + 4*kp) * lda + m0 + mc*8;
                u16x8 r0 = *(const u16x8*)p;
                u16x8 r1 = *(const u16x8*)(p + lda);
                u16x8 r2 = *(const u16x8*)(p + 2*lda);
                u16x8 r3 = *(const u16x8*)(p + 3*lda);
                #pragma unroll
                for (int j = 0; j < 8; ++j){
                    uint2 w;
                    w.x = (unsigned)r0[j] | ((unsigned)r1[j] << 16);
                    w.y = (unsigned)r2[j] | ((unsigned)r3[j] << 16);
                    *(uint2*)&As[(mc*8 + j)*64 + cs] = w;
                }
            }
            {
                const u16* p = B + (size_t)(k0 + 4*kp) * ldb + n0 + mc*8;
                u16x8 r0 = *(const u16x8*)p;
                u16x8 r1 = *(const u16x8*)(p + ldb);
                u16x8 r2 = *(const u16x8*)(p + 2*ldb);
                u16x8 r3 = *(const u16x8*)(p + 3*ldb);
                #pragma unroll
                for (int j = 0; j < 8; ++j){
                    uint2 w;
                    w.x = (unsigned)r0[j] | ((unsigned)r1[j] << 16);
                    w.y = (unsigned)r2[j] | ((unsigned)r3[j] << 16);
                    *(uint2*)&Bs[(mc*8 + j)*64 + cs] = w;
                }
            }
        }
        __syncthreads();
        #pragma unroll
        for (int ks = 0; ks < 2; ++ks) {
            bf16x8 afr[4], bfr[4];
            #pragma unroll
            for (int i = 0; i < 4; ++i){
                const int ra = wm*64 + i*16 + lr, rb = wn*64 + i*16 + lr;
                afr[i] = *(const bf16x8*)&As[ra*64 + (((ks*4 + lq) ^ swkey_(ra)) << 3)];
                bfr[i] = *(const bf16x8*)&Bs[rb*64 + (((ks*4 + lq) ^ swkey_(rb)) << 3)];
            }
            #pragma unroll
            for (int mi = 0; mi < 4; ++mi)
                #pragma unroll
                for (int ni = 0; ni < 4; ++ni)
                    acc[mi][ni] = __builtin_amdgcn_mfma_f32_16x16x32_bf16(afr[mi], bfr[ni], acc[mi][ni], 0, 0, 0);
        }
        __syncthreads();
    }

    if (MODE == 3){
        // pair-packed bf16 partials: u32 P32[z][(M/2)*N], pair = rows (2r,2r+1)
        unsigned* P32 = (unsigned*)outB;
        const size_t zb = (size_t)blockIdx.z * ((size_t)M * N / 2);
        #pragma unroll
        for (int ni = 0; ni < 4; ++ni){
            const int col = n0 + wn*64 + ni*16 + lr;
            #pragma unroll
            for (int mi = 0; mi < 4; ++mi){
                const int pr = (m0 + wm*64 + mi*16 + lq*4) >> 1;
                P32[zb + (size_t)pr*N + col]     = bfpack_(acc[mi][ni][0], acc[mi][ni][1]);
                P32[zb + (size_t)(pr+1)*N + col] = bfpack_(acc[mi][ni][2], acc[mi][ni][3]);
            }
        }
        return;
    }

    #pragma unroll
    for (int ni = 0; ni < 4; ++ni){
        const int col = n0 + wn*64 + ni*16 + lr;
        float bv = 0.0f;
        if (MODE==0 || MODE==1 || MODE==2 || MODE==6 || MODE==7 || MODE==8 || MODE==9) bv = bias[col];
        #pragma unroll
        for (int mi = 0; mi < 4; ++mi){
            const int rbase = m0 + wm*64 + mi*16 + lq*4;
            #pragma unroll
            for (int v = 0; v < 4; ++v){
                const int row = rbase + v;
                const size_t idx = (size_t)row * N + col;
                const float o = acc[mi][ni][v];
                if (MODE == 0){ outF[idx] = o + bv; }
                else if (MODE == 1){
                    const float u = o + bv;
                    outB[idx]  = bf1_(siluf_(u));
                    outB2[idx] = bf1_(dsiluf_(u));
                }
                else if (MODE == 2){ outB[idx] = bf1_(siluf_(o + bv)); }
                else if (MODE == 4){ outB[idx] = bf1_(o * bf2f_(aux[idx])); }
                else if (MODE == 5){ outB[idx] = bf1_(o + resF[idx]); }
                else if (MODE == 6){ const float t = o + bv + resF[idx]; outF[idx] = t; outB[idx] = bf1_(t); }
                else if (MODE == 7){ outF[idx] = o + bv + resF[idx]; }
                else if (MODE == 8){
                    const float t = o + bv + bf2f_(resB[idx]);
                    const float g = lrs[row] * DPCOEF * (t - vf[(size_t)row * ldv + col]);
                    outF[idx] = g; outB[idx] = bf1_(g);
                }
                else if (MODE == 9){ outB[idx] = bf1_(o + bv + bf2f_(resB[idx])); }
            }
        }
    }
}

// fused phase-0 conversions: x, mw1, mw2 cvt + wkvq concat + bkvq concat
#define XSLOTS   (NROWS*HDIM/8)       // 524288 -> 2048 blocks
#define W1SLOTS  (2*HEDIM*HDIM/8)     // 524288? no: 2*2048*512/8 = 262144 -> 1024
#define KVQSLOTS (3*HDIM*HDIM/8)      // 98304 -> 384 blocks
__global__ __launch_bounds__(256)
void prep_all_k(const float* __restrict__ x,  u16* __restrict__ xb,
                const float* __restrict__ mw1, u16* __restrict__ mw1b,
                const float* __restrict__ mw2, u16* __restrict__ mw2b,
                const float* __restrict__ wk, const float* __restrict__ wv,
                const float* __restrict__ wq, u16* __restrict__ wkvqb,
                const float* __restrict__ bk, const float* __restrict__ bv,
                const float* __restrict__ bq, float* __restrict__ bkvq)
{
    const int id = blockIdx.x * 256 + threadIdx.x;
    const int W1S = 2*HEDIM*HDIM/8;
    const float* src; u16* dst; int i;
    if (id < XSLOTS){ src = x; dst = xb; i = id; }
    else if (id < XSLOTS + W1S){ src = mw1; dst = mw1b; i = id - XSLOTS; }
    else if (id < XSLOTS + 2*W1S){ src = mw2; dst = mw2b; i = id - XSLOTS - W1S; }
    else if (id < XSLOTS + 2*W1S + KVQSLOTS){
        const int j = id - XSLOTS - 2*W1S;
        const int per = HDIM*HDIM/8;
        src = (j < per) ? wk : (j < 2*per ? wv : wq);
        i = (j < per) ? j : (j < 2*per ? j - per : j - 2*per);
        dst = wkvqb + (size_t)(j - i) * 8 * 0 + (size_t)j*8 - (size_t)i*8;  // dst base offset
        dst = wkvqb + ((size_t)j - i) * 8;  // segment base in wkvqb
    }
    else {
        const int j = id - XSLOTS - 2*W1S - KVQSLOTS;
        if (j < 3*HDIM)
            bkvq[j] = (j < HDIM) ? bk[j] : (j < 2*HDIM ? bv[j-HDIM] : bq[j-2*HDIM]);
        return;
    }
    const float4 a = *(const float4*)(src + (size_t)i*8);
    const float4 b = *(const float4*)(src + (size_t)i*8 + 4);
    u16x8 o;
    o[0]=bf1_(a.x); o[1]=bf1_(a.y); o[2]=bf1_(a.z); o[3]=bf1_(a.w);
    o[4]=bf1_(b.x); o[5]=bf1_(b.y); o[6]=bf1_(b.z); o[7]=bf1_(b.w);
    *(u16x8*)(dst + (size_t)i*8) = o;
}

__global__ __launch_bounds__(256)
void tcvt_k(const float* __restrict__ in, u16* __restrict__ out, int R, int C)
{
    __shared__ float t[32][33];
    const int tx = threadIdx.x & 31, ty = threadIdx.x >> 5;
    const int c0 = blockIdx.x * 32, r0 = blockIdx.y * 32;
    #pragma unroll
    for (int j = 0; j < 4; ++j)
        t[ty + 8*j][tx] = in[(size_t)(r0 + ty + 8*j) * C + c0 + tx];
    __syncthreads();
    #pragma unroll
    for (int j = 0; j < 4; ++j)
        out[(size_t)(c0 + ty + 8*j) * R + r0 + tx] = bf1_(t[tx][ty + 8*j]);
}

template<bool WF32>
__global__ __launch_bounds__(64)
void l2norm_k(const float* __restrict__ in, int ld,
              float* __restrict__ outF, u16* __restrict__ outB)
{
    const float* p = in + (size_t)blockIdx.x * ld;
    const int t = threadIdx.x;
    float4 v0 = *(const float4*)(p + t*8), v1 = *(const float4*)(p + t*8 + 4);
    float s = v0.x*v0.x+v0.y*v0.y+v0.z*v0.z+v0.w*v0.w
            + v1.x*v1.x+v1.y*v1.y+v1.z*v1.z+v1.w*v1.w;
    #pragma unroll
    for (int o = 1; o < 64; o <<= 1) s += __shfl_xor(s, o);
    const float sc = 1.0f / fmaxf(sqrtf(s), 1e-12f);
    v0.x*=sc; v0.y*=sc; v0.z*=sc; v0.w*=sc;
    v1.x*=sc; v1.y*=sc; v1.z*=sc; v1.w*=sc;
    if (WF32){
        float* q = outF + (size_t)blockIdx.x * HDIM;
        *(float4*)(q + t*8) = v0; *(float4*)(q + t*8 + 4) = v1;
    }
    u16x8 ob;
    ob[0]=bf1_(v0.x); ob[1]=bf1_(v0.y); ob[2]=bf1_(v0.z); ob[3]=bf1_(v0.w);
    ob[4]=bf1_(v1.x); ob[5]=bf1_(v1.y); ob[6]=bf1_(v1.z); ob[7]=bf1_(v1.w);
    *(u16x8*)(outB + (size_t)blockIdx.x * HDIM + t*8) = ob;
}

__global__ __launch_bounds__(64)
void gates_k(const float* __restrict__ x,
             const float* __restrict__ wlr, const float* __restrict__ blr,
             const float* __restrict__ wf,  const float* __restrict__ bfp,
             const float* __restrict__ wm,  const float* __restrict__ bm,
             float* __restrict__ lr_s, float* __restrict__ f_s, float* __restrict__ m_s)
{
    const size_t row = blockIdx.x;
    const float* p = x + row * HDIM;
    const int t = threadIdx.x;
    float s0 = 0.f, s1 = 0.f, s2 = 0.f;
    #pragma unroll
    for (int i = 0; i < 8; i += 4){
        float4 xv = *(const float4*)(p   + t*8 + i);
        float4 a  = *(const float4*)(wlr + t*8 + i);
        float4 b  = *(const float4*)(wf  + t*8 + i);
        float4 c  = *(const float4*)(wm  + t*8 + i);
        s0 += xv.x*a.x + xv.y*a.y + xv.z*a.z + xv.w*a.w;
        s1 += xv.x*b.x + xv.y*b.y + xv.z*b.z + xv.w*b.w;
        s2 += xv.x*c.x + xv.y*c.y + xv.z*c.z + xv.w*c.w;
    }
    #pragma unroll
    for (int o = 1; o < 64; o <<= 1){
        s0 += __shfl_xor(s0, o); s1 += __shfl_xor(s1, o); s2 += __shfl_xor(s2, o);
    }
    if (t == 0){
        lr_s[row] = sigmoidf_(s0 + blr[0]) * 0.1f;
        f_s[row]  = sigmoidf_(s1 + bfp[0]);
        m_s[row]  = sigmoidf_(s2 + bm[0]);
    }
}

__global__ __launch_bounds__(256)
void scalars_k(const float* __restrict__ lr_s, const float* __restrict__ f_s,
               const float* __restrict__ m_s, float* __restrict__ sc)
{
    __shared__ float sh0[256], sh1[256], sh2[256];
    const int t = threadIdx.x;
    float s0 = 0.f, s1 = 0.f, s2 = 0.f;
    for (int i = t; i < NROWS; i += 256){ s0 += f_s[i]; s1 += lr_s[i]; s2 += m_s[i]; }
    sh0[t] = s0; sh1[t] = s1; sh2[t] = s2;
    __syncthreads();
    for (int o = 128; o > 0; o >>= 1){
        if (t < o){ sh0[t] += sh0[t+o]; sh1[t] += sh1[t+o]; sh2[t] += sh2[t+o]; }
        __syncthreads();
    }
    if (t == 0){
        sc[0] = sh0[0] / (float)NROWS;
        sc[1] = sh1[0] / (float)NROWS;
        sc[2] = sh2[0] / (float)NROWS;
    }
}

template<typename T>
__global__ __launch_bounds__(64)
void colsum_part_k(const T* __restrict__ g, float* __restrict__ part, int cols)
{
    const int c = blockIdx.x * 64 + threadIdx.x;
    const int rc = blockIdx.y;
    const T* p = g + (size_t)rc * 128 * cols + c;
    float s = 0.f;
    for (int r = 0; r < 128; ++r){
        if (sizeof(T) == 2) s += bf2f_(*(const u16*)(p + (size_t)r * cols));
        else                s += *(const float*)(p + (size_t)r * cols);
    }
    part[(size_t)rc * cols + c] = s;
}

__global__ __launch_bounds__(256)
void colsum_upd_k(const float* __restrict__ part, const float* __restrict__ p,
                  const float* __restrict__ mom, const float* __restrict__ sc,
                  float* __restrict__ nb, int cols)
{
    const int c = blockIdx.x * 256 + threadIdx.x;
    if (c < cols){
        float s = 0.f;
        for (int r = 0; r < 64; ++r) s += part[(size_t)r * cols + c];
        nb[c] = p[c] * (1.0f - sc[0]) + sc[2] * mom[c] - sc[1] * s;
    }
}

// pair-packed split-K16 reduce + weight update -> bf16 new weights
// P32[z][(M/2)*N], pair i -> rows (2*(i/N), 2*(i/N)+1), col i%N
__global__ __launch_bounds__(256)
void fupdate16p_k(const float* __restrict__ p, const unsigned* __restrict__ P32,
                  const float* __restrict__ mom, const float* __restrict__ sc,
                  u16* __restrict__ nWb, int N, int MN2)
{
    const int i = blockIdx.x * 256 + threadIdx.x;
    if (i < MN2){
        float g0 = 0.f, g1 = 0.f;
        #pragma unroll
        for (int z = 0; z < 16; ++z){
            const unsigned w = P32[(size_t)z * MN2 + i];
            g0 += bf2f_((u16)(w & 0xffffu));
            g1 += bf2f_((u16)(w >> 16));
        }
        const int c = i & (N - 1);
        const size_t r0 = ((size_t)(i / N) * 2) * N + c;
        nWb[r0]     = bf1_(p[r0]     * (1.0f - sc[0]) + sc[2] * mom[r0]     - sc[1] * g0);
        nWb[r0 + N] = bf1_(p[r0 + N] * (1.0f - sc[0]) + sc[2] * mom[r0 + N] - sc[1] * g1);
    }
}

extern "C" void kernel_launch(void* const* d_in, const int* in_sizes, int n_in,
                              void* d_out, int out_size, void* d_ws, size_t ws_size,
                              hipStream_t stream)
{
    const float* x      = (const float*)d_in[0];
    const float* wq     = (const float*)d_in[1];
    const float* bq     = (const float*)d_in[2];
    const float* wk     = (const float*)d_in[3];
    const float* bk     = (const float*)d_in[4];
    const float* wv     = (const float*)d_in[5];
    const float* bv     = (const float*)d_in[6];
    const float* wlr    = (const float*)d_in[7];
    const float* blr    = (const float*)d_in[8];
    const float* wf     = (const float*)d_in[9];
    const float* bfp    = (const float*)d_in[10];
    const float* wm     = (const float*)d_in[11];
    const float* bm     = (const float*)d_in[12];
    const float* mw1    = (const float*)d_in[13];
    const float* mb1    = (const float*)d_in[14];
    const float* mw2    = (const float*)d_in[15];
    const float* mb2    = (const float*)d_in[16];
    const float* mom_w1 = (const float*)d_in[17];
    const float* mom_b1 = (const float*)d_in[18];
    const float* mom_w2 = (const float*)d_in[19];
    const float* mom_b2 = (const float*)d_in[20];
    float* out = (float*)d_out;

    char* base = (char*)d_ws;
    size_t off = 0;
    auto alloc = [&](size_t bytes)->char*{ char* p = base + off; off += (bytes + 255) & ~(size_t)255; return p; };
    const size_t NHf  = (size_t)NROWS * HDIM  * 4;
    const size_t NHb  = (size_t)NROWS * HDIM  * 2;
    const size_t NHEb = (size_t)NROWS * HEDIM * 2;
    const int    WHALF = HEDIM * HDIM;

    float* F2   = (float*)alloc(NHf);          // qf
    u16*  xb    = (u16*) alloc(NHb);           // x bf16 -> qb overlay
    u16*  kb    = (u16*) alloc(NHb);
    u16*  x1b   = (u16*) alloc(NHb);
    u16*  g2b   = (u16*) alloc(NHb);           // -> g1b overlay
    u16*  hb    = (u16*) alloc(NHEb);          // silu(u)
    u16*  db    = (u16*) alloc(NHEb);          // dsilu(u) / split-K pair partials
    u16*  dhb   = (u16*) alloc(NHEb + NHf);    // P3 (kvq f32 48MB) -> dh + F1 tail
    u16*  wkvqb = (u16*) alloc((size_t)3*HDIM*HDIM*2);
    float* bkvq = (float*)alloc((size_t)3*HDIM*4);
    u16*  mw1b  = (u16*) alloc((size_t)2*WHALF*2);
    u16*  mw2b  = (u16*) alloc((size_t)2*WHALF*2);
    u16*  mw2Tb = (u16*) alloc((size_t)2*WHALF*2);
    u16*  mw1T1b= (u16*) alloc((size_t)WHALF*2);
    u16*  nW1b  = (u16*) alloc((size_t)2*WHALF*2);
    u16*  nW2b  = (u16*) alloc((size_t)2*WHALF*2);
    float* cpart= (float*)alloc((size_t)64*HEDIM*4);
    float* lr_s = (float*)alloc((size_t)NROWS*4);
    float* f_s  = (float*)alloc((size_t)NROWS*4);
    float* m_s  = (float*)alloc((size_t)NROWS*4);
    float* sc   = (float*)alloc(64);
    float* nb1  = (float*)alloc((size_t)2*HEDIM*4);
    float* nb2  = (float*)alloc((size_t)2*HDIM*4);
    u16* qb  = xb;
    u16* g1b = g2b;
    float* P3 = (float*)dhb;
    float* F1 = (float*)((char*)dhb + NHEb);
    unsigned* Pp = (unsigned*)db;              // pair partials 16 x 2MB = 32MB

    const dim3 blk(256);
    const dim3 gKVQ (3*HDIM/128, NROWS/128);
    const dim3 gN512 (HDIM/128,  NROWS/128);
    const dim3 gN2048(HEDIM/128, NROWS/128);
    const dim3 gTN2  (HEDIM/128, HDIM/128, 16);
    const dim3 gTN1  (HDIM/128,  HEDIM/128, 16);
    const int MN2 = WHALF / 2;                 // 524288 pairs per weight half

    const float* mw1_1 = mw1 + (size_t)WHALF;
    const float* mw2_1 = mw2 + (size_t)WHALF;

    #define GARG(Ab,Bb,bi,rF,rB,ax,vv,ll,oF,oB,oB2,M,N,K,la,lb,lv) \
        ((const u16*)(Ab),(const u16*)(Bb),(const float*)(bi),(const float*)(rF),\
         (const u16*)(rB),(const u16*)(ax),(const float*)(vv),(const float*)(ll),\
         (float*)(oF),(u16*)(oB),(u16*)(oB2),(M),(N),(K),(la),(lb),(lv))

    // ---------- phase 0: fused conversions + gates ----------
    {
        const int nblk = (XSLOTS + 2*(2*HEDIM*HDIM/8) + KVQSLOTS)/256 + (3*HDIM + 255)/256;
        prep_all_k<<<dim3(nblk), blk, 0, stream>>>(x, xb, mw1, mw1b, mw2, mw2b,
                                                   wk, wv, wq, wkvqb, bk, bv, bq, bkvq);
    }
    tcvt_k<<<dim3(HEDIM/32, HDIM/32), blk, 0, stream>>>(mw2,   mw2Tb,         HDIM, HEDIM);
    tcvt_k<<<dim3(HEDIM/32, HDIM/32), blk, 0, stream>>>(mw2_1, mw2Tb + WHALF, HDIM, HEDIM);
    tcvt_k<<<dim3(HDIM/32, HEDIM/32), blk, 0, stream>>>(mw1_1, mw1T1b,        HEDIM, HDIM);
    gates_k<<<NROWS, 64, 0, stream>>>(x, wlr, blr, wf, bfp, wm, bm, lr_s, f_s, m_s);
    scalars_k<<<1, blk, 0, stream>>>(lr_s, f_s, m_s, sc);

    // ---------- phase 1: fused k|v|q projection ----------
    mgemm_k<0,false><<<gKVQ, blk, 0, stream>>>GARG(xb, wkvqb, bkvq, 0,0,0,0,0, P3, 0,0, NROWS,3*HDIM,HDIM, HDIM,HDIM, 3*HDIM);
    l2norm_k<false><<<NROWS, 64, 0, stream>>>(P3,          3*HDIM, nullptr, kb);
    l2norm_k<true ><<<NROWS, 64, 0, stream>>>(P3 + 2*HDIM, 3*HDIM, F2, qb);

    // ---------- phase 2: memory forward on k ----------
    mgemm_k<2,false><<<gN2048, blk, 0, stream>>>GARG(kb, mw1b, mb1, 0,0,0,0,0, 0, hb, 0, NROWS,HEDIM,HDIM, HDIM,HDIM, HEDIM);
    mgemm_k<9,false><<<gN512, blk, 0, stream>>>GARG(hb, mw2b, mb2, 0, kb, 0,0,0, 0, x1b, 0, NROWS,HDIM,HEDIM, HEDIM,HEDIM, HDIM);
    mgemm_k<1,false><<<gN2048, blk, 0, stream>>>GARG(x1b, mw1b+WHALF, mb1+HEDIM, 0,0,0,0,0, 0, hb, db, NROWS,HEDIM,HDIM, HDIM,HDIM, HEDIM);
    mgemm_k<8,false><<<gN512, blk, 0, stream>>>GARG(hb, mw2b+WHALF, mb2+HDIM, 0, x1b, 0, P3 + HDIM, lr_s, out, g2b, 0, NROWS,HDIM,HEDIM, HEDIM,HEDIM, 3*HDIM);

    // ---------- backward layer 1 ----------
    colsum_part_k<float><<<dim3(HDIM/64,64), 64, 0, stream>>>(out, cpart, HDIM);
    colsum_upd_k<<<dim3(HDIM/256), blk, 0, stream>>>(cpart, mb2+HDIM, mom_b2+HDIM, sc, nb2+HDIM, HDIM);
    mgemm_k<4,false><<<gN2048, blk, 0, stream>>>GARG(g2b, mw2Tb+WHALF, 0,0,0, db, 0,0, 0, dhb, 0, NROWS,HEDIM,HDIM, HDIM,HDIM, HEDIM);  // dh1
    mgemm_k<3,true><<<gTN2, blk, 0, stream>>>GARG(g2b, hb, 0,0,0,0,0,0, 0, Pp, 0, HDIM,HEDIM,NROWS, HDIM,HEDIM, HEDIM);                 // gW2_1
    fupdate16p_k<<<dim3((MN2+255)/256), blk, 0, stream>>>(mw2_1, Pp, mom_w2+WHALF, sc, nW2b+WHALF, HEDIM, MN2);
    colsum_part_k<u16><<<dim3(HEDIM/64,64), 64, 0, stream>>>(dhb, cpart, HEDIM);
    colsum_upd_k<<<dim3(HEDIM/256), blk, 0, stream>>>(cpart, mb1+HEDIM, mom_b1+HEDIM, sc, nb1+HEDIM, HEDIM);
    mgemm_k<3,true><<<gTN1, blk, 0, stream>>>GARG(dhb, x1b, 0,0,0,0,0,0, 0, Pp, 0, HEDIM,HDIM,NROWS, HEDIM,HDIM, HDIM);                 // gW1_1
    fupdate16p_k<<<dim3((MN2+255)/256), blk, 0, stream>>>(mw1_1, Pp, mom_w1+WHALF, sc, nW1b+WHALF, HDIM, MN2);
    mgemm_k<5,false><<<gN512, blk, 0, stream>>>GARG(dhb, mw1T1b, 0, out, 0,0,0,0, 0, g1b, 0, NROWS,HDIM,HEDIM, HEDIM,HEDIM, HDIM);      // g1

    // ---------- backward layer 0 ----------
    colsum_part_k<u16><<<dim3(HDIM/64,64), 64, 0, stream>>>(g1b, cpart, HDIM);
    colsum_upd_k<<<dim3(HDIM/256), blk, 0, stream>>>(cpart, mb2, mom_b2, sc, nb2, HDIM);
    mgemm_k<1,false><<<gN2048, blk, 0, stream>>>GARG(kb, mw1b, mb1, 0,0,0,0,0, 0, hb, db, NROWS,HEDIM,HDIM, HDIM,HDIM, HEDIM);          // recompute u0
    mgemm_k<4,false><<<gN2048, blk, 0, stream>>>GARG(g1b, mw2Tb, 0,0,0, db, 0,0, 0, dhb, 0, NROWS,HEDIM,HDIM, HDIM,HDIM, HEDIM);        // dh0
    mgemm_k<3,true><<<gTN2, blk, 0, stream>>>GARG(g1b, hb, 0,0,0,0,0,0, 0, Pp, 0, HDIM,HEDIM,NROWS, HDIM,HEDIM, HEDIM);                 // gW2_0
    fupdate16p_k<<<dim3((MN2+255)/256), blk, 0, stream>>>(mw2, Pp, mom_w2, sc, nW2b, HEDIM, MN2);
    colsum_part_k<u16><<<dim3(HEDIM/64,64), 64, 0, stream>>>(dhb, cpart, HEDIM);
    colsum_upd_k<<<dim3(HEDIM/256), blk, 0, stream>>>(cpart, mb1, mom_b1, sc, nb1, HEDIM);
    mgemm_k<3,true><<<gTN1, blk, 0, stream>>>GARG(dhb, kb, 0,0,0,0,0,0, 0, Pp, 0, HEDIM,HDIM,NROWS, HEDIM,HDIM, HDIM);                  // gW1_0
    fupdate16p_k<<<dim3((MN2+255)/256), blk, 0, stream>>>(mw1, Pp, mom_w1, sc, nW1b, HDIM, MN2);

    // ---------- phase 4: forward on q with new params ----------
    mgemm_k<2,false><<<gN2048, blk, 0, stream>>>GARG(qb, nW1b, nb1, 0,0,0,0,0, 0, hb, 0, NROWS,HEDIM,HDIM, HDIM,HDIM, HEDIM);
    mgemm_k<6,false><<<gN512, blk, 0, stream>>>GARG(hb, nW2b, nb2, F2, 0,0,0,0, F1, x1b, 0, NROWS,HDIM,HEDIM, HEDIM,HEDIM, HDIM);
    mgemm_k<2,false><<<gN2048, blk, 0, stream>>>GARG(x1b, nW1b+WHALF, nb1+HEDIM, 0,0,0,0,0, 0, hb, 0, NROWS,HEDIM,HDIM, HDIM,HDIM, HEDIM);
    mgemm_k<7,false><<<gN512, blk, 0, stream>>>GARG(hb, nW2b+WHALF, nb2+HDIM, F1, 0,0,0,0, out, 0,0, NROWS,HDIM,HEDIM, HEDIM,HEDIM, HDIM);

    #undef GARG
    (void)in_sizes; (void)n_in; (void)out_size; (void)ws_size;
}

// Round 8
// 790.366 us; speedup vs baseline: 6.7290x; 1.0216x over previous
//
#include <hip/hip_runtime.h>
#include <cstdint>
#include <cstddef>

// NeuralMemory — bf16 MFMA GEMMs, BK=64, swizzled linear LDS.
// R8: NT path = double-buffered LDS + counted vmcnt(8) + raw s_barrier
//     (loads stay in flight across barriers); TN path = T14 async split
//     (reg-prefetch next tile before MFMA, ds_write after read-barrier);
//     ws_size-conditional h0/d0 shadow buffers to skip the u0 recompute.

#define NROWS 8192
#define HDIM  512
#define HEDIM 2048
#define NCHUNK 8
#define BK    64
#define DPCOEF (2.0f / (HDIM * NCHUNK))

typedef unsigned short u16;
typedef __attribute__((ext_vector_type(8))) unsigned short u16x8;
typedef __attribute__((ext_vector_type(8))) short bf16x8;
typedef __attribute__((ext_vector_type(4))) float f32x4;

__device__ __forceinline__ float sigmoidf_(float x){ return 1.0f/(1.0f+__expf(-x)); }
__device__ __forceinline__ float siluf_(float x){ return x*sigmoidf_(x); }
__device__ __forceinline__ float dsiluf_(float x){ float s=sigmoidf_(x); return s*(1.0f+x*(1.0f-s)); }
__device__ __forceinline__ u16 bf1_(float x){
    union{float f; unsigned u;} v; v.f = x;
    return (u16)((v.u + 0x7fffu + ((v.u>>16)&1u)) >> 16);
}
__device__ __forceinline__ unsigned bfpack_(float a, float b){
    union{float f; unsigned u;} ua, ub; ua.f = a; ub.f = b;
    unsigned ra = (ua.u + 0x7fffu + ((ua.u>>16)&1u)) >> 16;
    unsigned rb = (ub.u + 0x7fffu + ((ub.u>>16)&1u)) & 0xffff0000u;
    return ra | rb;
}
__device__ __forceinline__ float bf2f_(u16 h){
    union{unsigned u; float f;} v; v.u = ((unsigned)h) << 16; return v.f;
}
__device__ __forceinline__ int swkey_(int row){
    return (((row>>3)&1)<<2) | (((row>>4)&1)<<1) | ((row>>5)&1);
}
__device__ __forceinline__ void gl_lds16(const u16* g, u16* l){
    __builtin_amdgcn_global_load_lds(
        (const __attribute__((address_space(1))) unsigned*)g,
        (__attribute__((address_space(3))) unsigned*)l, 16, 0, 0);
}
__device__ __forceinline__ void bar_(){ asm volatile("s_barrier" ::: "memory"); }
#define VMCNT8  asm volatile("s_waitcnt vmcnt(8)" ::: "memory")
#define VMCNT0  asm volatile("s_waitcnt vmcnt(0)" ::: "memory")
#define LGKM0   asm volatile("s_waitcnt lgkmcnt(0)" ::: "memory")

// ---------------------------------------------------------------------------
// bf16 GEMM, 128x128 tile, BK=64, 4 waves, XCD-chunked block swizzle.
// ATR=false: A[M,K], B[N,K] — global_load_lds into 2 LDS buffers, vmcnt(8).
// ATR=true : A[K,M], B[K,N] — T14: reg-prefetch next tile, write after reads.
// MODE: 0 outF=acc+b | 1 h,dsilu | 2 h only | 3 splitK16 pair-packed u32 bf16
//       4 *dsilu(aux) | 5 +resF->bf | 6 +b+resF->f32+bf | 7 +b+resF->f32
//       8 dpred (vf strided ldv) | 9 +b+resB->bf
// ---------------------------------------------------------------------------
template<int MODE, bool ATR>
__global__ __launch_bounds__(256)
void mgemm_k(const u16* __restrict__ A, const u16* __restrict__ B,
             const float* __restrict__ bias, const float* __restrict__ resF,
             const u16* __restrict__ resB, const u16* __restrict__ aux,
             const float* __restrict__ vf, const float* __restrict__ lrs,
             float* __restrict__ outF, u16* __restrict__ outB, u16* __restrict__ outB2,
             int M, int N, int K, int lda, int ldb, int ldv)
{
    constexpr int NBUF = ATR ? 1 : 2;
    __shared__ __align__(128) u16 As[NBUF][128*64];
    __shared__ __align__(128) u16 Bs[NBUF][128*64];
    const int tid = threadIdx.x;
    const int lane = tid & 63, wvi = tid >> 6;
    const int wm = wvi >> 1, wn = wvi & 1;
    const int lr = lane & 15, lq = lane >> 4;

    const int gx = gridDim.x;
    const int nwg = gx * gridDim.y;
    int bid = blockIdx.y * gx + blockIdx.x;
    bid = (bid & 7) * (nwg >> 3) + (bid >> 3);
    const int m0 = (bid / gx) * 128, n0 = (bid % gx) * 128;

    int kbeg = 0, kend = K;
    if (MODE == 3){ const int ks = K >> 4; kbeg = blockIdx.z * ks; kend = kbeg + ks; }
    const int nk = (kend - kbeg) / BK;

    f32x4 acc[4][4];
    const f32x4 zz = {0.f,0.f,0.f,0.f};
    #pragma unroll
    for (int i = 0; i < 4; ++i)
        #pragma unroll
        for (int j = 0; j < 4; ++j) acc[i][j] = zz;

    // TN staging state
    const int mc = tid & 15, kp = tid >> 4;
    const int tkey = (((mc&1)<<2)|(((mc>>1)&1)<<1)|((mc>>2)&1));
    const int tcs = ((kp >> 1) ^ tkey) * 8 + (kp & 1) * 4;
    u16x8 rgA0, rgA1, rgA2, rgA3, rgB0, rgB1, rgB2, rgB3;

    auto stageNT = [&](int k0, int b){
        #pragma unroll
        for (int it = 0; it < 4; ++it){
            const int seg = it*4 + wvi;
            const int key = (((seg&1)<<2)|(((seg>>1)&1)<<1)|((seg>>2)&1));
            const int row = seg*8 + (lane>>3);
            const int chunk = (lane&7) ^ key;
            gl_lds16(A + (size_t)(m0+row)*lda + k0 + chunk*8, &As[b][seg*512]);
            gl_lds16(B + (size_t)(n0+row)*ldb + k0 + chunk*8, &Bs[b][seg*512]);
        }
    };
    auto gloadTN = [&](int k0){
        const u16* pa = A + (size_t)(k0 + 4*kp) * lda + m0 + mc*8;
        rgA0 = *(const u16x8*)pa;          rgA1 = *(const u16x8*)(pa + lda);
        rgA2 = *(const u16x8*)(pa+2*lda);  rgA3 = *(const u16x8*)(pa + 3*lda);
        const u16* pb = B + (size_t)(k0 + 4*kp) * ldb + n0 + mc*8;
        rgB0 = *(const u16x8*)pb;          rgB1 = *(const u16x8*)(pb + ldb);
        rgB2 = *(const u16x8*)(pb+2*ldb);  rgB3 = *(const u16x8*)(pb + 3*ldb);
    };
    auto dswriteTN = [&](){
        #pragma unroll
        for (int j = 0; j < 8; ++j){
            uint2 w;
            w.x = (unsigned)rgA0[j] | ((unsigned)rgA1[j] << 16);
            w.y = (unsigned)rgA2[j] | ((unsigned)rgA3[j] << 16);
            *(uint2*)&As[0][(mc*8 + j)*64 + tcs] = w;
            uint2 v;
            v.x = (unsigned)rgB0[j] | ((unsigned)rgB1[j] << 16);
            v.y = (unsigned)rgB2[j] | ((unsigned)rgB3[j] << 16);
            *(uint2*)&Bs[0][(mc*8 + j)*64 + tcs] = v;
        }
    };
    auto mfmaStep = [&](int b){
        #pragma unroll
        for (int ks = 0; ks < 2; ++ks) {
            bf16x8 afr[4], bfr[4];
            #pragma unroll
            for (int i = 0; i < 4; ++i){
                const int ra = wm*64 + i*16 + lr, rb = wn*64 + i*16 + lr;
                afr[i] = *(const bf16x8*)&As[b][ra*64 + (((ks*4 + lq) ^ swkey_(ra)) << 3)];
                bfr[i] = *(const bf16x8*)&Bs[b][rb*64 + (((ks*4 + lq) ^ swkey_(rb)) << 3)];
            }
            #pragma unroll
            for (int mi = 0; mi < 4; ++mi)
                #pragma unroll
                for (int ni = 0; ni < 4; ++ni)
                    acc[mi][ni] = __builtin_amdgcn_mfma_f32_16x16x32_bf16(afr[mi], bfr[ni], acc[mi][ni], 0, 0, 0);
        }
    };

    if (!ATR) {
        // ---- double-buffered, counted-vmcnt pipeline
        stageNT(kbeg, 0);
        int cur = 0;
        for (int i = 0; i < nk; ++i){
            const int k0 = kbeg + i*BK;
            if (i + 1 < nk){ stageNT(k0 + BK, cur ^ 1); VMCNT8; }
            else           { VMCNT0; }
            bar_();
            mfmaStep(cur);
            bar_();
            cur ^= 1;
        }
    } else {
        // ---- single-buffer T14: prefetch regs early, write after read-barrier
        gloadTN(kbeg);
        dswriteTN();
        LGKM0; bar_();
        for (int i = 0; i < nk; ++i){
            const int k0 = kbeg + i*BK;
            const bool hn = (i + 1 < nk);
            if (hn) gloadTN(k0 + BK);
            mfmaStep(0);
            bar_();                       // all reads of As/Bs done
            if (hn){ dswriteTN(); LGKM0; }
            bar_();                       // writes visible to all
        }
    }

    if (MODE == 3){
        unsigned* P32 = (unsigned*)outB;
        const size_t zb = (size_t)blockIdx.z * ((size_t)M * N / 2);
        #pragma unroll
        for (int ni = 0; ni < 4; ++ni){
            const int col = n0 + wn*64 + ni*16 + lr;
            #pragma unroll
            for (int mi = 0; mi < 4; ++mi){
                const int pr = (m0 + wm*64 + mi*16 + lq*4) >> 1;
                P32[zb + (size_t)pr*N + col]     = bfpack_(acc[mi][ni][0], acc[mi][ni][1]);
                P32[zb + (size_t)(pr+1)*N + col] = bfpack_(acc[mi][ni][2], acc[mi][ni][3]);
            }
        }
        return;
    }

    #pragma unroll
    for (int ni = 0; ni < 4; ++ni){
        const int col = n0 + wn*64 + ni*16 + lr;
        float bv = 0.0f;
        if (MODE==0 || MODE==1 || MODE==2 || MODE==6 || MODE==7 || MODE==8 || MODE==9) bv = bias[col];
        #pragma unroll
        for (int mi = 0; mi < 4; ++mi){
            const int rbase = m0 + wm*64 + mi*16 + lq*4;
            #pragma unroll
            for (int v = 0; v < 4; ++v){
                const int row = rbase + v;
                const size_t idx = (size_t)row * N + col;
                const float o = acc[mi][ni][v];
                if (MODE == 0){ outF[idx] = o + bv; }
                else if (MODE == 1){
                    const float u = o + bv;
                    outB[idx]  = bf1_(siluf_(u));
                    outB2[idx] = bf1_(dsiluf_(u));
                }
                else if (MODE == 2){ outB[idx] = bf1_(siluf_(o + bv)); }
                else if (MODE == 4){ outB[idx] = bf1_(o * bf2f_(aux[idx])); }
                else if (MODE == 5){ outB[idx] = bf1_(o + resF[idx]); }
                else if (MODE == 6){ const float t = o + bv + resF[idx]; outF[idx] = t; outB[idx] = bf1_(t); }
                else if (MODE == 7){ outF[idx] = o + bv + resF[idx]; }
                else if (MODE == 8){
                    const float t = o + bv + bf2f_(resB[idx]);
                    const float g = lrs[row] * DPCOEF * (t - vf[(size_t)row * ldv + col]);
                    outF[idx] = g; outB[idx] = bf1_(g);
                }
                else if (MODE == 9){ outB[idx] = bf1_(o + bv + bf2f_(resB[idx])); }
            }
        }
    }
}

// fused phase-0 conversions
#define XSLOTS   (NROWS*HDIM/8)
#define KVQSLOTS (3*HDIM*HDIM/8)
__global__ __launch_bounds__(256)
void prep_all_k(const float* __restrict__ x,  u16* __restrict__ xb,
                const float* __restrict__ mw1, u16* __restrict__ mw1b,
                const float* __restrict__ mw2, u16* __restrict__ mw2b,
                const float* __restrict__ wk, const float* __restrict__ wv,
                const float* __restrict__ wq, u16* __restrict__ wkvqb,
                const float* __restrict__ bk, const float* __restrict__ bv,
                const float* __restrict__ bq, float* __restrict__ bkvq)
{
    const int id = blockIdx.x * 256 + threadIdx.x;
    const int W1S = 2*HEDIM*HDIM/8;
    const float* src; u16* dst; int i;
    if (id < XSLOTS){ src = x; dst = xb; i = id; }
    else if (id < XSLOTS + W1S){ src = mw1; dst = mw1b; i = id - XSLOTS; }
    else if (id < XSLOTS + 2*W1S){ src = mw2; dst = mw2b; i = id - XSLOTS - W1S; }
    else if (id < XSLOTS + 2*W1S + KVQSLOTS){
        const int j = id - XSLOTS - 2*W1S;
        const int per = HDIM*HDIM/8;
        src = (j < per) ? wk : (j < 2*per ? wv : wq);
        i = (j < per) ? j : (j < 2*per ? j - per : j - 2*per);
        dst = wkvqb + ((size_t)(j - i)) * 8;
    }
    else {
        const int j = id - XSLOTS - 2*W1S - KVQSLOTS;
        if (j < 3*HDIM)
            bkvq[j] = (j < HDIM) ? bk[j] : (j < 2*HDIM ? bv[j-HDIM] : bq[j-2*HDIM]);
        return;
    }
    const float4 a = *(const float4*)(src + (size_t)i*8);
    const float4 b = *(const float4*)(src + (size_t)i*8 + 4);
    u16x8 o;
    o[0]=bf1_(a.x); o[1]=bf1_(a.y); o[2]=bf1_(a.z); o[3]=bf1_(a.w);
    o[4]=bf1_(b.x); o[5]=bf1_(b.y); o[6]=bf1_(b.z); o[7]=bf1_(b.w);
    *(u16x8*)(dst + (size_t)i*8) = o;
}

__global__ __launch_bounds__(256)
void tcvt_k(const float* __restrict__ in, u16* __restrict__ out, int R, int C)
{
    __shared__ float t[32][33];
    const int tx = threadIdx.x & 31, ty = threadIdx.x >> 5;
    const int c0 = blockIdx.x * 32, r0 = blockIdx.y * 32;
    #pragma unroll
    for (int j = 0; j < 4; ++j)
        t[ty + 8*j][tx] = in[(size_t)(r0 + ty + 8*j) * C + c0 + tx];
    __syncthreads();
    #pragma unroll
    for (int j = 0; j < 4; ++j)
        out[(size_t)(c0 + ty + 8*j) * R + r0 + tx] = bf1_(t[tx][ty + 8*j]);
}

template<bool WF32>
__global__ __launch_bounds__(64)
void l2norm_k(const float* __restrict__ in, int ld,
              float* __restrict__ outF, u16* __restrict__ outB)
{
    const float* p = in + (size_t)blockIdx.x * ld;
    const int t = threadIdx.x;
    float4 v0 = *(const float4*)(p + t*8), v1 = *(const float4*)(p + t*8 + 4);
    float s = v0.x*v0.x+v0.y*v0.y+v0.z*v0.z+v0.w*v0.w
            + v1.x*v1.x+v1.y*v1.y+v1.z*v1.z+v1.w*v1.w;
    #pragma unroll
    for (int o = 1; o < 64; o <<= 1) s += __shfl_xor(s, o);
    const float sc = 1.0f / fmaxf(sqrtf(s), 1e-12f);
    v0.x*=sc; v0.y*=sc; v0.z*=sc; v0.w*=sc;
    v1.x*=sc; v1.y*=sc; v1.z*=sc; v1.w*=sc;
    if (WF32){
        float* q = outF + (size_t)blockIdx.x * HDIM;
        *(float4*)(q + t*8) = v0; *(float4*)(q + t*8 + 4) = v1;
    }
    u16x8 ob;
    ob[0]=bf1_(v0.x); ob[1]=bf1_(v0.y); ob[2]=bf1_(v0.z); ob[3]=bf1_(v0.w);
    ob[4]=bf1_(v1.x); ob[5]=bf1_(v1.y); ob[6]=bf1_(v1.z); ob[7]=bf1_(v1.w);
    *(u16x8*)(outB + (size_t)blockIdx.x * HDIM + t*8) = ob;
}

__global__ __launch_bounds__(64)
void gates_k(const float* __restrict__ x,
             const float* __restrict__ wlr, const float* __restrict__ blr,
             const float* __restrict__ wf,  const float* __restrict__ bfp,
             const float* __restrict__ wm,  const float* __restrict__ bm,
             float* __restrict__ lr_s, float* __restrict__ f_s, float* __restrict__ m_s)
{
    const size_t row = blockIdx.x;
    const float* p = x + row * HDIM;
    const int t = threadIdx.x;
    float s0 = 0.f, s1 = 0.f, s2 = 0.f;
    #pragma unroll
    for (int i = 0; i < 8; i += 4){
        float4 xv = *(const float4*)(p   + t*8 + i);
        float4 a  = *(const float4*)(wlr + t*8 + i);
        float4 b  = *(const float4*)(wf  + t*8 + i);
        float4 c  = *(const float4*)(wm  + t*8 + i);
        s0 += xv.x*a.x + xv.y*a.y + xv.z*a.z + xv.w*a.w;
        s1 += xv.x*b.x + xv.y*b.y + xv.z*b.z + xv.w*b.w;
        s2 += xv.x*c.x + xv.y*c.y + xv.z*c.z + xv.w*c.w;
    }
    #pragma unroll
    for (int o = 1; o < 64; o <<= 1){
        s0 += __shfl_xor(s0, o); s1 += __shfl_xor(s1, o); s2 += __shfl_xor(s2, o);
    }
    if (t == 0){
        lr_s[row] = sigmoidf_(s0 + blr[0]) * 0.1f;
        f_s[row]  = sigmoidf_(s1 + bfp[0]);
        m_s[row]  = sigmoidf_(s2 + bm[0]);
    }
}

__global__ __launch_bounds__(256)
void scalars_k(const float* __restrict__ lr_s, const float* __restrict__ f_s,
               const float* __restrict__ m_s, float* __restrict__ sc)
{
    __shared__ float sh0[256], sh1[256], sh2[256];
    const int t = threadIdx.x;
    float s0 = 0.f, s1 = 0.f, s2 = 0.f;
    for (int i = t; i < NROWS; i += 256){ s0 += f_s[i]; s1 += lr_s[i]; s2 += m_s[i]; }
    sh0[t] = s0; sh1[t] = s1; sh2[t] = s2;
    __syncthreads();
    for (int o = 128; o > 0; o >>= 1){
        if (t < o){ sh0[t] += sh0[t+o]; sh1[t] += sh1[t+o]; sh2[t] += sh2[t+o]; }
        __syncthreads();
    }
    if (t == 0){
        sc[0] = sh0[0] / (float)NROWS;
        sc[1] = sh1[0] / (float)NROWS;
        sc[2] = sh2[0] / (float)NROWS;
    }
}

template<typename T>
__global__ __launch_bounds__(64)
void colsum_part_k(const T* __restrict__ g, float* __restrict__ part, int cols)
{
    const int c = blockIdx.x * 64 + threadIdx.x;
    const int rc = blockIdx.y;
    const T* p = g + (size_t)rc * 128 * cols + c;
    float s = 0.f;
    for (int r = 0; r < 128; ++r){
        if (sizeof(T) == 2) s += bf2f_(*(const u16*)(p + (size_t)r * cols));
        else                s += *(const float*)(p + (size_t)r * cols);
    }
    part[(size_t)rc * cols + c] = s;
}

__global__ __launch_bounds__(256)
void colsum_upd_k(const float* __restrict__ part, const float* __restrict__ p,
                  const float* __restrict__ mom, const float* __restrict__ sc,
                  float* __restrict__ nb, int cols)
{
    const int c = blockIdx.x * 256 + threadIdx.x;
    if (c < cols){
        float s = 0.f;
        for (int r = 0; r < 64; ++r) s += part[(size_t)r * cols + c];
        nb[c] = p[c] * (1.0f - sc[0]) + sc[2] * mom[c] - sc[1] * s;
    }
}

__global__ __launch_bounds__(256)
void fupdate16p_k(const float* __restrict__ p, const unsigned* __restrict__ P32,
                  const float* __restrict__ mom, const float* __restrict__ sc,
                  u16* __restrict__ nWb, int N, int MN2)
{
    const int i = blockIdx.x * 256 + threadIdx.x;
    if (i < MN2){
        float g0 = 0.f, g1 = 0.f;
        #pragma unroll
        for (int z = 0; z < 16; ++z){
            const unsigned w = P32[(size_t)z * MN2 + i];
            g0 += bf2f_((u16)(w & 0xffffu));
            g1 += bf2f_((u16)(w >> 16));
        }
        const int c = i & (N - 1);
        const size_t r0 = ((size_t)(i / N) * 2) * N + c;
        nWb[r0]     = bf1_(p[r0]     * (1.0f - sc[0]) + sc[2] * mom[r0]     - sc[1] * g0);
        nWb[r0 + N] = bf1_(p[r0 + N] * (1.0f - sc[0]) + sc[2] * mom[r0 + N] - sc[1] * g1);
    }
}

extern "C" void kernel_launch(void* const* d_in, const int* in_sizes, int n_in,
                              void* d_out, int out_size, void* d_ws, size_t ws_size,
                              hipStream_t stream)
{
    const float* x      = (const float*)d_in[0];
    const float* wq     = (const float*)d_in[1];
    const float* bq     = (const float*)d_in[2];
    const float* wk     = (const float*)d_in[3];
    const float* bk     = (const float*)d_in[4];
    const float* wv     = (const float*)d_in[5];
    const float* bv     = (const float*)d_in[6];
    const float* wlr    = (const float*)d_in[7];
    const float* blr    = (const float*)d_in[8];
    const float* wf     = (const float*)d_in[9];
    const float* bfp    = (const float*)d_in[10];
    const float* wm     = (const float*)d_in[11];
    const float* bm     = (const float*)d_in[12];
    const float* mw1    = (const float*)d_in[13];
    const float* mb1    = (const float*)d_in[14];
    const float* mw2    = (const float*)d_in[15];
    const float* mb2    = (const float*)d_in[16];
    const float* mom_w1 = (const float*)d_in[17];
    const float* mom_b1 = (const float*)d_in[18];
    const float* mom_w2 = (const float*)d_in[19];
    const float* mom_b2 = (const float*)d_in[20];
    float* out = (float*)d_out;

    char* base = (char*)d_ws;
    size_t off = 0;
    auto alloc = [&](size_t bytes)->char*{ char* p = base + off; off += (bytes + 255) & ~(size_t)255; return p; };
    const size_t NHf  = (size_t)NROWS * HDIM  * 4;
    const size_t NHb  = (size_t)NROWS * HDIM  * 2;
    const size_t NHEb = (size_t)NROWS * HEDIM * 2;
    const int    WHALF = HEDIM * HDIM;

    float* F2   = (float*)alloc(NHf);
    u16*  xb    = (u16*) alloc(NHb);
    u16*  kb    = (u16*) alloc(NHb);
    u16*  x1b   = (u16*) alloc(NHb);
    u16*  g2b   = (u16*) alloc(NHb);
    u16*  hb    = (u16*) alloc(NHEb);
    u16*  db    = (u16*) alloc(NHEb);
    u16*  dhb   = (u16*) alloc(NHEb + NHf);
    u16*  wkvqb = (u16*) alloc((size_t)3*HDIM*HDIM*2);
    float* bkvq = (float*)alloc((size_t)3*HDIM*4);
    u16*  mw1b  = (u16*) alloc((size_t)2*WHALF*2);
    u16*  mw2b  = (u16*) alloc((size_t)2*WHALF*2);
    u16*  mw2Tb = (u16*) alloc((size_t)2*WHALF*2);
    u16*  mw1T1b= (u16*) alloc((size_t)WHALF*2);
    u16*  nW1b  = (u16*) alloc((size_t)2*WHALF*2);
    u16*  nW2b  = (u16*) alloc((size_t)2*WHALF*2);
    float* cpart= (float*)alloc((size_t)64*HEDIM*4);
    float* lr_s = (float*)alloc((size_t)NROWS*4);
    float* f_s  = (float*)alloc((size_t)NROWS*4);
    float* m_s  = (float*)alloc((size_t)NROWS*4);
    float* sc   = (float*)alloc(64);
    float* nb1  = (float*)alloc((size_t)2*HEDIM*4);
    float* nb2  = (float*)alloc((size_t)2*HDIM*4);

    // optional h0/d0 shadow buffers (skip the u0-recompute GEMM if they fit)
    const bool keep0 = (ws_size >= off + 2*NHEb + 1024);
    u16* h0b = keep0 ? (u16*)alloc(NHEb) : hb;
    u16* d0b = keep0 ? (u16*)alloc(NHEb) : db;

    u16* qb  = xb;
    u16* g1b = g2b;
    float* P3 = (float*)dhb;
    float* F1 = (float*)((char*)dhb + NHEb);
    unsigned* Pp = (unsigned*)db;

    const dim3 blk(256);
    const dim3 gKVQ (3*HDIM/128, NROWS/128);
    const dim3 gN512 (HDIM/128,  NROWS/128);
    const dim3 gN2048(HEDIM/128, NROWS/128);
    const dim3 gTN2  (HEDIM/128, HDIM/128, 16);
    const dim3 gTN1  (HDIM/128,  HEDIM/128, 16);
    const int MN2 = WHALF / 2;

    const float* mw1_1 = mw1 + (size_t)WHALF;
    const float* mw2_1 = mw2 + (size_t)WHALF;

    #define GARG(Ab,Bb,bi,rF,rB,ax,vv,ll,oF,oB,oB2,M,N,K,la,lb,lv) \
        ((const u16*)(Ab),(const u16*)(Bb),(const float*)(bi),(const float*)(rF),\
         (const u16*)(rB),(const u16*)(ax),(const float*)(vv),(const float*)(ll),\
         (float*)(oF),(u16*)(oB),(u16*)(oB2),(M),(N),(K),(la),(lb),(lv))

    // ---------- phase 0: fused conversions + gates ----------
    {
        const int nblk = (XSLOTS + 2*(2*HEDIM*HDIM/8) + KVQSLOTS)/256 + (3*HDIM + 255)/256;
        prep_all_k<<<dim3(nblk), blk, 0, stream>>>(x, xb, mw1, mw1b, mw2, mw2b,
                                                   wk, wv, wq, wkvqb, bk, bv, bq, bkvq);
    }
    tcvt_k<<<dim3(HEDIM/32, HDIM/32), blk, 0, stream>>>(mw2,   mw2Tb,         HDIM, HEDIM);
    tcvt_k<<<dim3(HEDIM/32, HDIM/32), blk, 0, stream>>>(mw2_1, mw2Tb + WHALF, HDIM, HEDIM);
    tcvt_k<<<dim3(HDIM/32, HEDIM/32), blk, 0, stream>>>(mw1_1, mw1T1b,        HEDIM, HDIM);
    gates_k<<<NROWS, 64, 0, stream>>>(x, wlr, blr, wf, bfp, wm, bm, lr_s, f_s, m_s);
    scalars_k<<<1, blk, 0, stream>>>(lr_s, f_s, m_s, sc);

    // ---------- phase 1: fused k|v|q projection ----------
    mgemm_k<0,false><<<gKVQ, blk, 0, stream>>>GARG(xb, wkvqb, bkvq, 0,0,0,0,0, P3, 0,0, NROWS,3*HDIM,HDIM, HDIM,HDIM, 3*HDIM);
    l2norm_k<false><<<NROWS, 64, 0, stream>>>(P3,          3*HDIM, nullptr, kb);
    l2norm_k<true ><<<NROWS, 64, 0, stream>>>(P3 + 2*HDIM, 3*HDIM, F2, qb);

    // ---------- phase 2: memory forward on k ----------
    if (keep0)
        mgemm_k<1,false><<<gN2048, blk, 0, stream>>>GARG(kb, mw1b, mb1, 0,0,0,0,0, 0, h0b, d0b, NROWS,HEDIM,HDIM, HDIM,HDIM, HEDIM);
    else
        mgemm_k<2,false><<<gN2048, blk, 0, stream>>>GARG(kb, mw1b, mb1, 0,0,0,0,0, 0, hb, 0, NROWS,HEDIM,HDIM, HDIM,HDIM, HEDIM);
    mgemm_k<9,false><<<gN512, blk, 0, stream>>>GARG(h0b, mw2b, mb2, 0, kb, 0,0,0, 0, x1b, 0, NROWS,HDIM,HEDIM, HEDIM,HEDIM, HDIM);
    mgemm_k<1,false><<<gN2048, blk, 0, stream>>>GARG(x1b, mw1b+WHALF, mb1+HEDIM, 0,0,0,0,0, 0, hb, db, NROWS,HEDIM,HDIM, HDIM,HDIM, HEDIM);
    mgemm_k<8,false><<<gN512, blk, 0, stream>>>GARG(hb, mw2b+WHALF, mb2+HDIM, 0, x1b, 0, P3 + HDIM, lr_s, out, g2b, 0, NROWS,HDIM,HEDIM, HEDIM,HEDIM, 3*HDIM);

    // ---------- backward layer 1 ----------
    colsum_part_k<float><<<dim3(HDIM/64,64), 64, 0, stream>>>(out, cpart, HDIM);
    colsum_upd_k<<<dim3(HDIM/256), blk, 0, stream>>>(cpart, mb2+HDIM, mom_b2+HDIM, sc, nb2+HDIM, HDIM);
    mgemm_k<4,false><<<gN2048, blk, 0, stream>>>GARG(g2b, mw2Tb+WHALF, 0,0,0, db, 0,0, 0, dhb, 0, NROWS,HEDIM,HDIM, HDIM,HDIM, HEDIM);  // dh1
    mgemm_k<3,true><<<gTN2, blk, 0, stream>>>GARG(g2b, hb, 0,0,0,0,0,0, 0, Pp, 0, HDIM,HEDIM,NROWS, HDIM,HEDIM, HEDIM);                 // gW2_1
    fupdate16p_k<<<dim3((MN2+255)/256), blk, 0, stream>>>(mw2_1, Pp, mom_w2+WHALF, sc, nW2b+WHALF, HEDIM, MN2);
    colsum_part_k<u16><<<dim3(HEDIM/64,64), 64, 0, stream>>>(dhb, cpart, HEDIM);
    colsum_upd_k<<<dim3(HEDIM/256), blk, 0, stream>>>(cpart, mb1+HEDIM, mom_b1+HEDIM, sc, nb1+HEDIM, HEDIM);
    mgemm_k<3,true><<<gTN1, blk, 0, stream>>>GARG(dhb, x1b, 0,0,0,0,0,0, 0, Pp, 0, HEDIM,HDIM,NROWS, HEDIM,HDIM, HDIM);                 // gW1_1
    fupdate16p_k<<<dim3((MN2+255)/256), blk, 0, stream>>>(mw1_1, Pp, mom_w1+WHALF, sc, nW1b+WHALF, HDIM, MN2);
    mgemm_k<5,false><<<gN512, blk, 0, stream>>>GARG(dhb, mw1T1b, 0, out, 0,0,0,0, 0, g1b, 0, NROWS,HDIM,HEDIM, HEDIM,HEDIM, HDIM);      // g1

    // ---------- backward layer 0 ----------
    colsum_part_k<u16><<<dim3(HDIM/64,64), 64, 0, stream>>>(g1b, cpart, HDIM);
    colsum_upd_k<<<dim3(HDIM/256), blk, 0, stream>>>(cpart, mb2, mom_b2, sc, nb2, HDIM);
    if (!keep0)
        mgemm_k<1,false><<<gN2048, blk, 0, stream>>>GARG(kb, mw1b, mb1, 0,0,0,0,0, 0, hb, db, NROWS,HEDIM,HDIM, HDIM,HDIM, HEDIM);      // recompute u0
    mgemm_k<4,false><<<gN2048, blk, 0, stream>>>GARG(g1b, mw2Tb, 0,0,0, d0b, 0,0, 0, dhb, 0, NROWS,HEDIM,HDIM, HDIM,HDIM, HEDIM);       // dh0
    mgemm_k<3,true><<<gTN2, blk, 0, stream>>>GARG(g1b, h0b, 0,0,0,0,0,0, 0, Pp, 0, HDIM,HEDIM,NROWS, HDIM,HEDIM, HEDIM);                // gW2_0
    fupdate16p_k<<<dim3((MN2+255)/256), blk, 0, stream>>>(mw2, Pp, mom_w2, sc, nW2b, HEDIM, MN2);
    colsum_part_k<u16><<<dim3(HEDIM/64,64), 64, 0, stream>>>(dhb, cpart, HEDIM);
    colsum_upd_k<<<dim3(HEDIM/256), blk, 0, stream>>>(cpart, mb1, mom_b1, sc, nb1, HEDIM);
    mgemm_k<3,true><<<gTN1, blk, 0, stream>>>GARG(dhb, kb, 0,0,0,0,0,0, 0, Pp, 0, HEDIM,HDIM,NROWS, HEDIM,HDIM, HDIM);                  // gW1_0
    fupdate16p_k<<<dim3((MN2+255)/256), blk, 0, stream>>>(mw1, Pp, mom_w1, sc, nW1b, HDIM, MN2);

    // ---------- phase 4: forward on q with new params ----------
    mgemm_k<2,false><<<gN2048, blk, 0, stream>>>GARG(qb, nW1b, nb1, 0,0,0,0,0, 0, hb, 0, NROWS,HEDIM,HDIM, HDIM,HDIM, HEDIM);
    mgemm_k<6,false><<<gN512, blk, 0, stream>>>GARG(hb, nW2b, nb2, F2, 0,0,0,0, F1, x1b, 0, NROWS,HDIM,HEDIM, HEDIM,HEDIM, HDIM);
    mgemm_k<2,false><<<gN2048, blk, 0, stream>>>GARG(x1b, nW1b+WHALF, nb1+HEDIM, 0,0,0,0,0, 0, hb, 0, NROWS,HEDIM,HDIM, HDIM,HDIM, HEDIM);
    mgemm_k<7,false><<<gN512, blk, 0, stream>>>GARG(hb, nW2b+WHALF, nb2+HDIM, F1, 0,0,0,0, out, 0,0, NROWS,HDIM,HEDIM, HEDIM,HEDIM, HDIM);

    #undef GARG
    (void)in_sizes; (void)n_in; (void)out_size;
}